// Round 9
// baseline (242.273 us; speedup 1.0000x reference)
//
#include <hip/hip_runtime.h>
#include <cstdint>
#include <cstddef>

// ---------------- constants ----------------
__constant__ int LV_N[5]    = {49152, 12288, 3072, 768, 192};   // H*W*3
__constant__ int LV_K[5]    = {2000, 2000, 2000, 768, 192};     // min(PRE_NMS, N)
__constant__ int LV_OFF[5]  = {0, 2000, 4000, 6000, 6768};      // concat offsets
__constant__ int LV_UOFF[5] = {0, 49152, 61440, 64512, 65280};  // u-array offsets
__constant__ int LV_W[5]    = {128, 64, 32, 16, 8};
__constant__ int LV_S[5]    = {4, 8, 16, 32, 64};
__constant__ int LV_LOGHW[5]= {14, 12, 10, 8, 6};
// mask geometry (rows padded by 128 so the scan prefetch never needs bounds tests)
__constant__ int WPL[5]     = {32, 32, 32, 12, 3};              // words per row
__constant__ int MOFF[5]    = {0, 68096, 136192, 204288, 215040};
__constant__ int MB_BASE[6] = {0, 256, 512, 768, 804, 807};     // mask-block bases
__constant__ int MB_CT[5]   = {8, 8, 8, 3, 1};                  // col tiles per lvl
__constant__ int SGB6[6]    = {0, 12, 15, 16, 17, 18};          // 4096-elem tile bases

#define M_TOT 6960
#define U_PER_IMG 65472
#define MAX_OUT 1000
#define MWORDS_PER_IMG 216000
#define CAP 4096

struct Ptrs { const float* cls[5]; const float* reg[5]; };

// ---------------- XLA:CPU-compatible expf (Cephes/Eigen pexp, FMA-contracted) ----
__device__ __forceinline__ float xla_expf(float x) {
  const float exp_hi = 88.3762626647950f;
  const float exp_lo = -88.3762626647949f;
  const float log2ef = 1.44269504088896341f;
  const float c1 = 0.693359375f;
  const float c2 = -2.12194440e-4f;
  const float p0 = 1.9875691500e-4f;
  const float p1 = 1.3981999507e-3f;
  const float p2 = 8.3334519073e-3f;
  const float p3 = 4.1665795894e-2f;
  const float p4 = 1.6666665459e-1f;
  const float p5 = 5.0000001201e-1f;
  float xx = fminf(fmaxf(x, exp_lo), exp_hi);
  float fx = floorf(__fmaf_rn(xx, log2ef, 0.5f));
  float r = __fmaf_rn(fx, -c1, xx);
  r = __fmaf_rn(fx, -c2, r);
  float z = __fmul_rn(r, r);
  float y = __fmaf_rn(p0, r, p1);
  y = __fmaf_rn(y, r, p2);
  y = __fmaf_rn(y, r, p3);
  y = __fmaf_rn(y, r, p4);
  y = __fmaf_rn(y, r, p5);
  y = __fmaf_rn(y, z, r);
  y = __fadd_rn(y, 1.0f);
  int n = (int)fx;
  float two_n = __uint_as_float((unsigned)(n + 127) << 23);
  return __fmul_rn(y, two_n);
}

__device__ __forceinline__ float ref_sigmoid(float x) {
  return __fdiv_rn(1.0f, __fadd_rn(1.0f, xla_expf(-x)));
}

// ================= K0: wide sigmoid + 4096-bin score-bit histogram ============
__global__ __launch_bounds__(1024) void k_sig(Ptrs p, unsigned* u_arr,
                                              unsigned* ghist) {
  const int img = blockIdx.y;
  const int bx = blockIdx.x;
  int lvl = 0;
  while (bx >= SGB6[lvl + 1]) ++lvl;
  const int N = LV_N[lvl], LOGHW = LV_LOGHW[lvl];
  const int HW = 1 << LOGHW;
  const int e0 = (bx - SGB6[lvl]) * 4096;
  const int e1 = (e0 + 4096 < N) ? e0 + 4096 : N;
  const int tid = (int)threadIdx.x;
  __shared__ unsigned h[4096];
  for (int e = tid; e < 4096; e += 1024) h[e] = 0;
  __syncthreads();
  const float* cls = p.cls[lvl] + (size_t)img * N;
  unsigned* u = u_arr + img * U_PER_IMG + LV_UOFF[lvl];
  for (int e = e0 + tid; e < e1; e += 1024) {
    float logit = cls[e];                  // plane-major: fully coalesced
    unsigned ub = __float_as_uint(ref_sigmoid(logit));
    int a = e >> LOGHW, pix = e & (HW - 1);
    u[pix * 3 + a] = ub;                   // channel-last (reference order)
    atomicAdd(&h[(ub >> 18) & 4095u], 1u);
  }
  __syncthreads();
  unsigned* gh = ghist + (size_t)(img * 5 + lvl) * 4096;
  for (int e = tid; e < 4096; e += 1024)
    if (h[e]) atomicAdd(&gh[e], h[e]);
}

// ================= K1a: threshold pick (O(bins), N-scan only on fallback) =====
__global__ __launch_bounds__(1024) void k_thresh(const unsigned* u_arr,
    const unsigned* ghist, unsigned long long* T64_arr) {
  const int blk = blockIdx.x;
  const int img = blk / 5, lvl = blk % 5;
  const int N = LV_N[lvl], K = LV_K[lvl];
  const int tid = (int)threadIdx.x;
  if (N <= K) { if (tid == 0) T64_arr[blk] = 0ULL; return; }
  __shared__ unsigned h[4096], sA[4096], sB[4096];
  __shared__ unsigned sh_D, sh_sD, sh_sD1;
  const unsigned* u = u_arr + img * U_PER_IMG + LV_UOFF[lvl];

  for (int e = tid; e < 4096; e += 1024)
    h[e] = ghist[(size_t)blk * 4096 + e];
  __syncthreads();

  unsigned long long prefix = 0;
  unsigned want = (unsigned)K, above = 0;
  const int shifts[6] = {50, 38, 26, 14, 2, 0};
  const int widths[6] = {12, 12, 12, 12, 12, 2};
  for (int rd = 0; rd < 6; ++rd) {
    const int shift = shifts[rd], width = widths[rd];
    const int nb = 1 << width;
    if (rd > 0) {                          // fallback: exact rescan (rare)
      for (int e = tid; e < nb; e += 1024) h[e] = 0;
      __syncthreads();
      for (int i = tid; i < N; i += 1024) {
        unsigned long long key =
            ((unsigned long long)u[i] << 32) | (unsigned)(~(unsigned)i);
        if ((key >> (shift + width)) == prefix)
          atomicAdd(&h[(unsigned)(key >> shift) & (unsigned)(nb - 1)], 1u);
      }
      __syncthreads();
    }
    // suffix scan s[d] = sum_{v>=d} h[v]
    unsigned *Ap = sA, *Bp = sB;
    for (int e = tid; e < nb; e += 1024) Ap[e] = h[e];
    __syncthreads();
    for (int off = 1; off < nb; off <<= 1) {
      for (int e = tid; e < nb; e += 1024)
        Bp[e] = Ap[e] + ((e + off < nb) ? Ap[e + off] : 0u);
      __syncthreads();
      unsigned* t = Ap; Ap = Bp; Bp = t;
    }
    for (int e = tid; e < nb; e += 1024) {
      unsigned s = Ap[e], sn = (e + 1 < nb) ? Ap[e + 1] : 0u;
      if (s >= want && sn < want) { sh_D = (unsigned)e; sh_sD = s; sh_sD1 = sn; }
    }
    __syncthreads();
    unsigned D = sh_D, sD = sh_sD, sD1 = sh_sD1;
    unsigned long long npref = (prefix << width) | (unsigned long long)D;
    if (above + sD <= (unsigned)CAP || rd == 5) {
      if (tid == 0) T64_arr[blk] = npref << shift;
      return;                              // uniform decision across block
    }
    above += sD1; want -= sD1; prefix = npref;
    __syncthreads();
  }
}

// ================= K1b: wide collect of keys >= T64 (unordered) ==============
__global__ __launch_bounds__(1024) void k_collect(const unsigned* u_arr,
    const unsigned long long* T64_arr, unsigned long long* gtk, unsigned* gcnt) {
  const int img = blockIdx.y;
  const int bx = blockIdx.x;
  int lvl = 0;
  while (bx >= SGB6[lvl + 1]) ++lvl;
  const int N = LV_N[lvl];
  const int e0 = (bx - SGB6[lvl]) * 4096;
  const int e1 = (e0 + 4096 < N) ? e0 + 4096 : N;
  const int tid = (int)threadIdx.x;
  const int lane = tid & 63;
  const unsigned long long T = T64_arr[img * 5 + lvl];
  const unsigned* u = u_arr + img * U_PER_IMG + LV_UOFF[lvl];
  unsigned long long* dst = gtk + (size_t)(img * 5 + lvl) * CAP;
  unsigned* cnt = gcnt + (img * 5 + lvl);
  for (int e = e0 + tid; e < e1; e += 1024) {
    unsigned long long key =
        ((unsigned long long)u[e] << 32) | (unsigned)(~(unsigned)e);
    bool pred = key >= T;
    unsigned long long bm = __ballot(pred);
    if (bm) {
      int leader = __ffsll((long long)bm) - 1;
      unsigned sbase = 0;
      if (lane == leader) sbase = atomicAdd(cnt, (unsigned)__popcll(bm));
      sbase = __shfl(sbase, leader);
      if (pred) {
        unsigned slot = sbase + (unsigned)__popcll(bm & ((1ULL << lane) - 1ULL));
        if (slot < (unsigned)CAP) dst[slot] = key;
      }
    }
  }
}

// ================= K1c: brute-force rank + direct decode (no sort) ===========
// Keys unique -> rank = #{j: key_j > key_i} is the exact sort permutation.
// Each thread owns one key: cnt broadcast LDS compares, decode into slot rank.
// Valid flags -> global bitmask via atomicOr (order-independent, deterministic).
__global__ __launch_bounds__(256) void k_rank(Ptrs p,
    const unsigned long long* gtk, const unsigned* gcnt,
    float* cand_box, float* cand_s, unsigned long long* vflags) {
  const int il = (int)blockIdx.y;
  const int img = il / 5, lvl = il % 5;
  const int N = LV_N[lvl], K = LV_K[lvl], W = LV_W[lvl], S = LV_S[lvl];
  const int HW = N / 3;
  const float* reg = p.reg[lvl] + (size_t)img * 12 * HW;
  const int tid = (int)threadIdx.x;
  unsigned cnt = gcnt[il];
  if (cnt > (unsigned)CAP) cnt = CAP;
  const unsigned cnt8 = (cnt + 7u) & ~7u;
  __shared__ unsigned long long keys[CAP];
  const unsigned long long* src = gtk + (size_t)il * CAP;
  for (int e = tid; e < (int)cnt8; e += 256)
    keys[e] = (e < (int)cnt) ? src[e] : 0ULL;   // real keys >= 2^32 > 0 pad
  __syncthreads();
  const int s = (int)blockIdx.x * 256 + tid;
  if (s >= (int)cnt) return;
  const unsigned long long mykey = keys[s];
  unsigned rank = 0;
  #pragma unroll 8
  for (unsigned j = 0; j < cnt8; ++j)
    rank += (keys[j] > mykey) ? 1u : 0u;        // broadcast read, conflict-free
  if (rank >= (unsigned)K) return;

  unsigned ubits = (unsigned)(mykey >> 32);
  unsigned idx = ~((unsigned)mykey);
  int a = (int)(idx % 3u); int pix = (int)(idx / 3u);
  int xq = pix % W, yq = pix / W;
  float dx = reg[(a * 4 + 0) * HW + pix];
  float dy = reg[(a * 4 + 1) * HW + pix];
  float dw = reg[(a * 4 + 2) * HW + pix];
  float dh = reg[(a * 4 + 3) * HW + pix];
  double rr = (a == 0) ? 0.5 : (a == 1 ? 1.0 : 2.0);
  double hr = sqrt(rr), wr = 1.0 / hr;
  double st = (double)S;
  double wsd = st * wr * 8.0, hsd = st * hr * 8.0;
  double sxd = (double)(xq * S), syd = (double)(yq * S);
  float a0 = (float)(sxd - 0.5 * wsd), a1 = (float)(syd - 0.5 * hsd);
  float a2 = (float)(sxd + 0.5 * wsd), a3 = (float)(syd + 0.5 * hsd);
  float px = __fmul_rn(__fadd_rn(a0, a2), 0.5f);
  float py = __fmul_rn(__fadd_rn(a1, a3), 0.5f);
  float pw = __fsub_rn(a2, a0), ph = __fsub_rn(a3, a1);
  const float MRf = 4.135166556742356f;  // |log(16/1000)| rounded to f32
  float dwc = fminf(fmaxf(dw, -MRf), MRf);
  float dhc = fminf(fmaxf(dh, -MRf), MRf);
  float gw = __fmul_rn(pw, xla_expf(dwc));
  float gh = __fmul_rn(ph, xla_expf(dhc));
  float gx = __fmaf_rn(pw, dx, px);
  float gy = __fmaf_rn(ph, dy, py);
  float x1 = fminf(fmaxf(__fmaf_rn(gw, -0.5f, gx), 0.0f), 512.0f);
  float y1 = fminf(fmaxf(__fmaf_rn(gh, -0.5f, gy), 0.0f), 512.0f);
  float x2 = fminf(fmaxf(__fmaf_rn(gw,  0.5f, gx), 0.0f), 512.0f);
  float y2 = fminf(fmaxf(__fmaf_rn(gh,  0.5f, gy), 0.0f), 512.0f);
  bool valid = (__fsub_rn(x2, x1) > 0.0f) && (__fsub_rn(y2, y1) > 0.0f);
  int pos = img * M_TOT + LV_OFF[lvl] + (int)rank;
  cand_box[(size_t)pos * 4 + 0] = x1;
  cand_box[(size_t)pos * 4 + 1] = y1;
  cand_box[(size_t)pos * 4 + 2] = x2;
  cand_box[(size_t)pos * 4 + 3] = y2;
  float score = __uint_as_float(ubits);
  cand_s[pos] = valid ? score : -1.0f;
  if (valid)
    atomicOr(&vflags[(size_t)il * 32 + (rank >> 6)], 1ULL << (rank & 63));
}

// ================= K1d: partition (valids first) + NMS-order arrays ==========
__global__ __launch_bounds__(256) void k_part(const float* cand_box,
    const float* cand_s, const unsigned long long* vflags,
    float* n_x1, float* n_y1, float* n_x2, float* n_y2, float* n_ar,
    float* n_sc, unsigned* n_pos, unsigned* V_arr) {
  const int il = (int)blockIdx.x;
  const int img = il / 5, lvl = il % 5;
  const int K = LV_K[lvl];
  const int tid = (int)threadIdx.x;
  __shared__ unsigned long long sflag[32];
  __shared__ unsigned wpre[33];
  if (tid < 32) sflag[tid] = vflags[(size_t)il * 32 + tid];
  __syncthreads();
  if (tid < 32) {
    unsigned c = (unsigned)__popcll(sflag[tid]);
    #pragma unroll
    for (int off = 1; off < 32; off <<= 1) {
      unsigned t = __shfl_up(c, off);
      if (tid >= off) c += t;
    }
    wpre[tid + 1] = c;
    if (tid == 0) wpre[0] = 0;
  }
  __syncthreads();
  const unsigned V = wpre[32];
  const float offv = __fmul_rn((float)lvl, 513.0f);
  const int base = img * M_TOT + LV_OFF[lvl];
  for (int r = tid; r < K; r += 256) {
    unsigned long long word = sflag[r >> 6];
    unsigned fl = (unsigned)((word >> (r & 63)) & 1ULL);
    unsigned excl = wpre[r >> 6] +
                    (unsigned)__popcll(word & ((1ULL << (r & 63)) - 1ULL));
    unsigned pdst = fl ? excl : V + ((unsigned)r - excl);
    const float* b = cand_box + (size_t)(base + r) * 4;
    float ox1 = __fadd_rn(b[0], offv), oy1 = __fadd_rn(b[1], offv);
    float ox2 = __fadd_rn(b[2], offv), oy2 = __fadd_rn(b[3], offv);
    int dst = base + (int)pdst;
    n_x1[dst] = ox1; n_y1[dst] = oy1; n_x2[dst] = ox2; n_y2[dst] = oy2;
    n_ar[dst] = __fmul_rn(__fsub_rn(ox2, ox1), __fsub_rn(oy2, oy1));
    n_sc[dst] = cand_s[base + r];
    n_pos[dst] = (unsigned)(LV_OFF[lvl] + r);
  }
  if (tid == 0) V_arr[il] = V;
}

// ================= K2a: suppression bit-matrix build =========================
__global__ __launch_bounds__(256) void k_mask(
    const float* n_x1, const float* n_y1, const float* n_x2, const float* n_y2,
    const float* n_ar, unsigned long long* mask) {
  const int img = blockIdx.y;
  const int bx = blockIdx.x;
  int lvl = 0;
  while (bx >= MB_BASE[lvl + 1]) ++lvl;
  const int t = bx - MB_BASE[lvl];
  const int ct = MB_CT[lvl];
  const int rt = t / ct, c = t % ct;
  const int K = LV_K[lvl];
  const int row0 = rt * 64, col0 = c * 256;
  if (col0 + 255 <= row0) return;  // entire tile has j <= r: bits never consumed

  __shared__ float4 cb4[256];
  __shared__ float cba[256];
  __shared__ float4 rb4[64];
  __shared__ float rba[64];
  const int base = img * M_TOT + LV_OFF[lvl];
  const int tid = (int)threadIdx.x;
  if (tid < 64) {
    int r = row0 + tid;
    if (r < K) {
      rb4[tid] = make_float4(n_x1[base + r], n_y1[base + r],
                             n_x2[base + r], n_y2[base + r]);
      rba[tid] = n_ar[base + r];
    }
  }
  {
    int j = col0 + tid;
    if (j < K) {
      cb4[tid] = make_float4(n_x1[base + j], n_y1[base + j],
                             n_x2[base + j], n_y2[base + j]);
      cba[tid] = n_ar[base + j];
    }
  }
  __syncthreads();
  const int wl = tid >> 6, rl = tid & 63;
  const int r = row0 + rl;
  if (r >= K) return;
  const float4 rb = rb4[rl];
  const float rar = rba[rl];
  unsigned long long word = 0ULL;
  const int jbase = wl * 64;
  const int jmax = K - col0 - jbase;   // bit k valid iff k < jmax
  #pragma unroll 16
  for (int k = 0; k < 64; ++k) {
    float4 cb = cb4[jbase + k];        // broadcast: all lanes same address
    float car = cba[jbase + k];
    float iw = fmaxf(__fsub_rn(fminf(rb.z, cb.z), fmaxf(rb.x, cb.x)), 0.0f);
    float ih = fmaxf(__fsub_rn(fminf(rb.w, cb.w), fmaxf(rb.y, cb.y)), 0.0f);
    float inter = __fmul_rn(iw, ih);
    float uni = __fsub_rn(__fadd_rn(rar, car), inter);
    float iou = (uni > 0.0f) ? __fdiv_rn(inter, uni) : 0.0f;
    if (iou > 0.7f && k < jmax) word |= (1ULL << k);
  }
  mask[(size_t)img * MWORDS_PER_IMG + MOFF[lvl] +
       (size_t)r * WPL[lvl] + (size_t)((col0 >> 6) + wl)] = word;
}

// ================= K2b: chunked greedy scan, LDS double-buffered rows =========
// No >16-element register arrays (they get scratch-demoted): next chunk's 64
// row-words stage into LDS buf[2] while current chunk computes.
#define TSTAGE(S, M)                                                        \
  {                                                                         \
    unsigned long long t_ = __shfl_xor(x, S);                               \
    x = (lane & S) ? ((x & (M)) | ((t_ >> S) & ~(M)))                       \
                   : ((x & ~(M)) | ((t_ << S) & (M)));                      \
  }

__global__ __launch_bounds__(64) void k_scan(const unsigned long long* mask,
    const unsigned* n_pos, const float* n_sc, const unsigned* V_arr,
    unsigned* kept_pos, unsigned long long* kept_key, unsigned* kept_cnt) {
  const int blk = blockIdx.x;
  const int img = blk / 5, lvl = blk % 5;
  const int K = LV_K[lvl], wpl = WPL[lvl];
  const int lane = (int)threadIdx.x;
  const unsigned long long* mb =
      mask + (size_t)img * MWORDS_PER_IMG + MOFF[lvl];
  const int ln = lane < wpl ? lane : 0;  // clamped word (dup loads/writes ok)

  __shared__ unsigned long long buf[2][64][32];
  __shared__ unsigned skept[MAX_OUT + 64];

  const int V = (int)V_arr[img * 5 + lvl];
  unsigned long long alive = 0ULL;
  if (lane < wpl) {
    int lo = lane * 64, hi = V < lo + 64 ? V : lo + 64;
    if (hi > lo) alive = (hi - lo == 64) ? ~0ULL : ((1ULL << (hi - lo)) - 1ULL);
  }
  const unsigned long long below = (1ULL << lane) - 1ULL;

  // preload chunk 0 rows + diag
  #pragma unroll
  for (int d = 0; d < 64; ++d) buf[0][d][ln] = mb[(size_t)d * wpl + ln];
  unsigned long long dnext = mb[(size_t)lane * wpl];

  int kept = 0;
  const int nchunks = (K + 63) >> 6;
  for (int c = 0; c < nchunks; ++c) {
    const int r0 = c << 6;
    const int cur = c & 1;
    // stage next chunk's rows (padded region -> always in-bounds)
    #pragma unroll
    for (int d = 0; d < 64; ++d)
      buf[cur ^ 1][d][ln] = mb[(size_t)(r0 + 64 + d) * wpl + ln];

    // transpose: lane j <- column j of the 64x64 diag block
    unsigned long long x = dnext;
    TSTAGE(32, 0xFFFFFFFF00000000ULL)
    TSTAGE(16, 0xFFFF0000FFFF0000ULL)
    TSTAGE(8,  0xFF00FF00FF00FF00ULL)
    TSTAGE(4,  0xF0F0F0F0F0F0F0F0ULL)
    TSTAGE(2,  0xCCCCCCCCCCCCCCCCULL)
    TSTAGE(1,  0xAAAAAAAAAAAAAAAAULL)
    dnext = mb[(size_t)(r0 + 64 + lane) * wpl + (c + 1)];

    // in-chunk greedy fixpoint (exact greedy, unique fixpoint)
    unsigned long long aw = __shfl(alive, c);
    unsigned long long kw = aw;
    while (true) {
      bool keep_j = (((aw >> lane) & 1ULL) != 0ULL) &&
                    ((kw & below & x) == 0ULL);
      unsigned long long nkw = __ballot(keep_j);
      if (nkw == kw) break;
      kw = nkw;
    }

    // record kept rows (parallel popcount-prefix)
    if ((kw >> lane) & 1ULL) {
      int idx = kept + (int)__popcll(kw & below);
      skept[idx] = (unsigned)(r0 + lane);
    }
    kept += (int)__popcll(kw);

    // cross-chunk suppression from LDS (branchless)
    #pragma unroll
    for (int d = 0; d < 64; ++d) {
      unsigned long long m =
          (unsigned long long)((long long)(kw << (63 - d)) >> 63);
      alive &= ~(buf[cur][d][ln] & m);
    }
    if (kept >= MAX_OUT) break;   // overshoot <=64 buffered; truncated below
  }
  if (kept > MAX_OUT) kept = MAX_OUT;
  __syncthreads();
  const int base = img * M_TOT + LV_OFF[lvl];
  const size_t bo = (size_t)(img * 5 + lvl) * 1024;
  for (int i = lane; i < kept; i += 64) {
    unsigned r = skept[i];
    unsigned pp = n_pos[base + (int)r];
    kept_pos[bo + i] = pp;
    kept_key[bo + i] =
        ((unsigned long long)__float_as_uint(n_sc[base + (int)r]) << 32) |
        (unsigned)(~pp);
  }
  if (lane == 0) kept_cnt[img * 5 + lvl] = (unsigned)kept;
}

// ================= K3: per-image merge of kept lists -> output rows ===========
__global__ __launch_bounds__(1024) void k_merge(const float* cand_box,
    const float* cand_s, const unsigned* kept_pos,
    const unsigned long long* kept_key, const unsigned* kept_cnt, float* out) {
  const int img = blockIdx.x;
  const int tid = (int)threadIdx.x;
  __shared__ unsigned cnts[5];
  __shared__ unsigned long long skey[5][1024];
  if (tid < 5) {
    unsigned c = kept_cnt[img * 5 + tid];
    cnts[tid] = c < (unsigned)MAX_OUT ? c : (unsigned)MAX_OUT;
  }
  __syncthreads();
  for (int e = tid; e < 5 * 1024; e += 1024) {
    int l = e >> 10, s = e & 1023;
    skey[l][s] = (s < (int)cnts[l])
        ? kept_key[(size_t)(img * 5 + l) * 1024 + s] : 0ULL;
  }
  __syncthreads();
  unsigned T = cnts[0] + cnts[1] + cnts[2] + cnts[3] + cnts[4];
  unsigned Tc = T < (unsigned)MAX_OUT ? T : (unsigned)MAX_OUT;
  for (int r = (int)Tc + tid; r < MAX_OUT; r += 1024) {
    float* o = out + (size_t)img * (MAX_OUT * 5) + (size_t)r * 5;
    o[0] = 0.f; o[1] = 0.f; o[2] = 0.f; o[3] = 0.f; o[4] = 0.f;
  }
  for (int e = tid; e < 5 * 1024; e += 1024) {
    int l = e >> 10, s = e & 1023;
    if (s >= (int)cnts[l]) continue;
    unsigned long long k0 = skey[l][s];
    unsigned rank = (unsigned)s;
    #pragma unroll
    for (int l2 = 0; l2 < 5; ++l2) {
      if (l2 == l) continue;
      int lo = 0, hi = (int)cnts[l2];
      while (lo < hi) {
        int mid = (lo + hi) >> 1;
        if (skey[l2][mid] > k0) lo = mid + 1; else hi = mid;
      }
      rank += (unsigned)lo;
    }
    if (rank < (unsigned)MAX_OUT) {
      unsigned pos = kept_pos[(size_t)(img * 5 + l) * 1024 + s];
      const float* b = cand_box + (size_t)(img * M_TOT + pos) * 4;
      float* o = out + (size_t)img * (MAX_OUT * 5) + (size_t)rank * 5;
      o[0] = b[0]; o[1] = b[1]; o[2] = b[2]; o[3] = b[3];
      o[4] = cand_s[img * M_TOT + pos];
    }
  }
}

// ================= host launch =================
extern "C" void kernel_launch(void* const* d_in, const int* in_sizes, int n_in,
                              void* d_out, int out_size, void* d_ws, size_t ws_size,
                              hipStream_t stream) {
  Ptrs p;
  bool interleaved = (n_in == 10 && in_sizes[1] == 4 * 12 * 128 * 128);
  for (int l = 0; l < 5; ++l) {
    if (interleaved) {
      p.cls[l] = (const float*)d_in[2 * l];
      p.reg[l] = (const float*)d_in[2 * l + 1];
    } else {
      p.cls[l] = (const float*)d_in[l];
      p.reg[l] = (const float*)d_in[5 + l];
    }
  }
  uint8_t* w = (uint8_t*)d_ws;
  size_t o = 0;
  auto carve = [&](size_t bytes) {
    void* ptr = w + o;
    o += (bytes + 255) & ~(size_t)255;
    return ptr;
  };
  // gcnt + ghist + vflags adjacent -> one memset zeroes all three
  unsigned* gcnt = (unsigned*)carve((size_t)20 * 4);                 // 256B slot
  unsigned* ghist = (unsigned*)carve((size_t)20 * 4096 * 4);
  unsigned long long* vflags = (unsigned long long*)carve((size_t)20 * 32 * 8);
  size_t zero_bytes = 256 + (size_t)20 * 4096 * 4 + (size_t)20 * 32 * 8;
  unsigned long long* T64_arr = (unsigned long long*)carve((size_t)20 * 8);
  unsigned* u_arr = (unsigned*)carve((size_t)4 * U_PER_IMG * 4);
  float* cand_box = (float*)carve((size_t)4 * M_TOT * 4 * 4);
  float* cand_s = (float*)carve((size_t)4 * M_TOT * 4);
  float* n_x1 = (float*)carve((size_t)4 * M_TOT * 4);
  float* n_y1 = (float*)carve((size_t)4 * M_TOT * 4);
  float* n_x2 = (float*)carve((size_t)4 * M_TOT * 4);
  float* n_y2 = (float*)carve((size_t)4 * M_TOT * 4);
  float* n_ar = (float*)carve((size_t)4 * M_TOT * 4);
  float* n_sc = (float*)carve((size_t)4 * M_TOT * 4);
  unsigned* n_pos = (unsigned*)carve((size_t)4 * M_TOT * 4);
  unsigned* V_arr = (unsigned*)carve((size_t)20 * 4);
  unsigned* kept_pos = (unsigned*)carve((size_t)4 * 5 * 1024 * 4);
  unsigned long long* kept_key = (unsigned long long*)carve((size_t)4 * 5 * 1024 * 8);
  unsigned* kept_cnt = (unsigned*)carve((size_t)20 * 4);
  unsigned long long* mask = (unsigned long long*)carve((size_t)4 * MWORDS_PER_IMG * 8);
  // gtk (20*4096 u64 = 640KB) aliases mask: dead before k_mask writes it.
  unsigned long long* gtk = mask;
  (void)ws_size; (void)out_size;

  hipMemsetAsync(gcnt, 0, zero_bytes, stream);
  k_sig<<<dim3(18, 4), 1024, 0, stream>>>(p, u_arr, ghist);
  k_thresh<<<20, 1024, 0, stream>>>(u_arr, ghist, T64_arr);
  k_collect<<<dim3(18, 4), 1024, 0, stream>>>(u_arr, T64_arr, gtk, gcnt);
  k_rank<<<dim3(16, 20), 256, 0, stream>>>(p, gtk, gcnt, cand_box, cand_s,
                                           vflags);
  k_part<<<20, 256, 0, stream>>>(cand_box, cand_s, vflags,
      n_x1, n_y1, n_x2, n_y2, n_ar, n_sc, n_pos, V_arr);
  k_mask<<<dim3(807, 4), 256, 0, stream>>>(n_x1, n_y1, n_x2, n_y2, n_ar, mask);
  k_scan<<<20, 64, 0, stream>>>(mask, n_pos, n_sc, V_arr,
                                kept_pos, kept_key, kept_cnt);
  k_merge<<<4, 1024, 0, stream>>>(cand_box, cand_s, kept_pos, kept_key,
                                  kept_cnt, (float*)d_out);
}

// Round 10
// 193.135 us; speedup vs baseline: 1.2544x; 1.2544x over previous
//
#include <hip/hip_runtime.h>
#include <cstdint>
#include <cstddef>

// ---------------- constants ----------------
__constant__ int LV_N[5]    = {49152, 12288, 3072, 768, 192};   // H*W*3
__constant__ int LV_K[5]    = {2000, 2000, 2000, 768, 192};     // min(PRE_NMS, N)
__constant__ int LV_OFF[5]  = {0, 2000, 4000, 6000, 6768};      // concat offsets
__constant__ int LV_UOFF[5] = {0, 49152, 61440, 64512, 65280};  // u-array offsets
__constant__ int LV_W[5]    = {128, 64, 32, 16, 8};
__constant__ int LV_S[5]    = {4, 8, 16, 32, 64};
__constant__ int LV_LOGHW[5]= {14, 12, 10, 8, 6};
// mask geometry (rows padded by 192 so scan prefetch needs no bounds tests)
__constant__ int WPL[5]     = {32, 32, 32, 12, 3};              // words per row
__constant__ int MOFF[5]    = {0, 70144, 140288, 210432, 221952};
__constant__ int MB_BASE[6] = {0, 256, 512, 768, 804, 807};     // mask-block bases
__constant__ int MB_CT[5]   = {8, 8, 8, 3, 1};                  // col tiles per lvl
__constant__ int SGB6[6]    = {0, 12, 15, 16, 17, 18};          // 4096-elem tile bases

#define M_TOT 6960
#define U_PER_IMG 65472
#define MAX_OUT 1000
#define MWORDS_PER_IMG 223104
#define CAP 4096

struct Ptrs { const float* cls[5]; const float* reg[5]; };

// ---------------- XLA:CPU-compatible expf (Cephes/Eigen pexp, FMA-contracted) ----
__device__ __forceinline__ float xla_expf(float x) {
  const float exp_hi = 88.3762626647950f;
  const float exp_lo = -88.3762626647949f;
  const float log2ef = 1.44269504088896341f;
  const float c1 = 0.693359375f;
  const float c2 = -2.12194440e-4f;
  const float p0 = 1.9875691500e-4f;
  const float p1 = 1.3981999507e-3f;
  const float p2 = 8.3334519073e-3f;
  const float p3 = 4.1665795894e-2f;
  const float p4 = 1.6666665459e-1f;
  const float p5 = 5.0000001201e-1f;
  float xx = fminf(fmaxf(x, exp_lo), exp_hi);
  float fx = floorf(__fmaf_rn(xx, log2ef, 0.5f));
  float r = __fmaf_rn(fx, -c1, xx);
  r = __fmaf_rn(fx, -c2, r);
  float z = __fmul_rn(r, r);
  float y = __fmaf_rn(p0, r, p1);
  y = __fmaf_rn(y, r, p2);
  y = __fmaf_rn(y, r, p3);
  y = __fmaf_rn(y, r, p4);
  y = __fmaf_rn(y, r, p5);
  y = __fmaf_rn(y, z, r);
  y = __fadd_rn(y, 1.0f);
  int n = (int)fx;
  float two_n = __uint_as_float((unsigned)(n + 127) << 23);
  return __fmul_rn(y, two_n);
}

__device__ __forceinline__ float ref_sigmoid(float x) {
  return __fdiv_rn(1.0f, __fadd_rn(1.0f, xla_expf(-x)));
}

// ================= K0: wide sigmoid + 4096-bin score-bit histogram ============
__global__ __launch_bounds__(1024) void k_sig(Ptrs p, unsigned* u_arr,
                                              unsigned* ghist) {
  const int img = blockIdx.y;
  const int bx = blockIdx.x;
  int lvl = 0;
  while (bx >= SGB6[lvl + 1]) ++lvl;
  const int N = LV_N[lvl], LOGHW = LV_LOGHW[lvl];
  const int HW = 1 << LOGHW;
  const int e0 = (bx - SGB6[lvl]) * 4096;
  const int e1 = (e0 + 4096 < N) ? e0 + 4096 : N;
  const int tid = (int)threadIdx.x;
  __shared__ unsigned h[4096];
  for (int e = tid; e < 4096; e += 1024) h[e] = 0;
  __syncthreads();
  const float* cls = p.cls[lvl] + (size_t)img * N;
  unsigned* u = u_arr + img * U_PER_IMG + LV_UOFF[lvl];
  for (int e = e0 + tid; e < e1; e += 1024) {
    float logit = cls[e];                  // plane-major: fully coalesced
    unsigned ub = __float_as_uint(ref_sigmoid(logit));
    int a = e >> LOGHW, pix = e & (HW - 1);
    u[pix * 3 + a] = ub;                   // channel-last (reference order)
    atomicAdd(&h[(ub >> 18) & 4095u], 1u);
  }
  __syncthreads();
  unsigned* gh = ghist + (size_t)(img * 5 + lvl) * 4096;
  for (int e = tid; e < 4096; e += 1024)
    if (h[e]) atomicAdd(&gh[e], h[e]);
}

// ================= K1a: threshold pick (O(bins), N-scan only on fallback) =====
__global__ __launch_bounds__(1024) void k_thresh(const unsigned* u_arr,
    const unsigned* ghist, unsigned long long* T64_arr) {
  const int blk = blockIdx.x;
  const int img = blk / 5, lvl = blk % 5;
  const int N = LV_N[lvl], K = LV_K[lvl];
  const int tid = (int)threadIdx.x;
  if (N <= K) { if (tid == 0) T64_arr[blk] = 0ULL; return; }
  __shared__ unsigned h[4096], sA[4096], sB[4096];
  __shared__ unsigned sh_D, sh_sD, sh_sD1;
  const unsigned* u = u_arr + img * U_PER_IMG + LV_UOFF[lvl];

  for (int e = tid; e < 4096; e += 1024)
    h[e] = ghist[(size_t)blk * 4096 + e];
  __syncthreads();

  unsigned long long prefix = 0;
  unsigned want = (unsigned)K, above = 0;
  const int shifts[6] = {50, 38, 26, 14, 2, 0};
  const int widths[6] = {12, 12, 12, 12, 12, 2};
  for (int rd = 0; rd < 6; ++rd) {
    const int shift = shifts[rd], width = widths[rd];
    const int nb = 1 << width;
    if (rd > 0) {                          // fallback: exact rescan (rare)
      for (int e = tid; e < nb; e += 1024) h[e] = 0;
      __syncthreads();
      for (int i = tid; i < N; i += 1024) {
        unsigned long long key =
            ((unsigned long long)u[i] << 32) | (unsigned)(~(unsigned)i);
        if ((key >> (shift + width)) == prefix)
          atomicAdd(&h[(unsigned)(key >> shift) & (unsigned)(nb - 1)], 1u);
      }
      __syncthreads();
    }
    // suffix scan s[d] = sum_{v>=d} h[v]
    unsigned *Ap = sA, *Bp = sB;
    for (int e = tid; e < nb; e += 1024) Ap[e] = h[e];
    __syncthreads();
    for (int off = 1; off < nb; off <<= 1) {
      for (int e = tid; e < nb; e += 1024)
        Bp[e] = Ap[e] + ((e + off < nb) ? Ap[e + off] : 0u);
      __syncthreads();
      unsigned* t = Ap; Ap = Bp; Bp = t;
    }
    for (int e = tid; e < nb; e += 1024) {
      unsigned s = Ap[e], sn = (e + 1 < nb) ? Ap[e + 1] : 0u;
      if (s >= want && sn < want) { sh_D = (unsigned)e; sh_sD = s; sh_sD1 = sn; }
    }
    __syncthreads();
    unsigned D = sh_D, sD = sh_sD, sD1 = sh_sD1;
    unsigned long long npref = (prefix << width) | (unsigned long long)D;
    if (above + sD <= (unsigned)CAP || rd == 5) {
      if (tid == 0) T64_arr[blk] = npref << shift;
      return;                              // uniform decision across block
    }
    above += sD1; want -= sD1; prefix = npref;
    __syncthreads();
  }
}

// ================= K1b: wide collect of keys >= T64 (unordered) ==============
__global__ __launch_bounds__(1024) void k_collect(const unsigned* u_arr,
    const unsigned long long* T64_arr, unsigned long long* gtk, unsigned* gcnt) {
  const int img = blockIdx.y;
  const int bx = blockIdx.x;
  int lvl = 0;
  while (bx >= SGB6[lvl + 1]) ++lvl;
  const int N = LV_N[lvl];
  const int e0 = (bx - SGB6[lvl]) * 4096;
  const int e1 = (e0 + 4096 < N) ? e0 + 4096 : N;
  const int tid = (int)threadIdx.x;
  const int lane = tid & 63;
  const unsigned long long T = T64_arr[img * 5 + lvl];
  const unsigned* u = u_arr + img * U_PER_IMG + LV_UOFF[lvl];
  unsigned long long* dst = gtk + (size_t)(img * 5 + lvl) * CAP;
  unsigned* cnt = gcnt + (img * 5 + lvl);
  for (int e = e0 + tid; e < e1; e += 1024) {
    unsigned long long key =
        ((unsigned long long)u[e] << 32) | (unsigned)(~(unsigned)e);
    bool pred = key >= T;
    unsigned long long bm = __ballot(pred);
    if (bm) {
      int leader = __ffsll((long long)bm) - 1;
      unsigned sbase = 0;
      if (lane == leader) sbase = atomicAdd(cnt, (unsigned)__popcll(bm));
      sbase = __shfl(sbase, leader);
      if (pred) {
        unsigned slot = sbase + (unsigned)__popcll(bm & ((1ULL << lane) - 1ULL));
        if (slot < (unsigned)CAP) dst[slot] = key;
      }
    }
  }
}

// ================= K1c: brute-force rank + direct decode (no sort) ===========
__global__ __launch_bounds__(256) void k_rank(Ptrs p,
    const unsigned long long* gtk, const unsigned* gcnt,
    float* cand_box, float* cand_s, unsigned long long* vflags) {
  const int il = (int)blockIdx.y;
  const int img = il / 5, lvl = il % 5;
  const int N = LV_N[lvl], K = LV_K[lvl], W = LV_W[lvl], S = LV_S[lvl];
  const int HW = N / 3;
  const float* reg = p.reg[lvl] + (size_t)img * 12 * HW;
  const int tid = (int)threadIdx.x;
  unsigned cnt = gcnt[il];
  if (cnt > (unsigned)CAP) cnt = CAP;
  const unsigned cnt8 = (cnt + 7u) & ~7u;
  __shared__ unsigned long long keys[CAP];
  const unsigned long long* src = gtk + (size_t)il * CAP;
  for (int e = tid; e < (int)cnt8; e += 256)
    keys[e] = (e < (int)cnt) ? src[e] : 0ULL;   // real keys >= 2^32 > 0 pad
  __syncthreads();
  const int s = (int)blockIdx.x * 256 + tid;
  if (s >= (int)cnt) return;
  const unsigned long long mykey = keys[s];
  unsigned rank = 0;
  #pragma unroll 8
  for (unsigned j = 0; j < cnt8; ++j)
    rank += (keys[j] > mykey) ? 1u : 0u;        // broadcast read, conflict-free
  if (rank >= (unsigned)K) return;

  unsigned ubits = (unsigned)(mykey >> 32);
  unsigned idx = ~((unsigned)mykey);
  int a = (int)(idx % 3u); int pix = (int)(idx / 3u);
  int xq = pix % W, yq = pix / W;
  float dx = reg[(a * 4 + 0) * HW + pix];
  float dy = reg[(a * 4 + 1) * HW + pix];
  float dw = reg[(a * 4 + 2) * HW + pix];
  float dh = reg[(a * 4 + 3) * HW + pix];
  double rr = (a == 0) ? 0.5 : (a == 1 ? 1.0 : 2.0);
  double hr = sqrt(rr), wr = 1.0 / hr;
  double st = (double)S;
  double wsd = st * wr * 8.0, hsd = st * hr * 8.0;
  double sxd = (double)(xq * S), syd = (double)(yq * S);
  float a0 = (float)(sxd - 0.5 * wsd), a1 = (float)(syd - 0.5 * hsd);
  float a2 = (float)(sxd + 0.5 * wsd), a3 = (float)(syd + 0.5 * hsd);
  float px = __fmul_rn(__fadd_rn(a0, a2), 0.5f);
  float py = __fmul_rn(__fadd_rn(a1, a3), 0.5f);
  float pw = __fsub_rn(a2, a0), ph = __fsub_rn(a3, a1);
  const float MRf = 4.135166556742356f;  // |log(16/1000)| rounded to f32
  float dwc = fminf(fmaxf(dw, -MRf), MRf);
  float dhc = fminf(fmaxf(dh, -MRf), MRf);
  float gw = __fmul_rn(pw, xla_expf(dwc));
  float gh = __fmul_rn(ph, xla_expf(dhc));
  float gx = __fmaf_rn(pw, dx, px);
  float gy = __fmaf_rn(ph, dy, py);
  float x1 = fminf(fmaxf(__fmaf_rn(gw, -0.5f, gx), 0.0f), 512.0f);
  float y1 = fminf(fmaxf(__fmaf_rn(gh, -0.5f, gy), 0.0f), 512.0f);
  float x2 = fminf(fmaxf(__fmaf_rn(gw,  0.5f, gx), 0.0f), 512.0f);
  float y2 = fminf(fmaxf(__fmaf_rn(gh,  0.5f, gy), 0.0f), 512.0f);
  bool valid = (__fsub_rn(x2, x1) > 0.0f) && (__fsub_rn(y2, y1) > 0.0f);
  int pos = img * M_TOT + LV_OFF[lvl] + (int)rank;
  cand_box[(size_t)pos * 4 + 0] = x1;
  cand_box[(size_t)pos * 4 + 1] = y1;
  cand_box[(size_t)pos * 4 + 2] = x2;
  cand_box[(size_t)pos * 4 + 3] = y2;
  float score = __uint_as_float(ubits);
  cand_s[pos] = valid ? score : -1.0f;
  if (valid)
    atomicOr(&vflags[(size_t)il * 32 + (rank >> 6)], 1ULL << (rank & 63));
}

// ================= K1d: partition (valids first) + NMS-order arrays ==========
__global__ __launch_bounds__(256) void k_part(const float* cand_box,
    const float* cand_s, const unsigned long long* vflags,
    float* n_x1, float* n_y1, float* n_x2, float* n_y2, float* n_ar,
    float* n_sc, unsigned* n_pos, unsigned* V_arr) {
  const int il = (int)blockIdx.x;
  const int img = il / 5, lvl = il % 5;
  const int K = LV_K[lvl];
  const int tid = (int)threadIdx.x;
  __shared__ unsigned long long sflag[32];
  __shared__ unsigned wpre[33];
  if (tid < 32) sflag[tid] = vflags[(size_t)il * 32 + tid];
  __syncthreads();
  if (tid < 32) {
    unsigned c = (unsigned)__popcll(sflag[tid]);
    #pragma unroll
    for (int off = 1; off < 32; off <<= 1) {
      unsigned t = __shfl_up(c, off);
      if (tid >= off) c += t;
    }
    wpre[tid + 1] = c;
    if (tid == 0) wpre[0] = 0;
  }
  __syncthreads();
  const unsigned V = wpre[32];
  const float offv = __fmul_rn((float)lvl, 513.0f);
  const int base = img * M_TOT + LV_OFF[lvl];
  for (int r = tid; r < K; r += 256) {
    unsigned long long word = sflag[r >> 6];
    unsigned fl = (unsigned)((word >> (r & 63)) & 1ULL);
    unsigned excl = wpre[r >> 6] +
                    (unsigned)__popcll(word & ((1ULL << (r & 63)) - 1ULL));
    unsigned pdst = fl ? excl : V + ((unsigned)r - excl);
    const float* b = cand_box + (size_t)(base + r) * 4;
    float ox1 = __fadd_rn(b[0], offv), oy1 = __fadd_rn(b[1], offv);
    float ox2 = __fadd_rn(b[2], offv), oy2 = __fadd_rn(b[3], offv);
    int dst = base + (int)pdst;
    n_x1[dst] = ox1; n_y1[dst] = oy1; n_x2[dst] = ox2; n_y2[dst] = oy2;
    n_ar[dst] = __fmul_rn(__fsub_rn(ox2, ox1), __fsub_rn(oy2, oy1));
    n_sc[dst] = cand_s[base + r];
    n_pos[dst] = (unsigned)(LV_OFF[lvl] + r);
  }
  if (tid == 0) V_arr[il] = V;
}

// ================= K2a: suppression bit-matrix build + diag transpose ========
#define TSTAGE(S, M)                                                        \
  {                                                                         \
    unsigned long long t_ = __shfl_xor(x, S);                               \
    x = (lane & S) ? ((x & (M)) | ((t_ >> S) & ~(M)))                       \
                   : ((x & ~(M)) | ((t_ << S) & (M)));                      \
  }

__global__ __launch_bounds__(256) void k_mask(
    const float* n_x1, const float* n_y1, const float* n_x2, const float* n_y2,
    const float* n_ar, unsigned long long* mask, unsigned long long* diagT) {
  const int img = blockIdx.y;
  const int bx = blockIdx.x;
  int lvl = 0;
  while (bx >= MB_BASE[lvl + 1]) ++lvl;
  const int t = bx - MB_BASE[lvl];
  const int ct = MB_CT[lvl];
  const int rt = t / ct, c = t % ct;
  const int K = LV_K[lvl];
  const int row0 = rt * 64, col0 = c * 256;
  if (col0 + 255 <= row0) return;  // entire tile has j <= r: bits never consumed

  __shared__ float4 cb4[256];
  __shared__ float cba[256];
  __shared__ float4 rb4[64];
  __shared__ float rba[64];
  const int base = img * M_TOT + LV_OFF[lvl];
  const int tid = (int)threadIdx.x;
  if (tid < 64) {
    int r = row0 + tid;
    if (r < K) {
      rb4[tid] = make_float4(n_x1[base + r], n_y1[base + r],
                             n_x2[base + r], n_y2[base + r]);
      rba[tid] = n_ar[base + r];
    } else {
      rb4[tid] = make_float4(0.f, 0.f, 0.f, 0.f);
      rba[tid] = 0.f;
    }
  }
  {
    int j = col0 + tid;
    if (j < K) {
      cb4[tid] = make_float4(n_x1[base + j], n_y1[base + j],
                             n_x2[base + j], n_y2[base + j]);
      cba[tid] = n_ar[base + j];
    }
  }
  __syncthreads();
  const int wl = tid >> 6, lane = tid & 63;
  const int r = row0 + lane;
  const bool rvalid = (r < K);
  const float4 rb = rb4[lane];
  const float rar = rba[lane];
  unsigned long long word = 0ULL;
  const int jbase = wl * 64;
  const int jmax = K - col0 - jbase;   // bit k valid iff k < jmax
  #pragma unroll 16
  for (int k = 0; k < 64; ++k) {
    float4 cb = cb4[jbase + k];        // broadcast: all lanes same address
    float car = cba[jbase + k];
    float iw = fmaxf(__fsub_rn(fminf(rb.z, cb.z), fmaxf(rb.x, cb.x)), 0.0f);
    float ih = fmaxf(__fsub_rn(fminf(rb.w, cb.w), fmaxf(rb.y, cb.y)), 0.0f);
    float inter = __fmul_rn(iw, ih);
    float uni = __fsub_rn(__fadd_rn(rar, car), inter);
    float iou = (uni > 0.0f) ? __fdiv_rn(inter, uni) : 0.0f;
    if (iou > 0.7f && k < jmax) word |= (1ULL << k);
  }
  if (!rvalid) word = 0ULL;
  if (rvalid)
    mask[(size_t)img * MWORDS_PER_IMG + MOFF[lvl] +
         (size_t)r * WPL[lvl] + (size_t)((col0 >> 6) + wl)] = word;
  // diag 64x64 block of this chunk lives in word wl where col0+64*wl == row0:
  // transpose it across lanes (lane i -> column i) and store to diagT.
  if (col0 + (wl << 6) == row0) {
    unsigned long long x = word;
    TSTAGE(32, 0xFFFFFFFF00000000ULL)
    TSTAGE(16, 0xFFFF0000FFFF0000ULL)
    TSTAGE(8,  0xFF00FF00FF00FF00ULL)
    TSTAGE(4,  0xF0F0F0F0F0F0F0F0ULL)
    TSTAGE(2,  0xCCCCCCCCCCCCCCCCULL)
    TSTAGE(1,  0xAAAAAAAAAAAAAAAAULL)
    diagT[(size_t)(img * 5 + lvl) * (40 * 64) + (size_t)rt * 64 + lane] = x;
  }
}

// ================= K2b: 8-wave chunked greedy scan ===========================
// Wave w, lane-group g owns alive word wk=w+8g as lazy per-lane partials (16
// partial copies, AND-combined only when word's chunk comes up). Per chunk:
// owner wave materializes word c (shfl-AND reduce), runs ballot fixpoint on
// the precomputed transposed diag (diagT), publishes kw (parity LDS slot,
// ONE barrier/chunk); all waves apply 4 branchless ANDs from 2-chunk-deep
// statically-named prefetch regs.
#define SCAN_CHUNK(P0, P1, P2, P3)                                          \
  {                                                                         \
    const int r0 = c << 6;                                                  \
    if (w == (c & 7)) {                                                     \
      unsigned long long v = (g == (c >> 3)) ? aw : ~0ULL;                  \
      v &= __shfl_xor(v, 1);                                                \
      v &= __shfl_xor(v, 2);                                                \
      v &= __shfl_xor(v, 4);                                                \
      v &= __shfl_xor(v, 8);                                                \
      v = __shfl(v, (c >> 3) * 16);                                         \
      unsigned long long x = dg;                                            \
      unsigned long long kw = v;                                            \
      while (true) {                                                        \
        bool keep_j = (((v >> lane) & 1ULL) != 0ULL) &&                     \
                      ((kw & below & x) == 0ULL);                           \
        unsigned long long nkw = __ballot(keep_j);                          \
        if (nkw == kw) break;                                               \
        kw = nkw;                                                           \
      }                                                                     \
      if ((kw >> lane) & 1ULL)                                              \
        skept[kept + (int)__popcll(kw & below)] = (unsigned)(r0 + lane);    \
      if (lane == 0) s_kw[c & 1] = kw;                                      \
      int no_ = next_own < 40 ? next_own : 39;                              \
      dg = dT[(size_t)no_ * 64 + lane];                                     \
      next_own += 8;                                                        \
    }                                                                       \
    __syncthreads();                                                        \
    unsigned long long kwv = s_kw[c & 1];                                   \
    kept += (int)__popcll(kwv);                                             \
    aw &= ~(P0 & (unsigned long long)((long long)(kwv << (63 - (d0 + 0))) >> 63)); \
    aw &= ~(P1 & (unsigned long long)((long long)(kwv << (63 - (d0 + 1))) >> 63)); \
    aw &= ~(P2 & (unsigned long long)((long long)(kwv << (63 - (d0 + 2))) >> 63)); \
    aw &= ~(P3 & (unsigned long long)((long long)(kwv << (63 - (d0 + 3))) >> 63)); \
    P0 = mb[(size_t)(r0 + 128 + d0 + 0) * wpl + wkc];                       \
    P1 = mb[(size_t)(r0 + 128 + d0 + 1) * wpl + wkc];                       \
    P2 = mb[(size_t)(r0 + 128 + d0 + 2) * wpl + wkc];                       \
    P3 = mb[(size_t)(r0 + 128 + d0 + 3) * wpl + wkc];                       \
    ++c;                                                                    \
  }

__global__ __launch_bounds__(512) void k_scan(const unsigned long long* mask,
    const unsigned long long* diagT,
    const unsigned* n_pos, const float* n_sc, const unsigned* V_arr,
    unsigned* kept_pos, unsigned long long* kept_key, unsigned* kept_cnt) {
  const int il = (int)blockIdx.x;
  const int img = il / 5, lvl = il % 5;
  const int K = LV_K[lvl], wpl = WPL[lvl];
  const int tid = (int)threadIdx.x;
  const int w = tid >> 6, lane = tid & 63;
  const unsigned long long* mb =
      mask + (size_t)img * MWORDS_PER_IMG + MOFF[lvl];
  const unsigned long long* dT = diagT + (size_t)il * (40 * 64);

  __shared__ unsigned long long s_kw[2];
  __shared__ unsigned skept[MAX_OUT + 64];

  const int g = lane >> 4;
  const int wk = w + 8 * g;
  const int wkc = wk < wpl ? wk : 0;      // clamped (dup loads harmless)
  const int d0 = (lane & 15) * 4;         // my 4 suppression rows per chunk
  const unsigned long long below = (1ULL << lane) - 1ULL;

  const int V = (int)V_arr[il];
  unsigned long long aw;
  {
    int lo = wk * 64, hi = V < lo + 64 ? V : lo + 64;
    aw = (hi > lo) ? ((hi - lo == 64) ? ~0ULL : ((1ULL << (hi - lo)) - 1ULL))
                   : 0ULL;
  }

  const int nchunks = (K + 63) >> 6;
  // preload rows for chunk 0 (pfA*) and chunk 1 (pfB*), diag for first owned
  unsigned long long pfA0 = mb[(size_t)(d0 + 0) * wpl + wkc];
  unsigned long long pfA1 = mb[(size_t)(d0 + 1) * wpl + wkc];
  unsigned long long pfA2 = mb[(size_t)(d0 + 2) * wpl + wkc];
  unsigned long long pfA3 = mb[(size_t)(d0 + 3) * wpl + wkc];
  unsigned long long pfB0 = mb[(size_t)(64 + d0 + 0) * wpl + wkc];
  unsigned long long pfB1 = mb[(size_t)(64 + d0 + 1) * wpl + wkc];
  unsigned long long pfB2 = mb[(size_t)(64 + d0 + 2) * wpl + wkc];
  unsigned long long pfB3 = mb[(size_t)(64 + d0 + 3) * wpl + wkc];
  unsigned long long dg = dT[(size_t)w * 64 + lane];
  int next_own = w + 8;

  int kept = 0;
  int c = 0;
  while (c < nchunks && kept < MAX_OUT) {
    SCAN_CHUNK(pfA0, pfA1, pfA2, pfA3)
    if (c >= nchunks || kept >= MAX_OUT) break;
    SCAN_CHUNK(pfB0, pfB1, pfB2, pfB3)
  }

  __syncthreads();
  const int kc = kept < MAX_OUT ? kept : MAX_OUT;
  const int base = img * M_TOT + LV_OFF[lvl];
  const size_t bo = (size_t)il * 1024;
  for (int i = tid; i < kc; i += 512) {
    unsigned r = skept[i];
    unsigned pp = n_pos[base + (int)r];
    kept_pos[bo + i] = pp;
    kept_key[bo + i] =
        ((unsigned long long)__float_as_uint(n_sc[base + (int)r]) << 32) |
        (unsigned)(~pp);
  }
  if (tid == 0) kept_cnt[il] = (unsigned)kc;
}

// ================= K3: per-image merge of kept lists -> output rows ===========
__global__ __launch_bounds__(1024) void k_merge(const float* cand_box,
    const float* cand_s, const unsigned* kept_pos,
    const unsigned long long* kept_key, const unsigned* kept_cnt, float* out) {
  const int img = blockIdx.x;
  const int tid = (int)threadIdx.x;
  __shared__ unsigned cnts[5];
  __shared__ unsigned long long skey[5][1024];
  if (tid < 5) {
    unsigned c = kept_cnt[img * 5 + tid];
    cnts[tid] = c < (unsigned)MAX_OUT ? c : (unsigned)MAX_OUT;
  }
  __syncthreads();
  for (int e = tid; e < 5 * 1024; e += 1024) {
    int l = e >> 10, s = e & 1023;
    skey[l][s] = (s < (int)cnts[l])
        ? kept_key[(size_t)(img * 5 + l) * 1024 + s] : 0ULL;
  }
  __syncthreads();
  unsigned T = cnts[0] + cnts[1] + cnts[2] + cnts[3] + cnts[4];
  unsigned Tc = T < (unsigned)MAX_OUT ? T : (unsigned)MAX_OUT;
  for (int r = (int)Tc + tid; r < MAX_OUT; r += 1024) {
    float* o = out + (size_t)img * (MAX_OUT * 5) + (size_t)r * 5;
    o[0] = 0.f; o[1] = 0.f; o[2] = 0.f; o[3] = 0.f; o[4] = 0.f;
  }
  for (int e = tid; e < 5 * 1024; e += 1024) {
    int l = e >> 10, s = e & 1023;
    if (s >= (int)cnts[l]) continue;
    unsigned long long k0 = skey[l][s];
    unsigned rank = (unsigned)s;
    #pragma unroll
    for (int l2 = 0; l2 < 5; ++l2) {
      if (l2 == l) continue;
      int lo = 0, hi = (int)cnts[l2];
      while (lo < hi) {
        int mid = (lo + hi) >> 1;
        if (skey[l2][mid] > k0) lo = mid + 1; else hi = mid;
      }
      rank += (unsigned)lo;
    }
    if (rank < (unsigned)MAX_OUT) {
      unsigned pos = kept_pos[(size_t)(img * 5 + l) * 1024 + s];
      const float* b = cand_box + (size_t)(img * M_TOT + pos) * 4;
      float* o = out + (size_t)img * (MAX_OUT * 5) + (size_t)rank * 5;
      o[0] = b[0]; o[1] = b[1]; o[2] = b[2]; o[3] = b[3];
      o[4] = cand_s[img * M_TOT + pos];
    }
  }
}

// ================= host launch =================
extern "C" void kernel_launch(void* const* d_in, const int* in_sizes, int n_in,
                              void* d_out, int out_size, void* d_ws, size_t ws_size,
                              hipStream_t stream) {
  Ptrs p;
  bool interleaved = (n_in == 10 && in_sizes[1] == 4 * 12 * 128 * 128);
  for (int l = 0; l < 5; ++l) {
    if (interleaved) {
      p.cls[l] = (const float*)d_in[2 * l];
      p.reg[l] = (const float*)d_in[2 * l + 1];
    } else {
      p.cls[l] = (const float*)d_in[l];
      p.reg[l] = (const float*)d_in[5 + l];
    }
  }
  uint8_t* w = (uint8_t*)d_ws;
  size_t o = 0;
  auto carve = [&](size_t bytes) {
    void* ptr = w + o;
    o += (bytes + 255) & ~(size_t)255;
    return ptr;
  };
  // gcnt + ghist + vflags adjacent -> one memset zeroes all three
  unsigned* gcnt = (unsigned*)carve((size_t)20 * 4);                 // 256B slot
  unsigned* ghist = (unsigned*)carve((size_t)20 * 4096 * 4);
  unsigned long long* vflags = (unsigned long long*)carve((size_t)20 * 32 * 8);
  size_t zero_bytes = 256 + (size_t)20 * 4096 * 4 + (size_t)20 * 32 * 8;
  unsigned long long* T64_arr = (unsigned long long*)carve((size_t)20 * 8);
  unsigned* u_arr = (unsigned*)carve((size_t)4 * U_PER_IMG * 4);
  float* cand_box = (float*)carve((size_t)4 * M_TOT * 4 * 4);
  float* cand_s = (float*)carve((size_t)4 * M_TOT * 4);
  float* n_x1 = (float*)carve((size_t)4 * M_TOT * 4);
  float* n_y1 = (float*)carve((size_t)4 * M_TOT * 4);
  float* n_x2 = (float*)carve((size_t)4 * M_TOT * 4);
  float* n_y2 = (float*)carve((size_t)4 * M_TOT * 4);
  float* n_ar = (float*)carve((size_t)4 * M_TOT * 4);
  float* n_sc = (float*)carve((size_t)4 * M_TOT * 4);
  unsigned* n_pos = (unsigned*)carve((size_t)4 * M_TOT * 4);
  unsigned* V_arr = (unsigned*)carve((size_t)20 * 4);
  unsigned* kept_pos = (unsigned*)carve((size_t)4 * 5 * 1024 * 4);
  unsigned long long* kept_key = (unsigned long long*)carve((size_t)4 * 5 * 1024 * 8);
  unsigned* kept_cnt = (unsigned*)carve((size_t)20 * 4);
  unsigned long long* diagT = (unsigned long long*)carve((size_t)20 * 40 * 64 * 8);
  unsigned long long* mask = (unsigned long long*)carve((size_t)4 * MWORDS_PER_IMG * 8);
  // gtk (20*4096 u64 = 640KB) aliases mask: dead before k_mask writes it.
  unsigned long long* gtk = mask;
  (void)ws_size; (void)out_size;

  hipMemsetAsync(gcnt, 0, zero_bytes, stream);
  k_sig<<<dim3(18, 4), 1024, 0, stream>>>(p, u_arr, ghist);
  k_thresh<<<20, 1024, 0, stream>>>(u_arr, ghist, T64_arr);
  k_collect<<<dim3(18, 4), 1024, 0, stream>>>(u_arr, T64_arr, gtk, gcnt);
  k_rank<<<dim3(16, 20), 256, 0, stream>>>(p, gtk, gcnt, cand_box, cand_s,
                                           vflags);
  k_part<<<20, 256, 0, stream>>>(cand_box, cand_s, vflags,
      n_x1, n_y1, n_x2, n_y2, n_ar, n_sc, n_pos, V_arr);
  k_mask<<<dim3(807, 4), 256, 0, stream>>>(n_x1, n_y1, n_x2, n_y2, n_ar,
                                           mask, diagT);
  k_scan<<<20, 512, 0, stream>>>(mask, diagT, n_pos, n_sc, V_arr,
                                 kept_pos, kept_key, kept_cnt);
  k_merge<<<4, 1024, 0, stream>>>(cand_box, cand_s, kept_pos, kept_key,
                                  kept_cnt, (float*)d_out);
}

// Round 11
// 151.362 us; speedup vs baseline: 1.6006x; 1.2760x over previous
//
#include <hip/hip_runtime.h>
#include <cstdint>
#include <cstddef>

// ---------------- constants ----------------
__constant__ int LV_N[5]    = {49152, 12288, 3072, 768, 192};   // H*W*3
__constant__ int LV_K[5]    = {2000, 2000, 2000, 768, 192};     // min(PRE_NMS, N)
__constant__ int LV_OFF[5]  = {0, 2000, 4000, 6000, 6768};      // concat offsets
__constant__ int LV_UOFF[5] = {0, 49152, 61440, 64512, 65280};  // u-array offsets
__constant__ int LV_W[5]    = {128, 64, 32, 16, 8};
__constant__ int LV_S[5]    = {4, 8, 16, 32, 64};
__constant__ int LV_LOGHW[5]= {14, 12, 10, 8, 6};
// mask geometry (rows padded by 192 so scan prefetch needs no bounds tests)
__constant__ int WPL[5]     = {32, 32, 32, 12, 3};              // words per row
__constant__ int MOFF[5]    = {0, 70144, 140288, 210432, 221952};
__constant__ int MB_BASE[6] = {0, 256, 512, 768, 804, 807};     // mask-block bases
__constant__ int MB_CT[5]   = {8, 8, 8, 3, 1};                  // col tiles per lvl
__constant__ int SGB6[6]    = {0, 12, 15, 16, 17, 18};          // 4096-elem tile bases

#define M_TOT 6960
#define U_PER_IMG 65472
#define MAX_OUT 1000
#define MWORDS_PER_IMG 223104
#define CAP 4096

struct Ptrs { const float* cls[5]; const float* reg[5]; };

// ---------------- XLA:CPU-compatible expf (Cephes/Eigen pexp, FMA-contracted) ----
__device__ __forceinline__ float xla_expf(float x) {
  const float exp_hi = 88.3762626647950f;
  const float exp_lo = -88.3762626647949f;
  const float log2ef = 1.44269504088896341f;
  const float c1 = 0.693359375f;
  const float c2 = -2.12194440e-4f;
  const float p0 = 1.9875691500e-4f;
  const float p1 = 1.3981999507e-3f;
  const float p2 = 8.3334519073e-3f;
  const float p3 = 4.1665795894e-2f;
  const float p4 = 1.6666665459e-1f;
  const float p5 = 5.0000001201e-1f;
  float xx = fminf(fmaxf(x, exp_lo), exp_hi);
  float fx = floorf(__fmaf_rn(xx, log2ef, 0.5f));
  float r = __fmaf_rn(fx, -c1, xx);
  r = __fmaf_rn(fx, -c2, r);
  float z = __fmul_rn(r, r);
  float y = __fmaf_rn(p0, r, p1);
  y = __fmaf_rn(y, r, p2);
  y = __fmaf_rn(y, r, p3);
  y = __fmaf_rn(y, r, p4);
  y = __fmaf_rn(y, r, p5);
  y = __fmaf_rn(y, z, r);
  y = __fadd_rn(y, 1.0f);
  int n = (int)fx;
  float two_n = __uint_as_float((unsigned)(n + 127) << 23);
  return __fmul_rn(y, two_n);
}

__device__ __forceinline__ float ref_sigmoid(float x) {
  return __fdiv_rn(1.0f, __fadd_rn(1.0f, xla_expf(-x)));
}

// ================= K0: wide sigmoid + 4096-bin score-bit histogram ============
__global__ __launch_bounds__(1024) void k_sig(Ptrs p, unsigned* u_arr,
                                              unsigned* ghist) {
  const int img = blockIdx.y;
  const int bx = blockIdx.x;
  int lvl = 0;
  while (bx >= SGB6[lvl + 1]) ++lvl;
  const int N = LV_N[lvl], LOGHW = LV_LOGHW[lvl];
  const int HW = 1 << LOGHW;
  const int e0 = (bx - SGB6[lvl]) * 4096;
  const int e1 = (e0 + 4096 < N) ? e0 + 4096 : N;
  const int tid = (int)threadIdx.x;
  __shared__ unsigned h[4096];
  for (int e = tid; e < 4096; e += 1024) h[e] = 0;
  __syncthreads();
  const float* cls = p.cls[lvl] + (size_t)img * N;
  unsigned* u = u_arr + img * U_PER_IMG + LV_UOFF[lvl];
  for (int e = e0 + tid; e < e1; e += 1024) {
    float logit = cls[e];                  // plane-major: fully coalesced
    unsigned ub = __float_as_uint(ref_sigmoid(logit));
    int a = e >> LOGHW, pix = e & (HW - 1);
    u[pix * 3 + a] = ub;                   // channel-last (reference order)
    atomicAdd(&h[(ub >> 18) & 4095u], 1u);
  }
  __syncthreads();
  unsigned* gh = ghist + (size_t)(img * 5 + lvl) * 4096;
  for (int e = tid; e < 4096; e += 1024)
    if (h[e]) atomicAdd(&gh[e], h[e]);
}

// ================= K1a: threshold pick (O(bins), N-scan only on fallback) =====
__global__ __launch_bounds__(1024) void k_thresh(const unsigned* u_arr,
    const unsigned* ghist, unsigned long long* T64_arr) {
  const int blk = blockIdx.x;
  const int img = blk / 5, lvl = blk % 5;
  const int N = LV_N[lvl], K = LV_K[lvl];
  const int tid = (int)threadIdx.x;
  if (N <= K) { if (tid == 0) T64_arr[blk] = 0ULL; return; }
  __shared__ unsigned h[4096], sA[4096], sB[4096];
  __shared__ unsigned sh_D, sh_sD, sh_sD1;
  const unsigned* u = u_arr + img * U_PER_IMG + LV_UOFF[lvl];

  for (int e = tid; e < 4096; e += 1024)
    h[e] = ghist[(size_t)blk * 4096 + e];
  __syncthreads();

  unsigned long long prefix = 0;
  unsigned want = (unsigned)K, above = 0;
  const int shifts[6] = {50, 38, 26, 14, 2, 0};
  const int widths[6] = {12, 12, 12, 12, 12, 2};
  for (int rd = 0; rd < 6; ++rd) {
    const int shift = shifts[rd], width = widths[rd];
    const int nb = 1 << width;
    if (rd > 0) {                          // fallback: exact rescan (rare)
      for (int e = tid; e < nb; e += 1024) h[e] = 0;
      __syncthreads();
      for (int i = tid; i < N; i += 1024) {
        unsigned long long key =
            ((unsigned long long)u[i] << 32) | (unsigned)(~(unsigned)i);
        if ((key >> (shift + width)) == prefix)
          atomicAdd(&h[(unsigned)(key >> shift) & (unsigned)(nb - 1)], 1u);
      }
      __syncthreads();
    }
    // suffix scan s[d] = sum_{v>=d} h[v]
    unsigned *Ap = sA, *Bp = sB;
    for (int e = tid; e < nb; e += 1024) Ap[e] = h[e];
    __syncthreads();
    for (int off = 1; off < nb; off <<= 1) {
      for (int e = tid; e < nb; e += 1024)
        Bp[e] = Ap[e] + ((e + off < nb) ? Ap[e + off] : 0u);
      __syncthreads();
      unsigned* t = Ap; Ap = Bp; Bp = t;
    }
    for (int e = tid; e < nb; e += 1024) {
      unsigned s = Ap[e], sn = (e + 1 < nb) ? Ap[e + 1] : 0u;
      if (s >= want && sn < want) { sh_D = (unsigned)e; sh_sD = s; sh_sD1 = sn; }
    }
    __syncthreads();
    unsigned D = sh_D, sD = sh_sD, sD1 = sh_sD1;
    unsigned long long npref = (prefix << width) | (unsigned long long)D;
    if (above + sD <= (unsigned)CAP || rd == 5) {
      if (tid == 0) T64_arr[blk] = npref << shift;
      return;                              // uniform decision across block
    }
    above += sD1; want -= sD1; prefix = npref;
    __syncthreads();
  }
}

// ================= K1b: wide collect, ONE global atomic per block ============
// Phase 1: preds -> per-(wave,iter) ballot counts in LDS. Phase 2: wave 0
// shfl-prefix-scans the 64 counts, lane 63 does the block's single atomicAdd.
// Phase 3: lanes write survivors at base + prefix. Slot order is
// nondeterministic but k_rank orders purely by key compares -> output stable.
__global__ __launch_bounds__(1024) void k_collect(const unsigned* u_arr,
    const unsigned long long* T64_arr, unsigned long long* gtk, unsigned* gcnt) {
  const int img = blockIdx.y;
  const int bx = blockIdx.x;
  int lvl = 0;
  while (bx >= SGB6[lvl + 1]) ++lvl;
  const int N = LV_N[lvl];
  const int e0 = (bx - SGB6[lvl]) * 4096;
  const int tid = (int)threadIdx.x;
  const int lane = tid & 63;
  const int w = tid >> 6;                     // 16 waves
  const unsigned long long T = T64_arr[img * 5 + lvl];
  const unsigned* u = u_arr + img * U_PER_IMG + LV_UOFF[lvl];

  __shared__ unsigned wcnt[64];               // [wave*4 + iter] -> offsets

  unsigned long long key0 = 0, key1 = 0, key2 = 0, key3 = 0;
  unsigned long long bm0, bm1, bm2, bm3;
  {
    int e = e0 + 0 * 1024 + tid;
    bool pr = false;
    if (e < N) { key0 = ((unsigned long long)u[e] << 32) | (unsigned)(~(unsigned)e); pr = key0 >= T; }
    bm0 = __ballot(pr);
    if (lane == 0) wcnt[w * 4 + 0] = (unsigned)__popcll(bm0);
  }
  {
    int e = e0 + 1 * 1024 + tid;
    bool pr = false;
    if (e < N) { key1 = ((unsigned long long)u[e] << 32) | (unsigned)(~(unsigned)e); pr = key1 >= T; }
    bm1 = __ballot(pr);
    if (lane == 0) wcnt[w * 4 + 1] = (unsigned)__popcll(bm1);
  }
  {
    int e = e0 + 2 * 1024 + tid;
    bool pr = false;
    if (e < N) { key2 = ((unsigned long long)u[e] << 32) | (unsigned)(~(unsigned)e); pr = key2 >= T; }
    bm2 = __ballot(pr);
    if (lane == 0) wcnt[w * 4 + 2] = (unsigned)__popcll(bm2);
  }
  {
    int e = e0 + 3 * 1024 + tid;
    bool pr = false;
    if (e < N) { key3 = ((unsigned long long)u[e] << 32) | (unsigned)(~(unsigned)e); pr = key3 >= T; }
    bm3 = __ballot(pr);
    if (lane == 0) wcnt[w * 4 + 3] = (unsigned)__popcll(bm3);
  }
  __syncthreads();
  if (tid < 64) {
    unsigned c = wcnt[tid];
    unsigned pre = c;
    #pragma unroll
    for (int off = 1; off < 64; off <<= 1) {
      unsigned t = __shfl_up(pre, off);
      if (tid >= off) pre += t;
    }
    unsigned total = __shfl(pre, 63);
    unsigned base = 0;
    if (tid == 63 && total) base = atomicAdd(gcnt + (img * 5 + lvl), total);
    base = __shfl(base, 63);
    wcnt[tid] = base + pre - c;               // exclusive (wave,iter) offset
  }
  __syncthreads();
  unsigned long long* dst = gtk + (size_t)(img * 5 + lvl) * CAP;
  const unsigned long long below = (1ULL << lane) - 1ULL;
  if ((bm0 >> lane) & 1ULL) {
    unsigned slot = wcnt[w * 4 + 0] + (unsigned)__popcll(bm0 & below);
    if (slot < (unsigned)CAP) dst[slot] = key0;
  }
  if ((bm1 >> lane) & 1ULL) {
    unsigned slot = wcnt[w * 4 + 1] + (unsigned)__popcll(bm1 & below);
    if (slot < (unsigned)CAP) dst[slot] = key1;
  }
  if ((bm2 >> lane) & 1ULL) {
    unsigned slot = wcnt[w * 4 + 2] + (unsigned)__popcll(bm2 & below);
    if (slot < (unsigned)CAP) dst[slot] = key2;
  }
  if ((bm3 >> lane) & 1ULL) {
    unsigned slot = wcnt[w * 4 + 3] + (unsigned)__popcll(bm3 & below);
    if (slot < (unsigned)CAP) dst[slot] = key3;
  }
}

// ================= K1c: brute-force rank + direct decode (no sort) ===========
__global__ __launch_bounds__(256) void k_rank(Ptrs p,
    const unsigned long long* gtk, const unsigned* gcnt,
    float* cand_box, float* cand_s, unsigned long long* vflags) {
  const int il = (int)blockIdx.y;
  const int img = il / 5, lvl = il % 5;
  const int N = LV_N[lvl], K = LV_K[lvl], W = LV_W[lvl], S = LV_S[lvl];
  const int HW = N / 3;
  const float* reg = p.reg[lvl] + (size_t)img * 12 * HW;
  const int tid = (int)threadIdx.x;
  unsigned cnt = gcnt[il];
  if (cnt > (unsigned)CAP) cnt = CAP;
  const unsigned cnt8 = (cnt + 7u) & ~7u;
  __shared__ unsigned long long keys[CAP];
  const unsigned long long* src = gtk + (size_t)il * CAP;
  for (int e = tid; e < (int)cnt8; e += 256)
    keys[e] = (e < (int)cnt) ? src[e] : 0ULL;   // real keys >= 2^32 > 0 pad
  __syncthreads();
  const int s = (int)blockIdx.x * 256 + tid;
  if (s >= (int)cnt) return;
  const unsigned long long mykey = keys[s];
  unsigned rank = 0;
  #pragma unroll 8
  for (unsigned j = 0; j < cnt8; ++j)
    rank += (keys[j] > mykey) ? 1u : 0u;        // broadcast read, conflict-free
  if (rank >= (unsigned)K) return;

  unsigned ubits = (unsigned)(mykey >> 32);
  unsigned idx = ~((unsigned)mykey);
  int a = (int)(idx % 3u); int pix = (int)(idx / 3u);
  int xq = pix % W, yq = pix / W;
  float dx = reg[(a * 4 + 0) * HW + pix];
  float dy = reg[(a * 4 + 1) * HW + pix];
  float dw = reg[(a * 4 + 2) * HW + pix];
  float dh = reg[(a * 4 + 3) * HW + pix];
  double rr = (a == 0) ? 0.5 : (a == 1 ? 1.0 : 2.0);
  double hr = sqrt(rr), wr = 1.0 / hr;
  double st = (double)S;
  double wsd = st * wr * 8.0, hsd = st * hr * 8.0;
  double sxd = (double)(xq * S), syd = (double)(yq * S);
  float a0 = (float)(sxd - 0.5 * wsd), a1 = (float)(syd - 0.5 * hsd);
  float a2 = (float)(sxd + 0.5 * wsd), a3 = (float)(syd + 0.5 * hsd);
  float px = __fmul_rn(__fadd_rn(a0, a2), 0.5f);
  float py = __fmul_rn(__fadd_rn(a1, a3), 0.5f);
  float pw = __fsub_rn(a2, a0), ph = __fsub_rn(a3, a1);
  const float MRf = 4.135166556742356f;  // |log(16/1000)| rounded to f32
  float dwc = fminf(fmaxf(dw, -MRf), MRf);
  float dhc = fminf(fmaxf(dh, -MRf), MRf);
  float gw = __fmul_rn(pw, xla_expf(dwc));
  float gh = __fmul_rn(ph, xla_expf(dhc));
  float gx = __fmaf_rn(pw, dx, px);
  float gy = __fmaf_rn(ph, dy, py);
  float x1 = fminf(fmaxf(__fmaf_rn(gw, -0.5f, gx), 0.0f), 512.0f);
  float y1 = fminf(fmaxf(__fmaf_rn(gh, -0.5f, gy), 0.0f), 512.0f);
  float x2 = fminf(fmaxf(__fmaf_rn(gw,  0.5f, gx), 0.0f), 512.0f);
  float y2 = fminf(fmaxf(__fmaf_rn(gh,  0.5f, gy), 0.0f), 512.0f);
  bool valid = (__fsub_rn(x2, x1) > 0.0f) && (__fsub_rn(y2, y1) > 0.0f);
  int pos = img * M_TOT + LV_OFF[lvl] + (int)rank;
  cand_box[(size_t)pos * 4 + 0] = x1;
  cand_box[(size_t)pos * 4 + 1] = y1;
  cand_box[(size_t)pos * 4 + 2] = x2;
  cand_box[(size_t)pos * 4 + 3] = y2;
  float score = __uint_as_float(ubits);
  cand_s[pos] = valid ? score : -1.0f;
  if (valid)
    atomicOr(&vflags[(size_t)il * 32 + (rank >> 6)], 1ULL << (rank & 63));
}

// ================= K1d: partition (valids first) + NMS-order arrays ==========
__global__ __launch_bounds__(256) void k_part(const float* cand_box,
    const float* cand_s, const unsigned long long* vflags,
    float* n_x1, float* n_y1, float* n_x2, float* n_y2, float* n_ar,
    float* n_sc, unsigned* n_pos, unsigned* V_arr) {
  const int il = (int)blockIdx.x;
  const int img = il / 5, lvl = il % 5;
  const int K = LV_K[lvl];
  const int tid = (int)threadIdx.x;
  __shared__ unsigned long long sflag[32];
  __shared__ unsigned wpre[33];
  if (tid < 32) sflag[tid] = vflags[(size_t)il * 32 + tid];
  __syncthreads();
  if (tid < 32) {
    unsigned c = (unsigned)__popcll(sflag[tid]);
    #pragma unroll
    for (int off = 1; off < 32; off <<= 1) {
      unsigned t = __shfl_up(c, off);
      if (tid >= off) c += t;
    }
    wpre[tid + 1] = c;
    if (tid == 0) wpre[0] = 0;
  }
  __syncthreads();
  const unsigned V = wpre[32];
  const float offv = __fmul_rn((float)lvl, 513.0f);
  const int base = img * M_TOT + LV_OFF[lvl];
  for (int r = tid; r < K; r += 256) {
    unsigned long long word = sflag[r >> 6];
    unsigned fl = (unsigned)((word >> (r & 63)) & 1ULL);
    unsigned excl = wpre[r >> 6] +
                    (unsigned)__popcll(word & ((1ULL << (r & 63)) - 1ULL));
    unsigned pdst = fl ? excl : V + ((unsigned)r - excl);
    const float* b = cand_box + (size_t)(base + r) * 4;
    float ox1 = __fadd_rn(b[0], offv), oy1 = __fadd_rn(b[1], offv);
    float ox2 = __fadd_rn(b[2], offv), oy2 = __fadd_rn(b[3], offv);
    int dst = base + (int)pdst;
    n_x1[dst] = ox1; n_y1[dst] = oy1; n_x2[dst] = ox2; n_y2[dst] = oy2;
    n_ar[dst] = __fmul_rn(__fsub_rn(ox2, ox1), __fsub_rn(oy2, oy1));
    n_sc[dst] = cand_s[base + r];
    n_pos[dst] = (unsigned)(LV_OFF[lvl] + r);
  }
  if (tid == 0) V_arr[il] = V;
}

// ================= K2a: suppression bit-matrix build + diag transpose ========
#define TSTAGE(S, M)                                                        \
  {                                                                         \
    unsigned long long t_ = __shfl_xor(x, S);                               \
    x = (lane & S) ? ((x & (M)) | ((t_ >> S) & ~(M)))                       \
                   : ((x & ~(M)) | ((t_ << S) & (M)));                      \
  }

__global__ __launch_bounds__(256) void k_mask(
    const float* n_x1, const float* n_y1, const float* n_x2, const float* n_y2,
    const float* n_ar, unsigned long long* mask, unsigned long long* diagT) {
  const int img = blockIdx.y;
  const int bx = blockIdx.x;
  int lvl = 0;
  while (bx >= MB_BASE[lvl + 1]) ++lvl;
  const int t = bx - MB_BASE[lvl];
  const int ct = MB_CT[lvl];
  const int rt = t / ct, c = t % ct;
  const int K = LV_K[lvl];
  const int row0 = rt * 64, col0 = c * 256;
  if (col0 + 255 <= row0) return;  // entire tile has j <= r: bits never consumed

  __shared__ float4 cb4[256];
  __shared__ float cba[256];
  __shared__ float4 rb4[64];
  __shared__ float rba[64];
  const int base = img * M_TOT + LV_OFF[lvl];
  const int tid = (int)threadIdx.x;
  if (tid < 64) {
    int r = row0 + tid;
    if (r < K) {
      rb4[tid] = make_float4(n_x1[base + r], n_y1[base + r],
                             n_x2[base + r], n_y2[base + r]);
      rba[tid] = n_ar[base + r];
    } else {
      rb4[tid] = make_float4(0.f, 0.f, 0.f, 0.f);
      rba[tid] = 0.f;
    }
  }
  {
    int j = col0 + tid;
    if (j < K) {
      cb4[tid] = make_float4(n_x1[base + j], n_y1[base + j],
                             n_x2[base + j], n_y2[base + j]);
      cba[tid] = n_ar[base + j];
    }
  }
  __syncthreads();
  const int wl = tid >> 6, lane = tid & 63;
  const int r = row0 + lane;
  const bool rvalid = (r < K);
  const float4 rb = rb4[lane];
  const float rar = rba[lane];
  unsigned long long word = 0ULL;
  const int jbase = wl * 64;
  const int jmax = K - col0 - jbase;   // bit k valid iff k < jmax
  #pragma unroll 16
  for (int k = 0; k < 64; ++k) {
    float4 cb = cb4[jbase + k];        // broadcast: all lanes same address
    float car = cba[jbase + k];
    float iw = fmaxf(__fsub_rn(fminf(rb.z, cb.z), fmaxf(rb.x, cb.x)), 0.0f);
    float ih = fmaxf(__fsub_rn(fminf(rb.w, cb.w), fmaxf(rb.y, cb.y)), 0.0f);
    float inter = __fmul_rn(iw, ih);
    float uni = __fsub_rn(__fadd_rn(rar, car), inter);
    float iou = (uni > 0.0f) ? __fdiv_rn(inter, uni) : 0.0f;
    if (iou > 0.7f && k < jmax) word |= (1ULL << k);
  }
  if (!rvalid) word = 0ULL;
  if (rvalid)
    mask[(size_t)img * MWORDS_PER_IMG + MOFF[lvl] +
         (size_t)r * WPL[lvl] + (size_t)((col0 >> 6) + wl)] = word;
  // diag 64x64 block of this chunk lives in word wl where col0+64*wl == row0:
  // transpose it across lanes (lane i -> column i) and store to diagT.
  if (col0 + (wl << 6) == row0) {
    unsigned long long x = word;
    TSTAGE(32, 0xFFFFFFFF00000000ULL)
    TSTAGE(16, 0xFFFF0000FFFF0000ULL)
    TSTAGE(8,  0xFF00FF00FF00FF00ULL)
    TSTAGE(4,  0xF0F0F0F0F0F0F0F0ULL)
    TSTAGE(2,  0xCCCCCCCCCCCCCCCCULL)
    TSTAGE(1,  0xAAAAAAAAAAAAAAAAULL)
    diagT[(size_t)(img * 5 + lvl) * (40 * 64) + (size_t)rt * 64 + lane] = x;
  }
}

// ================= K2b: 8-wave chunked greedy scan ===========================
#define SCAN_CHUNK(P0, P1, P2, P3)                                          \
  {                                                                         \
    const int r0 = c << 6;                                                  \
    if (w == (c & 7)) {                                                     \
      unsigned long long v = (g == (c >> 3)) ? aw : ~0ULL;                  \
      v &= __shfl_xor(v, 1);                                                \
      v &= __shfl_xor(v, 2);                                                \
      v &= __shfl_xor(v, 4);                                                \
      v &= __shfl_xor(v, 8);                                                \
      v = __shfl(v, (c >> 3) * 16);                                         \
      unsigned long long x = dg;                                            \
      unsigned long long kw = v;                                            \
      while (true) {                                                        \
        bool keep_j = (((v >> lane) & 1ULL) != 0ULL) &&                     \
                      ((kw & below & x) == 0ULL);                           \
        unsigned long long nkw = __ballot(keep_j);                          \
        if (nkw == kw) break;                                               \
        kw = nkw;                                                           \
      }                                                                     \
      if ((kw >> lane) & 1ULL)                                              \
        skept[kept + (int)__popcll(kw & below)] = (unsigned)(r0 + lane);    \
      if (lane == 0) s_kw[c & 1] = kw;                                      \
      int no_ = next_own < 40 ? next_own : 39;                              \
      dg = dT[(size_t)no_ * 64 + lane];                                     \
      next_own += 8;                                                        \
    }                                                                       \
    __syncthreads();                                                        \
    unsigned long long kwv = s_kw[c & 1];                                   \
    kept += (int)__popcll(kwv);                                             \
    aw &= ~(P0 & (unsigned long long)((long long)(kwv << (63 - (d0 + 0))) >> 63)); \
    aw &= ~(P1 & (unsigned long long)((long long)(kwv << (63 - (d0 + 1))) >> 63)); \
    aw &= ~(P2 & (unsigned long long)((long long)(kwv << (63 - (d0 + 2))) >> 63)); \
    aw &= ~(P3 & (unsigned long long)((long long)(kwv << (63 - (d0 + 3))) >> 63)); \
    P0 = mb[(size_t)(r0 + 128 + d0 + 0) * wpl + wkc];                       \
    P1 = mb[(size_t)(r0 + 128 + d0 + 1) * wpl + wkc];                       \
    P2 = mb[(size_t)(r0 + 128 + d0 + 2) * wpl + wkc];                       \
    P3 = mb[(size_t)(r0 + 128 + d0 + 3) * wpl + wkc];                       \
    ++c;                                                                    \
  }

__global__ __launch_bounds__(512) void k_scan(const unsigned long long* mask,
    const unsigned long long* diagT,
    const unsigned* n_pos, const float* n_sc, const unsigned* V_arr,
    unsigned* kept_pos, unsigned long long* kept_key, unsigned* kept_cnt) {
  const int il = (int)blockIdx.x;
  const int img = il / 5, lvl = il % 5;
  const int K = LV_K[lvl], wpl = WPL[lvl];
  const int tid = (int)threadIdx.x;
  const int w = tid >> 6, lane = tid & 63;
  const unsigned long long* mb =
      mask + (size_t)img * MWORDS_PER_IMG + MOFF[lvl];
  const unsigned long long* dT = diagT + (size_t)il * (40 * 64);

  __shared__ unsigned long long s_kw[2];
  __shared__ unsigned skept[MAX_OUT + 64];

  const int g = lane >> 4;
  const int wk = w + 8 * g;
  const int wkc = wk < wpl ? wk : 0;      // clamped (dup loads harmless)
  const int d0 = (lane & 15) * 4;         // my 4 suppression rows per chunk
  const unsigned long long below = (1ULL << lane) - 1ULL;

  const int V = (int)V_arr[il];
  unsigned long long aw;
  {
    int lo = wk * 64, hi = V < lo + 64 ? V : lo + 64;
    aw = (hi > lo) ? ((hi - lo == 64) ? ~0ULL : ((1ULL << (hi - lo)) - 1ULL))
                   : 0ULL;
  }

  const int nchunks = (K + 63) >> 6;
  unsigned long long pfA0 = mb[(size_t)(d0 + 0) * wpl + wkc];
  unsigned long long pfA1 = mb[(size_t)(d0 + 1) * wpl + wkc];
  unsigned long long pfA2 = mb[(size_t)(d0 + 2) * wpl + wkc];
  unsigned long long pfA3 = mb[(size_t)(d0 + 3) * wpl + wkc];
  unsigned long long pfB0 = mb[(size_t)(64 + d0 + 0) * wpl + wkc];
  unsigned long long pfB1 = mb[(size_t)(64 + d0 + 1) * wpl + wkc];
  unsigned long long pfB2 = mb[(size_t)(64 + d0 + 2) * wpl + wkc];
  unsigned long long pfB3 = mb[(size_t)(64 + d0 + 3) * wpl + wkc];
  unsigned long long dg = dT[(size_t)w * 64 + lane];
  int next_own = w + 8;

  int kept = 0;
  int c = 0;
  while (c < nchunks && kept < MAX_OUT) {
    SCAN_CHUNK(pfA0, pfA1, pfA2, pfA3)
    if (c >= nchunks || kept >= MAX_OUT) break;
    SCAN_CHUNK(pfB0, pfB1, pfB2, pfB3)
  }

  __syncthreads();
  const int kc = kept < MAX_OUT ? kept : MAX_OUT;
  const int base = img * M_TOT + LV_OFF[lvl];
  const size_t bo = (size_t)il * 1024;
  for (int i = tid; i < kc; i += 512) {
    unsigned r = skept[i];
    unsigned pp = n_pos[base + (int)r];
    kept_pos[bo + i] = pp;
    kept_key[bo + i] =
        ((unsigned long long)__float_as_uint(n_sc[base + (int)r]) << 32) |
        (unsigned)(~pp);
  }
  if (tid == 0) kept_cnt[il] = (unsigned)kc;
}

// ================= K3: per-image merge of kept lists -> output rows ===========
__global__ __launch_bounds__(1024) void k_merge(const float* cand_box,
    const float* cand_s, const unsigned* kept_pos,
    const unsigned long long* kept_key, const unsigned* kept_cnt, float* out) {
  const int img = blockIdx.x;
  const int tid = (int)threadIdx.x;
  __shared__ unsigned cnts[5];
  __shared__ unsigned long long skey[5][1024];
  if (tid < 5) {
    unsigned c = kept_cnt[img * 5 + tid];
    cnts[tid] = c < (unsigned)MAX_OUT ? c : (unsigned)MAX_OUT;
  }
  __syncthreads();
  for (int e = tid; e < 5 * 1024; e += 1024) {
    int l = e >> 10, s = e & 1023;
    skey[l][s] = (s < (int)cnts[l])
        ? kept_key[(size_t)(img * 5 + l) * 1024 + s] : 0ULL;
  }
  __syncthreads();
  unsigned T = cnts[0] + cnts[1] + cnts[2] + cnts[3] + cnts[4];
  unsigned Tc = T < (unsigned)MAX_OUT ? T : (unsigned)MAX_OUT;
  for (int r = (int)Tc + tid; r < MAX_OUT; r += 1024) {
    float* o = out + (size_t)img * (MAX_OUT * 5) + (size_t)r * 5;
    o[0] = 0.f; o[1] = 0.f; o[2] = 0.f; o[3] = 0.f; o[4] = 0.f;
  }
  for (int e = tid; e < 5 * 1024; e += 1024) {
    int l = e >> 10, s = e & 1023;
    if (s >= (int)cnts[l]) continue;
    unsigned long long k0 = skey[l][s];
    unsigned rank = (unsigned)s;
    #pragma unroll
    for (int l2 = 0; l2 < 5; ++l2) {
      if (l2 == l) continue;
      int lo = 0, hi = (int)cnts[l2];
      while (lo < hi) {
        int mid = (lo + hi) >> 1;
        if (skey[l2][mid] > k0) lo = mid + 1; else hi = mid;
      }
      rank += (unsigned)lo;
    }
    if (rank < (unsigned)MAX_OUT) {
      unsigned pos = kept_pos[(size_t)(img * 5 + l) * 1024 + s];
      const float* b = cand_box + (size_t)(img * M_TOT + pos) * 4;
      float* o = out + (size_t)img * (MAX_OUT * 5) + (size_t)rank * 5;
      o[0] = b[0]; o[1] = b[1]; o[2] = b[2]; o[3] = b[3];
      o[4] = cand_s[img * M_TOT + pos];
    }
  }
}

// ================= host launch =================
extern "C" void kernel_launch(void* const* d_in, const int* in_sizes, int n_in,
                              void* d_out, int out_size, void* d_ws, size_t ws_size,
                              hipStream_t stream) {
  Ptrs p;
  bool interleaved = (n_in == 10 && in_sizes[1] == 4 * 12 * 128 * 128);
  for (int l = 0; l < 5; ++l) {
    if (interleaved) {
      p.cls[l] = (const float*)d_in[2 * l];
      p.reg[l] = (const float*)d_in[2 * l + 1];
    } else {
      p.cls[l] = (const float*)d_in[l];
      p.reg[l] = (const float*)d_in[5 + l];
    }
  }
  uint8_t* w = (uint8_t*)d_ws;
  size_t o = 0;
  auto carve = [&](size_t bytes) {
    void* ptr = w + o;
    o += (bytes + 255) & ~(size_t)255;
    return ptr;
  };
  // gcnt + ghist + vflags adjacent -> one memset zeroes all three
  unsigned* gcnt = (unsigned*)carve((size_t)20 * 4);                 // 256B slot
  unsigned* ghist = (unsigned*)carve((size_t)20 * 4096 * 4);
  unsigned long long* vflags = (unsigned long long*)carve((size_t)20 * 32 * 8);
  size_t zero_bytes = 256 + (size_t)20 * 4096 * 4 + (size_t)20 * 32 * 8;
  unsigned long long* T64_arr = (unsigned long long*)carve((size_t)20 * 8);
  unsigned* u_arr = (unsigned*)carve((size_t)4 * U_PER_IMG * 4);
  float* cand_box = (float*)carve((size_t)4 * M_TOT * 4 * 4);
  float* cand_s = (float*)carve((size_t)4 * M_TOT * 4);
  float* n_x1 = (float*)carve((size_t)4 * M_TOT * 4);
  float* n_y1 = (float*)carve((size_t)4 * M_TOT * 4);
  float* n_x2 = (float*)carve((size_t)4 * M_TOT * 4);
  float* n_y2 = (float*)carve((size_t)4 * M_TOT * 4);
  float* n_ar = (float*)carve((size_t)4 * M_TOT * 4);
  float* n_sc = (float*)carve((size_t)4 * M_TOT * 4);
  unsigned* n_pos = (unsigned*)carve((size_t)4 * M_TOT * 4);
  unsigned* V_arr = (unsigned*)carve((size_t)20 * 4);
  unsigned* kept_pos = (unsigned*)carve((size_t)4 * 5 * 1024 * 4);
  unsigned long long* kept_key = (unsigned long long*)carve((size_t)4 * 5 * 1024 * 8);
  unsigned* kept_cnt = (unsigned*)carve((size_t)20 * 4);
  unsigned long long* diagT = (unsigned long long*)carve((size_t)20 * 40 * 64 * 8);
  unsigned long long* mask = (unsigned long long*)carve((size_t)4 * MWORDS_PER_IMG * 8);
  // gtk (20*4096 u64 = 640KB) aliases mask: dead before k_mask writes it.
  unsigned long long* gtk = mask;
  (void)ws_size; (void)out_size;

  hipMemsetAsync(gcnt, 0, zero_bytes, stream);
  k_sig<<<dim3(18, 4), 1024, 0, stream>>>(p, u_arr, ghist);
  k_thresh<<<20, 1024, 0, stream>>>(u_arr, ghist, T64_arr);
  k_collect<<<dim3(18, 4), 1024, 0, stream>>>(u_arr, T64_arr, gtk, gcnt);
  k_rank<<<dim3(16, 20), 256, 0, stream>>>(p, gtk, gcnt, cand_box, cand_s,
                                           vflags);
  k_part<<<20, 256, 0, stream>>>(cand_box, cand_s, vflags,
      n_x1, n_y1, n_x2, n_y2, n_ar, n_sc, n_pos, V_arr);
  k_mask<<<dim3(807, 4), 256, 0, stream>>>(n_x1, n_y1, n_x2, n_y2, n_ar,
                                           mask, diagT);
  k_scan<<<20, 512, 0, stream>>>(mask, diagT, n_pos, n_sc, V_arr,
                                 kept_pos, kept_key, kept_cnt);
  k_merge<<<4, 1024, 0, stream>>>(cand_box, cand_s, kept_pos, kept_key,
                                  kept_cnt, (float*)d_out);
}

// Round 12
// 141.867 us; speedup vs baseline: 1.7077x; 1.0669x over previous
//
#include <hip/hip_runtime.h>
#include <cstdint>
#include <cstddef>

// ---------------- constants ----------------
__constant__ int LV_N[5]    = {49152, 12288, 3072, 768, 192};   // H*W*3
__constant__ int LV_K[5]    = {2000, 2000, 2000, 768, 192};     // min(PRE_NMS, N)
__constant__ int LV_OFF[5]  = {0, 2000, 4000, 6000, 6768};      // concat offsets
__constant__ int LV_UOFF[5] = {0, 49152, 61440, 64512, 65280};  // u-array offsets
__constant__ int LV_W[5]    = {128, 64, 32, 16, 8};
__constant__ int LV_S[5]    = {4, 8, 16, 32, 64};
__constant__ int LV_LOGHW[5]= {14, 12, 10, 8, 6};
// mask geometry (rows padded by 192 so scan prefetch needs no bounds tests)
__constant__ int WPL[5]     = {32, 32, 32, 12, 3};              // words per row
__constant__ int MOFF[5]    = {0, 70144, 140288, 210432, 221952};
__constant__ int MB_BASE[6] = {0, 256, 512, 768, 804, 807};     // mask-block bases
__constant__ int MB_CT[5]   = {8, 8, 8, 3, 1};                  // col tiles per lvl
__constant__ int SGB6[6]    = {0, 12, 15, 16, 17, 18};          // 4096-elem tile bases

#define M_TOT 6960
#define U_PER_IMG 65472
#define MAX_OUT 1000
#define MWORDS_PER_IMG 223104
#define CAP 4096

struct Ptrs { const float* cls[5]; const float* reg[5]; };

// ---------------- XLA:CPU-compatible expf (Cephes/Eigen pexp, FMA-contracted) ----
__device__ __forceinline__ float xla_expf(float x) {
  const float exp_hi = 88.3762626647950f;
  const float exp_lo = -88.3762626647949f;
  const float log2ef = 1.44269504088896341f;
  const float c1 = 0.693359375f;
  const float c2 = -2.12194440e-4f;
  const float p0 = 1.9875691500e-4f;
  const float p1 = 1.3981999507e-3f;
  const float p2 = 8.3334519073e-3f;
  const float p3 = 4.1665795894e-2f;
  const float p4 = 1.6666665459e-1f;
  const float p5 = 5.0000001201e-1f;
  float xx = fminf(fmaxf(x, exp_lo), exp_hi);
  float fx = floorf(__fmaf_rn(xx, log2ef, 0.5f));
  float r = __fmaf_rn(fx, -c1, xx);
  r = __fmaf_rn(fx, -c2, r);
  float z = __fmul_rn(r, r);
  float y = __fmaf_rn(p0, r, p1);
  y = __fmaf_rn(y, r, p2);
  y = __fmaf_rn(y, r, p3);
  y = __fmaf_rn(y, r, p4);
  y = __fmaf_rn(y, r, p5);
  y = __fmaf_rn(y, z, r);
  y = __fadd_rn(y, 1.0f);
  int n = (int)fx;
  float two_n = __uint_as_float((unsigned)(n + 127) << 23);
  return __fmul_rn(y, two_n);
}

__device__ __forceinline__ float ref_sigmoid(float x) {
  return __fdiv_rn(1.0f, __fadd_rn(1.0f, xla_expf(-x)));
}

// ================= K0: wide sigmoid + 4096-bin score-bit histogram ============
__global__ __launch_bounds__(1024) void k_sig(Ptrs p, unsigned* u_arr,
                                              unsigned* ghist) {
  const int img = blockIdx.y;
  const int bx = blockIdx.x;
  int lvl = 0;
  while (bx >= SGB6[lvl + 1]) ++lvl;
  const int N = LV_N[lvl], LOGHW = LV_LOGHW[lvl];
  const int HW = 1 << LOGHW;
  const int e0 = (bx - SGB6[lvl]) * 4096;
  const int e1 = (e0 + 4096 < N) ? e0 + 4096 : N;
  const int tid = (int)threadIdx.x;
  __shared__ unsigned h[4096];
  for (int e = tid; e < 4096; e += 1024) h[e] = 0;
  __syncthreads();
  const float* cls = p.cls[lvl] + (size_t)img * N;
  unsigned* u = u_arr + img * U_PER_IMG + LV_UOFF[lvl];
  for (int e = e0 + tid; e < e1; e += 1024) {
    float logit = cls[e];                  // plane-major: fully coalesced
    unsigned ub = __float_as_uint(ref_sigmoid(logit));
    int a = e >> LOGHW, pix = e & (HW - 1);
    u[pix * 3 + a] = ub;                   // channel-last (reference order)
    atomicAdd(&h[(ub >> 18) & 4095u], 1u);
  }
  __syncthreads();
  unsigned* gh = ghist + (size_t)(img * 5 + lvl) * 4096;
  for (int e = tid; e < 4096; e += 1024)
    if (h[e]) atomicAdd(&gh[e], h[e]);
}

// ================= K1a: threshold pick (O(bins), N-scan only on fallback) =====
__global__ __launch_bounds__(1024) void k_thresh(const unsigned* u_arr,
    const unsigned* ghist, unsigned long long* T64_arr) {
  const int blk = blockIdx.x;
  const int img = blk / 5, lvl = blk % 5;
  const int N = LV_N[lvl], K = LV_K[lvl];
  const int tid = (int)threadIdx.x;
  if (N <= K) { if (tid == 0) T64_arr[blk] = 0ULL; return; }
  __shared__ unsigned h[4096], sA[4096], sB[4096];
  __shared__ unsigned sh_D, sh_sD, sh_sD1;
  const unsigned* u = u_arr + img * U_PER_IMG + LV_UOFF[lvl];

  for (int e = tid; e < 4096; e += 1024)
    h[e] = ghist[(size_t)blk * 4096 + e];
  __syncthreads();

  unsigned long long prefix = 0;
  unsigned want = (unsigned)K, above = 0;
  const int shifts[6] = {50, 38, 26, 14, 2, 0};
  const int widths[6] = {12, 12, 12, 12, 12, 2};
  for (int rd = 0; rd < 6; ++rd) {
    const int shift = shifts[rd], width = widths[rd];
    const int nb = 1 << width;
    if (rd > 0) {                          // fallback: exact rescan (rare)
      for (int e = tid; e < nb; e += 1024) h[e] = 0;
      __syncthreads();
      for (int i = tid; i < N; i += 1024) {
        unsigned long long key =
            ((unsigned long long)u[i] << 32) | (unsigned)(~(unsigned)i);
        if ((key >> (shift + width)) == prefix)
          atomicAdd(&h[(unsigned)(key >> shift) & (unsigned)(nb - 1)], 1u);
      }
      __syncthreads();
    }
    // suffix scan s[d] = sum_{v>=d} h[v]
    unsigned *Ap = sA, *Bp = sB;
    for (int e = tid; e < nb; e += 1024) Ap[e] = h[e];
    __syncthreads();
    for (int off = 1; off < nb; off <<= 1) {
      for (int e = tid; e < nb; e += 1024)
        Bp[e] = Ap[e] + ((e + off < nb) ? Ap[e + off] : 0u);
      __syncthreads();
      unsigned* t = Ap; Ap = Bp; Bp = t;
    }
    for (int e = tid; e < nb; e += 1024) {
      unsigned s = Ap[e], sn = (e + 1 < nb) ? Ap[e + 1] : 0u;
      if (s >= want && sn < want) { sh_D = (unsigned)e; sh_sD = s; sh_sD1 = sn; }
    }
    __syncthreads();
    unsigned D = sh_D, sD = sh_sD, sD1 = sh_sD1;
    unsigned long long npref = (prefix << width) | (unsigned long long)D;
    if (above + sD <= (unsigned)CAP || rd == 5) {
      if (tid == 0) T64_arr[blk] = npref << shift;
      return;                              // uniform decision across block
    }
    above += sD1; want -= sD1; prefix = npref;
    __syncthreads();
  }
}

// ================= K1b: wide collect, ONE global atomic per block ============
__global__ __launch_bounds__(1024) void k_collect(const unsigned* u_arr,
    const unsigned long long* T64_arr, unsigned long long* gtk, unsigned* gcnt) {
  const int img = blockIdx.y;
  const int bx = blockIdx.x;
  int lvl = 0;
  while (bx >= SGB6[lvl + 1]) ++lvl;
  const int N = LV_N[lvl];
  const int e0 = (bx - SGB6[lvl]) * 4096;
  const int tid = (int)threadIdx.x;
  const int lane = tid & 63;
  const int w = tid >> 6;                     // 16 waves
  const unsigned long long T = T64_arr[img * 5 + lvl];
  const unsigned* u = u_arr + img * U_PER_IMG + LV_UOFF[lvl];

  __shared__ unsigned wcnt[64];               // [wave*4 + iter] -> offsets

  unsigned long long key0 = 0, key1 = 0, key2 = 0, key3 = 0;
  unsigned long long bm0, bm1, bm2, bm3;
  {
    int e = e0 + 0 * 1024 + tid;
    bool pr = false;
    if (e < N) { key0 = ((unsigned long long)u[e] << 32) | (unsigned)(~(unsigned)e); pr = key0 >= T; }
    bm0 = __ballot(pr);
    if (lane == 0) wcnt[w * 4 + 0] = (unsigned)__popcll(bm0);
  }
  {
    int e = e0 + 1 * 1024 + tid;
    bool pr = false;
    if (e < N) { key1 = ((unsigned long long)u[e] << 32) | (unsigned)(~(unsigned)e); pr = key1 >= T; }
    bm1 = __ballot(pr);
    if (lane == 0) wcnt[w * 4 + 1] = (unsigned)__popcll(bm1);
  }
  {
    int e = e0 + 2 * 1024 + tid;
    bool pr = false;
    if (e < N) { key2 = ((unsigned long long)u[e] << 32) | (unsigned)(~(unsigned)e); pr = key2 >= T; }
    bm2 = __ballot(pr);
    if (lane == 0) wcnt[w * 4 + 2] = (unsigned)__popcll(bm2);
  }
  {
    int e = e0 + 3 * 1024 + tid;
    bool pr = false;
    if (e < N) { key3 = ((unsigned long long)u[e] << 32) | (unsigned)(~(unsigned)e); pr = key3 >= T; }
    bm3 = __ballot(pr);
    if (lane == 0) wcnt[w * 4 + 3] = (unsigned)__popcll(bm3);
  }
  __syncthreads();
  if (tid < 64) {
    unsigned c = wcnt[tid];
    unsigned pre = c;
    #pragma unroll
    for (int off = 1; off < 64; off <<= 1) {
      unsigned t = __shfl_up(pre, off);
      if (tid >= off) pre += t;
    }
    unsigned total = __shfl(pre, 63);
    unsigned base = 0;
    if (tid == 63 && total) base = atomicAdd(gcnt + (img * 5 + lvl), total);
    base = __shfl(base, 63);
    wcnt[tid] = base + pre - c;               // exclusive (wave,iter) offset
  }
  __syncthreads();
  unsigned long long* dst = gtk + (size_t)(img * 5 + lvl) * CAP;
  const unsigned long long below = (1ULL << lane) - 1ULL;
  if ((bm0 >> lane) & 1ULL) {
    unsigned slot = wcnt[w * 4 + 0] + (unsigned)__popcll(bm0 & below);
    if (slot < (unsigned)CAP) dst[slot] = key0;
  }
  if ((bm1 >> lane) & 1ULL) {
    unsigned slot = wcnt[w * 4 + 1] + (unsigned)__popcll(bm1 & below);
    if (slot < (unsigned)CAP) dst[slot] = key1;
  }
  if ((bm2 >> lane) & 1ULL) {
    unsigned slot = wcnt[w * 4 + 2] + (unsigned)__popcll(bm2 & below);
    if (slot < (unsigned)CAP) dst[slot] = key2;
  }
  if ((bm3 >> lane) & 1ULL) {
    unsigned slot = wcnt[w * 4 + 3] + (unsigned)__popcll(bm3 & below);
    if (slot < (unsigned)CAP) dst[slot] = key3;
  }
}

// ================= K1c: brute-force rank + direct decode (no sort) ===========
// b128 broadcast LDS reads (2 keys/instr), 16 reads (32 keys) in flight, 4
// independent accumulators -> LDS latency fully covered. Uniform early-exit
// for row-tiles beyond cnt.
__global__ __launch_bounds__(256) void k_rank(Ptrs p,
    const unsigned long long* gtk, const unsigned* gcnt,
    float* cand_box, float* cand_s, unsigned long long* vflags) {
  const int il = (int)blockIdx.y;
  const int img = il / 5, lvl = il % 5;
  const int N = LV_N[lvl], K = LV_K[lvl], W = LV_W[lvl], S = LV_S[lvl];
  const int HW = N / 3;
  const float* reg = p.reg[lvl] + (size_t)img * 12 * HW;
  const int tid = (int)threadIdx.x;
  unsigned cnt = gcnt[il];
  if (cnt > (unsigned)CAP) cnt = CAP;
  if ((unsigned)blockIdx.x * 256u >= cnt) return;   // uniform: skip staging too
  const unsigned cnt32 = (cnt + 31u) & ~31u;
  __shared__ ulonglong2 keys2[CAP / 2];
  unsigned long long* keys = (unsigned long long*)keys2;
  const unsigned long long* src = gtk + (size_t)il * CAP;
  for (int e = tid; e < (int)cnt32; e += 256)
    keys[e] = (e < (int)cnt) ? src[e] : 0ULL;   // real keys >= 2^32 > 0 pad
  __syncthreads();
  const int s = (int)blockIdx.x * 256 + tid;
  if (s >= (int)cnt) return;
  const unsigned long long mykey = keys[s];
  unsigned r0 = 0, r1 = 0, r2 = 0, r3 = 0;
  const unsigned half = cnt32 >> 1;           // # of ulonglong2 entries
  for (unsigned j = 0; j < half; j += 16) {
    #pragma unroll
    for (int q = 0; q < 16; q += 4) {
      ulonglong2 a = keys2[j + q + 0];
      ulonglong2 b = keys2[j + q + 1];
      ulonglong2 cc = keys2[j + q + 2];
      ulonglong2 d = keys2[j + q + 3];
      r0 += (a.x > mykey ? 1u : 0u) + (a.y > mykey ? 1u : 0u);
      r1 += (b.x > mykey ? 1u : 0u) + (b.y > mykey ? 1u : 0u);
      r2 += (cc.x > mykey ? 1u : 0u) + (cc.y > mykey ? 1u : 0u);
      r3 += (d.x > mykey ? 1u : 0u) + (d.y > mykey ? 1u : 0u);
    }
  }
  unsigned rank = r0 + r1 + r2 + r3;
  if (rank >= (unsigned)K) return;

  unsigned ubits = (unsigned)(mykey >> 32);
  unsigned idx = ~((unsigned)mykey);
  int a = (int)(idx % 3u); int pix = (int)(idx / 3u);
  int xq = pix % W, yq = pix / W;
  float dx = reg[(a * 4 + 0) * HW + pix];
  float dy = reg[(a * 4 + 1) * HW + pix];
  float dw = reg[(a * 4 + 2) * HW + pix];
  float dh = reg[(a * 4 + 3) * HW + pix];
  double rr = (a == 0) ? 0.5 : (a == 1 ? 1.0 : 2.0);
  double hr = sqrt(rr), wr = 1.0 / hr;
  double st = (double)S;
  double wsd = st * wr * 8.0, hsd = st * hr * 8.0;
  double sxd = (double)(xq * S), syd = (double)(yq * S);
  float a0 = (float)(sxd - 0.5 * wsd), a1 = (float)(syd - 0.5 * hsd);
  float a2 = (float)(sxd + 0.5 * wsd), a3 = (float)(syd + 0.5 * hsd);
  float px = __fmul_rn(__fadd_rn(a0, a2), 0.5f);
  float py = __fmul_rn(__fadd_rn(a1, a3), 0.5f);
  float pw = __fsub_rn(a2, a0), ph = __fsub_rn(a3, a1);
  const float MRf = 4.135166556742356f;  // |log(16/1000)| rounded to f32
  float dwc = fminf(fmaxf(dw, -MRf), MRf);
  float dhc = fminf(fmaxf(dh, -MRf), MRf);
  float gw = __fmul_rn(pw, xla_expf(dwc));
  float gh = __fmul_rn(ph, xla_expf(dhc));
  float gx = __fmaf_rn(pw, dx, px);
  float gy = __fmaf_rn(ph, dy, py);
  float x1 = fminf(fmaxf(__fmaf_rn(gw, -0.5f, gx), 0.0f), 512.0f);
  float y1 = fminf(fmaxf(__fmaf_rn(gh, -0.5f, gy), 0.0f), 512.0f);
  float x2 = fminf(fmaxf(__fmaf_rn(gw,  0.5f, gx), 0.0f), 512.0f);
  float y2 = fminf(fmaxf(__fmaf_rn(gh,  0.5f, gy), 0.0f), 512.0f);
  bool valid = (__fsub_rn(x2, x1) > 0.0f) && (__fsub_rn(y2, y1) > 0.0f);
  int pos = img * M_TOT + LV_OFF[lvl] + (int)rank;
  cand_box[(size_t)pos * 4 + 0] = x1;
  cand_box[(size_t)pos * 4 + 1] = y1;
  cand_box[(size_t)pos * 4 + 2] = x2;
  cand_box[(size_t)pos * 4 + 3] = y2;
  float score = __uint_as_float(ubits);
  cand_s[pos] = valid ? score : -1.0f;
  if (valid)
    atomicOr(&vflags[(size_t)il * 32 + (rank >> 6)], 1ULL << (rank & 63));
}

// ================= K1d: partition (valids first) + NMS-order arrays ==========
__global__ __launch_bounds__(256) void k_part(const float* cand_box,
    const float* cand_s, const unsigned long long* vflags,
    float* n_x1, float* n_y1, float* n_x2, float* n_y2, float* n_ar,
    float* n_sc, unsigned* n_pos, unsigned* V_arr) {
  const int il = (int)blockIdx.x;
  const int img = il / 5, lvl = il % 5;
  const int K = LV_K[lvl];
  const int tid = (int)threadIdx.x;
  __shared__ unsigned long long sflag[32];
  __shared__ unsigned wpre[33];
  if (tid < 32) sflag[tid] = vflags[(size_t)il * 32 + tid];
  __syncthreads();
  if (tid < 32) {
    unsigned c = (unsigned)__popcll(sflag[tid]);
    #pragma unroll
    for (int off = 1; off < 32; off <<= 1) {
      unsigned t = __shfl_up(c, off);
      if (tid >= off) c += t;
    }
    wpre[tid + 1] = c;
    if (tid == 0) wpre[0] = 0;
  }
  __syncthreads();
  const unsigned V = wpre[32];
  const float offv = __fmul_rn((float)lvl, 513.0f);
  const int base = img * M_TOT + LV_OFF[lvl];
  for (int r = tid; r < K; r += 256) {
    unsigned long long word = sflag[r >> 6];
    unsigned fl = (unsigned)((word >> (r & 63)) & 1ULL);
    unsigned excl = wpre[r >> 6] +
                    (unsigned)__popcll(word & ((1ULL << (r & 63)) - 1ULL));
    unsigned pdst = fl ? excl : V + ((unsigned)r - excl);
    const float* b = cand_box + (size_t)(base + r) * 4;
    float ox1 = __fadd_rn(b[0], offv), oy1 = __fadd_rn(b[1], offv);
    float ox2 = __fadd_rn(b[2], offv), oy2 = __fadd_rn(b[3], offv);
    int dst = base + (int)pdst;
    n_x1[dst] = ox1; n_y1[dst] = oy1; n_x2[dst] = ox2; n_y2[dst] = oy2;
    n_ar[dst] = __fmul_rn(__fsub_rn(ox2, ox1), __fsub_rn(oy2, oy1));
    n_sc[dst] = cand_s[base + r];
    n_pos[dst] = (unsigned)(LV_OFF[lvl] + r);
  }
  if (tid == 0) V_arr[il] = V;
}

// ================= K2a: suppression bit-matrix build + diag transpose ========
#define TSTAGE(S, M)                                                        \
  {                                                                         \
    unsigned long long t_ = __shfl_xor(x, S);                               \
    x = (lane & S) ? ((x & (M)) | ((t_ >> S) & ~(M)))                       \
                   : ((x & ~(M)) | ((t_ << S) & (M)));                      \
  }

__global__ __launch_bounds__(256) void k_mask(
    const float* n_x1, const float* n_y1, const float* n_x2, const float* n_y2,
    const float* n_ar, unsigned long long* mask, unsigned long long* diagT) {
  const int img = blockIdx.y;
  const int bx = blockIdx.x;
  int lvl = 0;
  while (bx >= MB_BASE[lvl + 1]) ++lvl;
  const int t = bx - MB_BASE[lvl];
  const int ct = MB_CT[lvl];
  const int rt = t / ct, c = t % ct;
  const int K = LV_K[lvl];
  const int row0 = rt * 64, col0 = c * 256;
  if (col0 + 255 <= row0) return;  // entire tile has j <= r: bits never consumed

  __shared__ float4 cb4[256];
  __shared__ float cba[256];
  __shared__ float4 rb4[64];
  __shared__ float rba[64];
  const int base = img * M_TOT + LV_OFF[lvl];
  const int tid = (int)threadIdx.x;
  if (tid < 64) {
    int r = row0 + tid;
    if (r < K) {
      rb4[tid] = make_float4(n_x1[base + r], n_y1[base + r],
                             n_x2[base + r], n_y2[base + r]);
      rba[tid] = n_ar[base + r];
    } else {
      rb4[tid] = make_float4(0.f, 0.f, 0.f, 0.f);
      rba[tid] = 0.f;
    }
  }
  {
    int j = col0 + tid;
    if (j < K) {
      cb4[tid] = make_float4(n_x1[base + j], n_y1[base + j],
                             n_x2[base + j], n_y2[base + j]);
      cba[tid] = n_ar[base + j];
    }
  }
  __syncthreads();
  const int wl = tid >> 6, lane = tid & 63;
  const int r = row0 + lane;
  const bool rvalid = (r < K);
  const float4 rb = rb4[lane];
  const float rar = rba[lane];
  unsigned long long word = 0ULL;
  const int jbase = wl * 64;
  const int jmax = K - col0 - jbase;   // bit k valid iff k < jmax
  #pragma unroll 16
  for (int k = 0; k < 64; ++k) {
    float4 cb = cb4[jbase + k];        // broadcast: all lanes same address
    float car = cba[jbase + k];
    float iw = fmaxf(__fsub_rn(fminf(rb.z, cb.z), fmaxf(rb.x, cb.x)), 0.0f);
    float ih = fmaxf(__fsub_rn(fminf(rb.w, cb.w), fmaxf(rb.y, cb.y)), 0.0f);
    float inter = __fmul_rn(iw, ih);
    float uni = __fsub_rn(__fadd_rn(rar, car), inter);
    float iou = (uni > 0.0f) ? __fdiv_rn(inter, uni) : 0.0f;
    if (iou > 0.7f && k < jmax) word |= (1ULL << k);
  }
  if (!rvalid) word = 0ULL;
  if (rvalid)
    mask[(size_t)img * MWORDS_PER_IMG + MOFF[lvl] +
         (size_t)r * WPL[lvl] + (size_t)((col0 >> 6) + wl)] = word;
  // diag 64x64 block of this chunk lives in word wl where col0+64*wl == row0:
  // transpose it across lanes (lane i -> column i) and store to diagT.
  if (col0 + (wl << 6) == row0) {
    unsigned long long x = word;
    TSTAGE(32, 0xFFFFFFFF00000000ULL)
    TSTAGE(16, 0xFFFF0000FFFF0000ULL)
    TSTAGE(8,  0xFF00FF00FF00FF00ULL)
    TSTAGE(4,  0xF0F0F0F0F0F0F0F0ULL)
    TSTAGE(2,  0xCCCCCCCCCCCCCCCCULL)
    TSTAGE(1,  0xAAAAAAAAAAAAAAAAULL)
    diagT[(size_t)(img * 5 + lvl) * (40 * 64) + (size_t)rt * 64 + lane] = x;
  }
}

// ================= K2b: 8-wave chunked greedy scan ===========================
#define SCAN_CHUNK(P0, P1, P2, P3)                                          \
  {                                                                         \
    const int r0 = c << 6;                                                  \
    if (w == (c & 7)) {                                                     \
      unsigned long long v = (g == (c >> 3)) ? aw : ~0ULL;                  \
      v &= __shfl_xor(v, 1);                                                \
      v &= __shfl_xor(v, 2);                                                \
      v &= __shfl_xor(v, 4);                                                \
      v &= __shfl_xor(v, 8);                                                \
      v = __shfl(v, (c >> 3) * 16);                                         \
      unsigned long long x = dg;                                            \
      unsigned long long kw = v;                                            \
      while (true) {                                                        \
        bool keep_j = (((v >> lane) & 1ULL) != 0ULL) &&                     \
                      ((kw & below & x) == 0ULL);                           \
        unsigned long long nkw = __ballot(keep_j);                          \
        if (nkw == kw) break;                                               \
        kw = nkw;                                                           \
      }                                                                     \
      if ((kw >> lane) & 1ULL)                                              \
        skept[kept + (int)__popcll(kw & below)] = (unsigned)(r0 + lane);    \
      if (lane == 0) s_kw[c & 1] = kw;                                      \
      int no_ = next_own < 40 ? next_own : 39;                              \
      dg = dT[(size_t)no_ * 64 + lane];                                     \
      next_own += 8;                                                        \
    }                                                                       \
    __syncthreads();                                                        \
    unsigned long long kwv = s_kw[c & 1];                                   \
    kept += (int)__popcll(kwv);                                             \
    aw &= ~(P0 & (unsigned long long)((long long)(kwv << (63 - (d0 + 0))) >> 63)); \
    aw &= ~(P1 & (unsigned long long)((long long)(kwv << (63 - (d0 + 1))) >> 63)); \
    aw &= ~(P2 & (unsigned long long)((long long)(kwv << (63 - (d0 + 2))) >> 63)); \
    aw &= ~(P3 & (unsigned long long)((long long)(kwv << (63 - (d0 + 3))) >> 63)); \
    P0 = mb[(size_t)(r0 + 128 + d0 + 0) * wpl + wkc];                       \
    P1 = mb[(size_t)(r0 + 128 + d0 + 1) * wpl + wkc];                       \
    P2 = mb[(size_t)(r0 + 128 + d0 + 2) * wpl + wkc];                       \
    P3 = mb[(size_t)(r0 + 128 + d0 + 3) * wpl + wkc];                       \
    ++c;                                                                    \
  }

__global__ __launch_bounds__(512) void k_scan(const unsigned long long* mask,
    const unsigned long long* diagT,
    const unsigned* n_pos, const float* n_sc, const unsigned* V_arr,
    unsigned* kept_pos, unsigned long long* kept_key, unsigned* kept_cnt) {
  const int il = (int)blockIdx.x;
  const int img = il / 5, lvl = il % 5;
  const int K = LV_K[lvl], wpl = WPL[lvl];
  const int tid = (int)threadIdx.x;
  const int w = tid >> 6, lane = tid & 63;
  const unsigned long long* mb =
      mask + (size_t)img * MWORDS_PER_IMG + MOFF[lvl];
  const unsigned long long* dT = diagT + (size_t)il * (40 * 64);

  __shared__ unsigned long long s_kw[2];
  __shared__ unsigned skept[MAX_OUT + 64];

  const int g = lane >> 4;
  const int wk = w + 8 * g;
  const int wkc = wk < wpl ? wk : 0;      // clamped (dup loads harmless)
  const int d0 = (lane & 15) * 4;         // my 4 suppression rows per chunk
  const unsigned long long below = (1ULL << lane) - 1ULL;

  const int V = (int)V_arr[il];
  unsigned long long aw;
  {
    int lo = wk * 64, hi = V < lo + 64 ? V : lo + 64;
    aw = (hi > lo) ? ((hi - lo == 64) ? ~0ULL : ((1ULL << (hi - lo)) - 1ULL))
                   : 0ULL;
  }

  const int nchunks = (K + 63) >> 6;
  unsigned long long pfA0 = mb[(size_t)(d0 + 0) * wpl + wkc];
  unsigned long long pfA1 = mb[(size_t)(d0 + 1) * wpl + wkc];
  unsigned long long pfA2 = mb[(size_t)(d0 + 2) * wpl + wkc];
  unsigned long long pfA3 = mb[(size_t)(d0 + 3) * wpl + wkc];
  unsigned long long pfB0 = mb[(size_t)(64 + d0 + 0) * wpl + wkc];
  unsigned long long pfB1 = mb[(size_t)(64 + d0 + 1) * wpl + wkc];
  unsigned long long pfB2 = mb[(size_t)(64 + d0 + 2) * wpl + wkc];
  unsigned long long pfB3 = mb[(size_t)(64 + d0 + 3) * wpl + wkc];
  unsigned long long dg = dT[(size_t)w * 64 + lane];
  int next_own = w + 8;

  int kept = 0;
  int c = 0;
  while (c < nchunks && kept < MAX_OUT) {
    SCAN_CHUNK(pfA0, pfA1, pfA2, pfA3)
    if (c >= nchunks || kept >= MAX_OUT) break;
    SCAN_CHUNK(pfB0, pfB1, pfB2, pfB3)
  }

  __syncthreads();
  const int kc = kept < MAX_OUT ? kept : MAX_OUT;
  const int base = img * M_TOT + LV_OFF[lvl];
  const size_t bo = (size_t)il * 1024;
  for (int i = tid; i < kc; i += 512) {
    unsigned r = skept[i];
    unsigned pp = n_pos[base + (int)r];
    kept_pos[bo + i] = pp;
    kept_key[bo + i] =
        ((unsigned long long)__float_as_uint(n_sc[base + (int)r]) << 32) |
        (unsigned)(~pp);
  }
  if (tid == 0) kept_cnt[il] = (unsigned)kc;
}

// ================= K3: per-image merge of kept lists -> output rows ===========
__global__ __launch_bounds__(1024) void k_merge(const float* cand_box,
    const float* cand_s, const unsigned* kept_pos,
    const unsigned long long* kept_key, const unsigned* kept_cnt, float* out) {
  const int img = blockIdx.x;
  const int tid = (int)threadIdx.x;
  __shared__ unsigned cnts[5];
  __shared__ unsigned long long skey[5][1024];
  if (tid < 5) {
    unsigned c = kept_cnt[img * 5 + tid];
    cnts[tid] = c < (unsigned)MAX_OUT ? c : (unsigned)MAX_OUT;
  }
  __syncthreads();
  for (int e = tid; e < 5 * 1024; e += 1024) {
    int l = e >> 10, s = e & 1023;
    skey[l][s] = (s < (int)cnts[l])
        ? kept_key[(size_t)(img * 5 + l) * 1024 + s] : 0ULL;
  }
  __syncthreads();
  unsigned T = cnts[0] + cnts[1] + cnts[2] + cnts[3] + cnts[4];
  unsigned Tc = T < (unsigned)MAX_OUT ? T : (unsigned)MAX_OUT;
  for (int r = (int)Tc + tid; r < MAX_OUT; r += 1024) {
    float* o = out + (size_t)img * (MAX_OUT * 5) + (size_t)r * 5;
    o[0] = 0.f; o[1] = 0.f; o[2] = 0.f; o[3] = 0.f; o[4] = 0.f;
  }
  for (int e = tid; e < 5 * 1024; e += 1024) {
    int l = e >> 10, s = e & 1023;
    if (s >= (int)cnts[l]) continue;
    unsigned long long k0 = skey[l][s];
    unsigned rank = (unsigned)s;
    #pragma unroll
    for (int l2 = 0; l2 < 5; ++l2) {
      if (l2 == l) continue;
      int lo = 0, hi = (int)cnts[l2];
      while (lo < hi) {
        int mid = (lo + hi) >> 1;
        if (skey[l2][mid] > k0) lo = mid + 1; else hi = mid;
      }
      rank += (unsigned)lo;
    }
    if (rank < (unsigned)MAX_OUT) {
      unsigned pos = kept_pos[(size_t)(img * 5 + l) * 1024 + s];
      const float* b = cand_box + (size_t)(img * M_TOT + pos) * 4;
      float* o = out + (size_t)img * (MAX_OUT * 5) + (size_t)rank * 5;
      o[0] = b[0]; o[1] = b[1]; o[2] = b[2]; o[3] = b[3];
      o[4] = cand_s[img * M_TOT + pos];
    }
  }
}

// ================= host launch =================
extern "C" void kernel_launch(void* const* d_in, const int* in_sizes, int n_in,
                              void* d_out, int out_size, void* d_ws, size_t ws_size,
                              hipStream_t stream) {
  Ptrs p;
  bool interleaved = (n_in == 10 && in_sizes[1] == 4 * 12 * 128 * 128);
  for (int l = 0; l < 5; ++l) {
    if (interleaved) {
      p.cls[l] = (const float*)d_in[2 * l];
      p.reg[l] = (const float*)d_in[2 * l + 1];
    } else {
      p.cls[l] = (const float*)d_in[l];
      p.reg[l] = (const float*)d_in[5 + l];
    }
  }
  uint8_t* w = (uint8_t*)d_ws;
  size_t o = 0;
  auto carve = [&](size_t bytes) {
    void* ptr = w + o;
    o += (bytes + 255) & ~(size_t)255;
    return ptr;
  };
  // gcnt + ghist + vflags adjacent -> one memset zeroes all three
  unsigned* gcnt = (unsigned*)carve((size_t)20 * 4);                 // 256B slot
  unsigned* ghist = (unsigned*)carve((size_t)20 * 4096 * 4);
  unsigned long long* vflags = (unsigned long long*)carve((size_t)20 * 32 * 8);
  size_t zero_bytes = 256 + (size_t)20 * 4096 * 4 + (size_t)20 * 32 * 8;
  unsigned long long* T64_arr = (unsigned long long*)carve((size_t)20 * 8);
  unsigned* u_arr = (unsigned*)carve((size_t)4 * U_PER_IMG * 4);
  float* cand_box = (float*)carve((size_t)4 * M_TOT * 4 * 4);
  float* cand_s = (float*)carve((size_t)4 * M_TOT * 4);
  float* n_x1 = (float*)carve((size_t)4 * M_TOT * 4);
  float* n_y1 = (float*)carve((size_t)4 * M_TOT * 4);
  float* n_x2 = (float*)carve((size_t)4 * M_TOT * 4);
  float* n_y2 = (float*)carve((size_t)4 * M_TOT * 4);
  float* n_ar = (float*)carve((size_t)4 * M_TOT * 4);
  float* n_sc = (float*)carve((size_t)4 * M_TOT * 4);
  unsigned* n_pos = (unsigned*)carve((size_t)4 * M_TOT * 4);
  unsigned* V_arr = (unsigned*)carve((size_t)20 * 4);
  unsigned* kept_pos = (unsigned*)carve((size_t)4 * 5 * 1024 * 4);
  unsigned long long* kept_key = (unsigned long long*)carve((size_t)4 * 5 * 1024 * 8);
  unsigned* kept_cnt = (unsigned*)carve((size_t)20 * 4);
  unsigned long long* diagT = (unsigned long long*)carve((size_t)20 * 40 * 64 * 8);
  unsigned long long* mask = (unsigned long long*)carve((size_t)4 * MWORDS_PER_IMG * 8);
  // gtk (20*4096 u64 = 640KB) aliases mask: dead before k_mask writes it.
  unsigned long long* gtk = mask;
  (void)ws_size; (void)out_size;

  hipMemsetAsync(gcnt, 0, zero_bytes, stream);
  k_sig<<<dim3(18, 4), 1024, 0, stream>>>(p, u_arr, ghist);
  k_thresh<<<20, 1024, 0, stream>>>(u_arr, ghist, T64_arr);
  k_collect<<<dim3(18, 4), 1024, 0, stream>>>(u_arr, T64_arr, gtk, gcnt);
  k_rank<<<dim3(16, 20), 256, 0, stream>>>(p, gtk, gcnt, cand_box, cand_s,
                                           vflags);
  k_part<<<20, 256, 0, stream>>>(cand_box, cand_s, vflags,
      n_x1, n_y1, n_x2, n_y2, n_ar, n_sc, n_pos, V_arr);
  k_mask<<<dim3(807, 4), 256, 0, stream>>>(n_x1, n_y1, n_x2, n_y2, n_ar,
                                           mask, diagT);
  k_scan<<<20, 512, 0, stream>>>(mask, diagT, n_pos, n_sc, V_arr,
                                 kept_pos, kept_key, kept_cnt);
  k_merge<<<4, 1024, 0, stream>>>(cand_box, cand_s, kept_pos, kept_key,
                                  kept_cnt, (float*)d_out);
}

// Round 13
// 135.452 us; speedup vs baseline: 1.7886x; 1.0474x over previous
//
#include <hip/hip_runtime.h>
#include <cstdint>
#include <cstddef>

// ---------------- constants ----------------
__constant__ int LV_N[5]    = {49152, 12288, 3072, 768, 192};   // H*W*3
__constant__ int LV_K[5]    = {2000, 2000, 2000, 768, 192};     // min(PRE_NMS, N)
__constant__ int LV_OFF[5]  = {0, 2000, 4000, 6000, 6768};      // concat offsets
__constant__ int LV_UOFF[5] = {0, 49152, 61440, 64512, 65280};  // u-array offsets
__constant__ int LV_W[5]    = {128, 64, 32, 16, 8};
__constant__ int LV_S[5]    = {4, 8, 16, 32, 64};
__constant__ int LV_LOGHW[5]= {14, 12, 10, 8, 6};
// mask geometry (rows padded by 192 so scan prefetch needs no bounds tests)
__constant__ int WPL[5]     = {32, 32, 32, 12, 3};              // words per row
__constant__ int MOFF[5]    = {0, 70144, 140288, 210432, 221952};
__constant__ int MB_BASE[6] = {0, 256, 512, 768, 804, 807};     // mask-block bases
__constant__ int MB_CT[5]   = {8, 8, 8, 3, 1};                  // col tiles per lvl
__constant__ int SGB6[6]    = {0, 12, 15, 16, 17, 18};          // 4096-elem tile bases

#define M_TOT 6960
#define U_PER_IMG 65472
#define MAX_OUT 1000
#define MWORDS_PER_IMG 223104
#define CAP 4096

struct Ptrs { const float* cls[5]; const float* reg[5]; };

// fl(inter/uni) > 0.7f  <=>  inter/uni >= MTH  (tie at MTH rounds to even
// mantissa 0x3F333334 > 0.7f). Evaluated in f64: exact except a ~2^-53 band.
#define MTH 0.7000000178813934326171875

// ---------------- XLA:CPU-compatible expf (Cephes/Eigen pexp, FMA-contracted) ----
__device__ __forceinline__ float xla_expf(float x) {
  const float exp_hi = 88.3762626647950f;
  const float exp_lo = -88.3762626647949f;
  const float log2ef = 1.44269504088896341f;
  const float c1 = 0.693359375f;
  const float c2 = -2.12194440e-4f;
  const float p0 = 1.9875691500e-4f;
  const float p1 = 1.3981999507e-3f;
  const float p2 = 8.3334519073e-3f;
  const float p3 = 4.1665795894e-2f;
  const float p4 = 1.6666665459e-1f;
  const float p5 = 5.0000001201e-1f;
  float xx = fminf(fmaxf(x, exp_lo), exp_hi);
  float fx = floorf(__fmaf_rn(xx, log2ef, 0.5f));
  float r = __fmaf_rn(fx, -c1, xx);
  r = __fmaf_rn(fx, -c2, r);
  float z = __fmul_rn(r, r);
  float y = __fmaf_rn(p0, r, p1);
  y = __fmaf_rn(y, r, p2);
  y = __fmaf_rn(y, r, p3);
  y = __fmaf_rn(y, r, p4);
  y = __fmaf_rn(y, r, p5);
  y = __fmaf_rn(y, z, r);
  y = __fadd_rn(y, 1.0f);
  int n = (int)fx;
  float two_n = __uint_as_float((unsigned)(n + 127) << 23);
  return __fmul_rn(y, two_n);
}

__device__ __forceinline__ float ref_sigmoid(float x) {
  return __fdiv_rn(1.0f, __fadd_rn(1.0f, xla_expf(-x)));
}

// ================= K-1: fast zero of gcnt+ghist+vflags ======================
__global__ __launch_bounds__(256) void k_zero(uint4* ptr, int n4) {
  int i = (int)blockIdx.x * 256 + (int)threadIdx.x;
  if (i < n4) ptr[i] = make_uint4(0u, 0u, 0u, 0u);
}

// ================= K0: wide sigmoid + 4096-bin score-bit histogram ============
__global__ __launch_bounds__(1024) void k_sig(Ptrs p, unsigned* u_arr,
                                              unsigned* ghist) {
  const int img = blockIdx.y;
  const int bx = blockIdx.x;
  int lvl = 0;
  while (bx >= SGB6[lvl + 1]) ++lvl;
  const int N = LV_N[lvl], LOGHW = LV_LOGHW[lvl];
  const int HW = 1 << LOGHW;
  const int e0 = (bx - SGB6[lvl]) * 4096;
  const int e1 = (e0 + 4096 < N) ? e0 + 4096 : N;
  const int tid = (int)threadIdx.x;
  __shared__ unsigned h[4096];
  for (int e = tid; e < 4096; e += 1024) h[e] = 0;
  __syncthreads();
  const float* cls = p.cls[lvl] + (size_t)img * N;
  unsigned* u = u_arr + img * U_PER_IMG + LV_UOFF[lvl];
  for (int e = e0 + tid; e < e1; e += 1024) {
    float logit = cls[e];                  // plane-major: fully coalesced
    unsigned ub = __float_as_uint(ref_sigmoid(logit));
    int a = e >> LOGHW, pix = e & (HW - 1);
    u[pix * 3 + a] = ub;                   // channel-last (reference order)
    atomicAdd(&h[(ub >> 18) & 4095u], 1u);
  }
  __syncthreads();
  unsigned* gh = ghist + (size_t)(img * 5 + lvl) * 4096;
  for (int e = tid; e < 4096; e += 1024)
    if (h[e]) atomicAdd(&gh[e], h[e]);
}

// ================= K1a: threshold pick (O(bins), N-scan only on fallback) =====
__global__ __launch_bounds__(1024) void k_thresh(const unsigned* u_arr,
    const unsigned* ghist, unsigned long long* T64_arr) {
  const int blk = blockIdx.x;
  const int img = blk / 5, lvl = blk % 5;
  const int N = LV_N[lvl], K = LV_K[lvl];
  const int tid = (int)threadIdx.x;
  if (N <= K) { if (tid == 0) T64_arr[blk] = 0ULL; return; }
  __shared__ unsigned h[4096], sA[4096], sB[4096];
  __shared__ unsigned sh_D, sh_sD, sh_sD1;
  const unsigned* u = u_arr + img * U_PER_IMG + LV_UOFF[lvl];

  for (int e = tid; e < 4096; e += 1024)
    h[e] = ghist[(size_t)blk * 4096 + e];
  __syncthreads();

  unsigned long long prefix = 0;
  unsigned want = (unsigned)K, above = 0;
  const int shifts[6] = {50, 38, 26, 14, 2, 0};
  const int widths[6] = {12, 12, 12, 12, 12, 2};
  for (int rd = 0; rd < 6; ++rd) {
    const int shift = shifts[rd], width = widths[rd];
    const int nb = 1 << width;
    if (rd > 0) {                          // fallback: exact rescan (rare)
      for (int e = tid; e < nb; e += 1024) h[e] = 0;
      __syncthreads();
      for (int i = tid; i < N; i += 1024) {
        unsigned long long key =
            ((unsigned long long)u[i] << 32) | (unsigned)(~(unsigned)i);
        if ((key >> (shift + width)) == prefix)
          atomicAdd(&h[(unsigned)(key >> shift) & (unsigned)(nb - 1)], 1u);
      }
      __syncthreads();
    }
    // suffix scan s[d] = sum_{v>=d} h[v]
    unsigned *Ap = sA, *Bp = sB;
    for (int e = tid; e < nb; e += 1024) Ap[e] = h[e];
    __syncthreads();
    for (int off = 1; off < nb; off <<= 1) {
      for (int e = tid; e < nb; e += 1024)
        Bp[e] = Ap[e] + ((e + off < nb) ? Ap[e + off] : 0u);
      __syncthreads();
      unsigned* t = Ap; Ap = Bp; Bp = t;
    }
    for (int e = tid; e < nb; e += 1024) {
      unsigned s = Ap[e], sn = (e + 1 < nb) ? Ap[e + 1] : 0u;
      if (s >= want && sn < want) { sh_D = (unsigned)e; sh_sD = s; sh_sD1 = sn; }
    }
    __syncthreads();
    unsigned D = sh_D, sD = sh_sD, sD1 = sh_sD1;
    unsigned long long npref = (prefix << width) | (unsigned long long)D;
    if (above + sD <= (unsigned)CAP || rd == 5) {
      if (tid == 0) T64_arr[blk] = npref << shift;
      return;                              // uniform decision across block
    }
    above += sD1; want -= sD1; prefix = npref;
    __syncthreads();
  }
}

// ================= K1b: wide collect, ONE global atomic per block ============
__global__ __launch_bounds__(1024) void k_collect(const unsigned* u_arr,
    const unsigned long long* T64_arr, unsigned long long* gtk, unsigned* gcnt) {
  const int img = blockIdx.y;
  const int bx = blockIdx.x;
  int lvl = 0;
  while (bx >= SGB6[lvl + 1]) ++lvl;
  const int N = LV_N[lvl];
  const int e0 = (bx - SGB6[lvl]) * 4096;
  const int tid = (int)threadIdx.x;
  const int lane = tid & 63;
  const int w = tid >> 6;                     // 16 waves
  const unsigned long long T = T64_arr[img * 5 + lvl];
  const unsigned* u = u_arr + img * U_PER_IMG + LV_UOFF[lvl];

  __shared__ unsigned wcnt[64];               // [wave*4 + iter] -> offsets

  unsigned long long key0 = 0, key1 = 0, key2 = 0, key3 = 0;
  unsigned long long bm0, bm1, bm2, bm3;
  {
    int e = e0 + 0 * 1024 + tid;
    bool pr = false;
    if (e < N) { key0 = ((unsigned long long)u[e] << 32) | (unsigned)(~(unsigned)e); pr = key0 >= T; }
    bm0 = __ballot(pr);
    if (lane == 0) wcnt[w * 4 + 0] = (unsigned)__popcll(bm0);
  }
  {
    int e = e0 + 1 * 1024 + tid;
    bool pr = false;
    if (e < N) { key1 = ((unsigned long long)u[e] << 32) | (unsigned)(~(unsigned)e); pr = key1 >= T; }
    bm1 = __ballot(pr);
    if (lane == 0) wcnt[w * 4 + 1] = (unsigned)__popcll(bm1);
  }
  {
    int e = e0 + 2 * 1024 + tid;
    bool pr = false;
    if (e < N) { key2 = ((unsigned long long)u[e] << 32) | (unsigned)(~(unsigned)e); pr = key2 >= T; }
    bm2 = __ballot(pr);
    if (lane == 0) wcnt[w * 4 + 2] = (unsigned)__popcll(bm2);
  }
  {
    int e = e0 + 3 * 1024 + tid;
    bool pr = false;
    if (e < N) { key3 = ((unsigned long long)u[e] << 32) | (unsigned)(~(unsigned)e); pr = key3 >= T; }
    bm3 = __ballot(pr);
    if (lane == 0) wcnt[w * 4 + 3] = (unsigned)__popcll(bm3);
  }
  __syncthreads();
  if (tid < 64) {
    unsigned c = wcnt[tid];
    unsigned pre = c;
    #pragma unroll
    for (int off = 1; off < 64; off <<= 1) {
      unsigned t = __shfl_up(pre, off);
      if (tid >= off) pre += t;
    }
    unsigned total = __shfl(pre, 63);
    unsigned base = 0;
    if (tid == 63 && total) base = atomicAdd(gcnt + (img * 5 + lvl), total);
    base = __shfl(base, 63);
    wcnt[tid] = base + pre - c;               // exclusive (wave,iter) offset
  }
  __syncthreads();
  unsigned long long* dst = gtk + (size_t)(img * 5 + lvl) * CAP;
  const unsigned long long below = (1ULL << lane) - 1ULL;
  if ((bm0 >> lane) & 1ULL) {
    unsigned slot = wcnt[w * 4 + 0] + (unsigned)__popcll(bm0 & below);
    if (slot < (unsigned)CAP) dst[slot] = key0;
  }
  if ((bm1 >> lane) & 1ULL) {
    unsigned slot = wcnt[w * 4 + 1] + (unsigned)__popcll(bm1 & below);
    if (slot < (unsigned)CAP) dst[slot] = key1;
  }
  if ((bm2 >> lane) & 1ULL) {
    unsigned slot = wcnt[w * 4 + 2] + (unsigned)__popcll(bm2 & below);
    if (slot < (unsigned)CAP) dst[slot] = key2;
  }
  if ((bm3 >> lane) & 1ULL) {
    unsigned slot = wcnt[w * 4 + 3] + (unsigned)__popcll(bm3 & below);
    if (slot < (unsigned)CAP) dst[slot] = key3;
  }
}

// ================= K1c: brute-force rank + direct decode (no sort) ===========
__global__ __launch_bounds__(256) void k_rank(Ptrs p,
    const unsigned long long* gtk, const unsigned* gcnt,
    float* cand_box, float* cand_s, unsigned long long* vflags) {
  const int il = (int)blockIdx.y;
  const int img = il / 5, lvl = il % 5;
  const int N = LV_N[lvl], K = LV_K[lvl], W = LV_W[lvl], S = LV_S[lvl];
  const int HW = N / 3;
  const float* reg = p.reg[lvl] + (size_t)img * 12 * HW;
  const int tid = (int)threadIdx.x;
  unsigned cnt = gcnt[il];
  if (cnt > (unsigned)CAP) cnt = CAP;
  if ((unsigned)blockIdx.x * 256u >= cnt) return;   // uniform: skip staging too
  const unsigned cnt32 = (cnt + 31u) & ~31u;
  __shared__ ulonglong2 keys2[CAP / 2];
  unsigned long long* keys = (unsigned long long*)keys2;
  const unsigned long long* src = gtk + (size_t)il * CAP;
  for (int e = tid; e < (int)cnt32; e += 256)
    keys[e] = (e < (int)cnt) ? src[e] : 0ULL;   // real keys >= 2^32 > 0 pad
  __syncthreads();
  const int s = (int)blockIdx.x * 256 + tid;
  if (s >= (int)cnt) return;
  const unsigned long long mykey = keys[s];
  unsigned r0 = 0, r1 = 0, r2 = 0, r3 = 0;
  const unsigned half = cnt32 >> 1;           // # of ulonglong2 entries
  for (unsigned j = 0; j < half; j += 16) {
    #pragma unroll
    for (int q = 0; q < 16; q += 4) {
      ulonglong2 a = keys2[j + q + 0];
      ulonglong2 b = keys2[j + q + 1];
      ulonglong2 cc = keys2[j + q + 2];
      ulonglong2 d = keys2[j + q + 3];
      r0 += (a.x > mykey ? 1u : 0u) + (a.y > mykey ? 1u : 0u);
      r1 += (b.x > mykey ? 1u : 0u) + (b.y > mykey ? 1u : 0u);
      r2 += (cc.x > mykey ? 1u : 0u) + (cc.y > mykey ? 1u : 0u);
      r3 += (d.x > mykey ? 1u : 0u) + (d.y > mykey ? 1u : 0u);
    }
  }
  unsigned rank = r0 + r1 + r2 + r3;
  if (rank >= (unsigned)K) return;

  unsigned ubits = (unsigned)(mykey >> 32);
  unsigned idx = ~((unsigned)mykey);
  int a = (int)(idx % 3u); int pix = (int)(idx / 3u);
  int xq = pix % W, yq = pix / W;
  float dx = reg[(a * 4 + 0) * HW + pix];
  float dy = reg[(a * 4 + 1) * HW + pix];
  float dw = reg[(a * 4 + 2) * HW + pix];
  float dh = reg[(a * 4 + 3) * HW + pix];
  double rr = (a == 0) ? 0.5 : (a == 1 ? 1.0 : 2.0);
  double hr = sqrt(rr), wr = 1.0 / hr;
  double st = (double)S;
  double wsd = st * wr * 8.0, hsd = st * hr * 8.0;
  double sxd = (double)(xq * S), syd = (double)(yq * S);
  float a0 = (float)(sxd - 0.5 * wsd), a1 = (float)(syd - 0.5 * hsd);
  float a2 = (float)(sxd + 0.5 * wsd), a3 = (float)(syd + 0.5 * hsd);
  float px = __fmul_rn(__fadd_rn(a0, a2), 0.5f);
  float py = __fmul_rn(__fadd_rn(a1, a3), 0.5f);
  float pw = __fsub_rn(a2, a0), ph = __fsub_rn(a3, a1);
  const float MRf = 4.135166556742356f;  // |log(16/1000)| rounded to f32
  float dwc = fminf(fmaxf(dw, -MRf), MRf);
  float dhc = fminf(fmaxf(dh, -MRf), MRf);
  float gw = __fmul_rn(pw, xla_expf(dwc));
  float gh = __fmul_rn(ph, xla_expf(dhc));
  float gx = __fmaf_rn(pw, dx, px);
  float gy = __fmaf_rn(ph, dy, py);
  float x1 = fminf(fmaxf(__fmaf_rn(gw, -0.5f, gx), 0.0f), 512.0f);
  float y1 = fminf(fmaxf(__fmaf_rn(gh, -0.5f, gy), 0.0f), 512.0f);
  float x2 = fminf(fmaxf(__fmaf_rn(gw,  0.5f, gx), 0.0f), 512.0f);
  float y2 = fminf(fmaxf(__fmaf_rn(gh,  0.5f, gy), 0.0f), 512.0f);
  bool valid = (__fsub_rn(x2, x1) > 0.0f) && (__fsub_rn(y2, y1) > 0.0f);
  int pos = img * M_TOT + LV_OFF[lvl] + (int)rank;
  cand_box[(size_t)pos * 4 + 0] = x1;
  cand_box[(size_t)pos * 4 + 1] = y1;
  cand_box[(size_t)pos * 4 + 2] = x2;
  cand_box[(size_t)pos * 4 + 3] = y2;
  float score = __uint_as_float(ubits);
  cand_s[pos] = valid ? score : -1.0f;
  if (valid)
    atomicOr(&vflags[(size_t)il * 32 + (rank >> 6)], 1ULL << (rank & 63));
}

// ================= K1d: partition (valids first) + NMS-order arrays ==========
__global__ __launch_bounds__(256) void k_part(const float* cand_box,
    const float* cand_s, const unsigned long long* vflags,
    float* n_x1, float* n_y1, float* n_x2, float* n_y2, float* n_ar,
    float* n_sc, unsigned* n_pos, unsigned* V_arr) {
  const int il = (int)blockIdx.x;
  const int img = il / 5, lvl = il % 5;
  const int K = LV_K[lvl];
  const int tid = (int)threadIdx.x;
  __shared__ unsigned long long sflag[32];
  __shared__ unsigned wpre[33];
  if (tid < 32) sflag[tid] = vflags[(size_t)il * 32 + tid];
  __syncthreads();
  if (tid < 32) {
    unsigned c = (unsigned)__popcll(sflag[tid]);
    #pragma unroll
    for (int off = 1; off < 32; off <<= 1) {
      unsigned t = __shfl_up(c, off);
      if (tid >= off) c += t;
    }
    wpre[tid + 1] = c;
    if (tid == 0) wpre[0] = 0;
  }
  __syncthreads();
  const unsigned V = wpre[32];
  const float offv = __fmul_rn((float)lvl, 513.0f);
  const int base = img * M_TOT + LV_OFF[lvl];
  for (int r = tid; r < K; r += 256) {
    unsigned long long word = sflag[r >> 6];
    unsigned fl = (unsigned)((word >> (r & 63)) & 1ULL);
    unsigned excl = wpre[r >> 6] +
                    (unsigned)__popcll(word & ((1ULL << (r & 63)) - 1ULL));
    unsigned pdst = fl ? excl : V + ((unsigned)r - excl);
    const float* b = cand_box + (size_t)(base + r) * 4;
    float ox1 = __fadd_rn(b[0], offv), oy1 = __fadd_rn(b[1], offv);
    float ox2 = __fadd_rn(b[2], offv), oy2 = __fadd_rn(b[3], offv);
    int dst = base + (int)pdst;
    n_x1[dst] = ox1; n_y1[dst] = oy1; n_x2[dst] = ox2; n_y2[dst] = oy2;
    n_ar[dst] = __fmul_rn(__fsub_rn(ox2, ox1), __fsub_rn(oy2, oy1));
    n_sc[dst] = cand_s[base + r];
    n_pos[dst] = (unsigned)(LV_OFF[lvl] + r);
  }
  if (tid == 0) V_arr[il] = V;
}

// ================= K2a: suppression bit-matrix build + diag transpose ========
// Division-free bit-exact IoU test: fl(inter/uni)>0.7f <=> inter >= MTH*uni
// evaluated in f64 (2 cvt + mul + cmp instead of the ~12-op div sequence).
#define TSTAGE(S, M)                                                        \
  {                                                                         \
    unsigned long long t_ = __shfl_xor(x, S);                               \
    x = (lane & S) ? ((x & (M)) | ((t_ >> S) & ~(M)))                       \
                   : ((x & ~(M)) | ((t_ << S) & (M)));                      \
  }

__global__ __launch_bounds__(256) void k_mask(
    const float* n_x1, const float* n_y1, const float* n_x2, const float* n_y2,
    const float* n_ar, unsigned long long* mask, unsigned long long* diagT) {
  const int img = blockIdx.y;
  const int bx = blockIdx.x;
  int lvl = 0;
  while (bx >= MB_BASE[lvl + 1]) ++lvl;
  const int t = bx - MB_BASE[lvl];
  const int ct = MB_CT[lvl];
  const int rt = t / ct, c = t % ct;
  const int K = LV_K[lvl];
  const int row0 = rt * 64, col0 = c * 256;
  if (col0 + 255 <= row0) return;  // entire tile has j <= r: bits never consumed

  __shared__ float4 cb4[256];
  __shared__ float cba[256];
  __shared__ float4 rb4[64];
  __shared__ float rba[64];
  const int base = img * M_TOT + LV_OFF[lvl];
  const int tid = (int)threadIdx.x;
  if (tid < 64) {
    int r = row0 + tid;
    if (r < K) {
      rb4[tid] = make_float4(n_x1[base + r], n_y1[base + r],
                             n_x2[base + r], n_y2[base + r]);
      rba[tid] = n_ar[base + r];
    } else {
      rb4[tid] = make_float4(0.f, 0.f, 0.f, 0.f);
      rba[tid] = 0.f;
    }
  }
  {
    int j = col0 + tid;
    if (j < K) {
      cb4[tid] = make_float4(n_x1[base + j], n_y1[base + j],
                             n_x2[base + j], n_y2[base + j]);
      cba[tid] = n_ar[base + j];
    }
  }
  __syncthreads();
  const int wl = tid >> 6, lane = tid & 63;
  const int r = row0 + lane;
  const bool rvalid = (r < K);
  const float4 rb = rb4[lane];
  const float rar = rba[lane];
  unsigned long long word = 0ULL;
  const int jbase = wl * 64;
  const int jmax = K - col0 - jbase;   // bit k valid iff k < jmax
  #pragma unroll 16
  for (int k = 0; k < 64; ++k) {
    float4 cb = cb4[jbase + k];        // broadcast: all lanes same address
    float car = cba[jbase + k];
    float iw = fmaxf(__fsub_rn(fminf(rb.z, cb.z), fmaxf(rb.x, cb.x)), 0.0f);
    float ih = fmaxf(__fsub_rn(fminf(rb.w, cb.w), fmaxf(rb.y, cb.y)), 0.0f);
    float inter = __fmul_rn(iw, ih);
    float uni = __fsub_rn(__fadd_rn(rar, car), inter);
    bool sup = (uni > 0.0f) && ((double)inter >= MTH * (double)uni);
    if (sup && k < jmax) word |= (1ULL << k);
  }
  if (!rvalid) word = 0ULL;
  if (rvalid)
    mask[(size_t)img * MWORDS_PER_IMG + MOFF[lvl] +
         (size_t)r * WPL[lvl] + (size_t)((col0 >> 6) + wl)] = word;
  // diag 64x64 block of this chunk lives in word wl where col0+64*wl == row0:
  // transpose it across lanes (lane i -> column i) and store to diagT.
  if (col0 + (wl << 6) == row0) {
    unsigned long long x = word;
    TSTAGE(32, 0xFFFFFFFF00000000ULL)
    TSTAGE(16, 0xFFFF0000FFFF0000ULL)
    TSTAGE(8,  0xFF00FF00FF00FF00ULL)
    TSTAGE(4,  0xF0F0F0F0F0F0F0F0ULL)
    TSTAGE(2,  0xCCCCCCCCCCCCCCCCULL)
    TSTAGE(1,  0xAAAAAAAAAAAAAAAAULL)
    diagT[(size_t)(img * 5 + lvl) * (40 * 64) + (size_t)rt * 64 + lane] = x;
  }
}

// ================= K2b: 8-wave chunked greedy scan ===========================
#define SCAN_CHUNK(P0, P1, P2, P3)                                          \
  {                                                                         \
    const int r0 = c << 6;                                                  \
    if (w == (c & 7)) {                                                     \
      unsigned long long v = (g == (c >> 3)) ? aw : ~0ULL;                  \
      v &= __shfl_xor(v, 1);                                                \
      v &= __shfl_xor(v, 2);                                                \
      v &= __shfl_xor(v, 4);                                                \
      v &= __shfl_xor(v, 8);                                                \
      v = __shfl(v, (c >> 3) * 16);                                         \
      unsigned long long x = dg;                                            \
      unsigned long long kw = v;                                            \
      while (true) {                                                        \
        bool keep_j = (((v >> lane) & 1ULL) != 0ULL) &&                     \
                      ((kw & below & x) == 0ULL);                           \
        unsigned long long nkw = __ballot(keep_j);                          \
        if (nkw == kw) break;                                               \
        kw = nkw;                                                           \
      }                                                                     \
      if ((kw >> lane) & 1ULL)                                              \
        skept[kept + (int)__popcll(kw & below)] = (unsigned)(r0 + lane);    \
      if (lane == 0) s_kw[c & 1] = kw;                                      \
      int no_ = next_own < 40 ? next_own : 39;                              \
      dg = dT[(size_t)no_ * 64 + lane];                                     \
      next_own += 8;                                                        \
    }                                                                       \
    __syncthreads();                                                        \
    unsigned long long kwv = s_kw[c & 1];                                   \
    kept += (int)__popcll(kwv);                                             \
    aw &= ~(P0 & (unsigned long long)((long long)(kwv << (63 - (d0 + 0))) >> 63)); \
    aw &= ~(P1 & (unsigned long long)((long long)(kwv << (63 - (d0 + 1))) >> 63)); \
    aw &= ~(P2 & (unsigned long long)((long long)(kwv << (63 - (d0 + 2))) >> 63)); \
    aw &= ~(P3 & (unsigned long long)((long long)(kwv << (63 - (d0 + 3))) >> 63)); \
    P0 = mb[(size_t)(r0 + 128 + d0 + 0) * wpl + wkc];                       \
    P1 = mb[(size_t)(r0 + 128 + d0 + 1) * wpl + wkc];                       \
    P2 = mb[(size_t)(r0 + 128 + d0 + 2) * wpl + wkc];                       \
    P3 = mb[(size_t)(r0 + 128 + d0 + 3) * wpl + wkc];                       \
    ++c;                                                                    \
  }

__global__ __launch_bounds__(512) void k_scan(const unsigned long long* mask,
    const unsigned long long* diagT,
    const unsigned* n_pos, const float* n_sc, const unsigned* V_arr,
    unsigned* kept_pos, unsigned long long* kept_key, unsigned* kept_cnt) {
  const int il = (int)blockIdx.x;
  const int img = il / 5, lvl = il % 5;
  const int K = LV_K[lvl], wpl = WPL[lvl];
  const int tid = (int)threadIdx.x;
  const int w = tid >> 6, lane = tid & 63;
  const unsigned long long* mb =
      mask + (size_t)img * MWORDS_PER_IMG + MOFF[lvl];
  const unsigned long long* dT = diagT + (size_t)il * (40 * 64);

  __shared__ unsigned long long s_kw[2];
  __shared__ unsigned skept[MAX_OUT + 64];

  const int g = lane >> 4;
  const int wk = w + 8 * g;
  const int wkc = wk < wpl ? wk : 0;      // clamped (dup loads harmless)
  const int d0 = (lane & 15) * 4;         // my 4 suppression rows per chunk
  const unsigned long long below = (1ULL << lane) - 1ULL;

  const int V = (int)V_arr[il];
  unsigned long long aw;
  {
    int lo = wk * 64, hi = V < lo + 64 ? V : lo + 64;
    aw = (hi > lo) ? ((hi - lo == 64) ? ~0ULL : ((1ULL << (hi - lo)) - 1ULL))
                   : 0ULL;
  }

  const int nchunks = (K + 63) >> 6;
  unsigned long long pfA0 = mb[(size_t)(d0 + 0) * wpl + wkc];
  unsigned long long pfA1 = mb[(size_t)(d0 + 1) * wpl + wkc];
  unsigned long long pfA2 = mb[(size_t)(d0 + 2) * wpl + wkc];
  unsigned long long pfA3 = mb[(size_t)(d0 + 3) * wpl + wkc];
  unsigned long long pfB0 = mb[(size_t)(64 + d0 + 0) * wpl + wkc];
  unsigned long long pfB1 = mb[(size_t)(64 + d0 + 1) * wpl + wkc];
  unsigned long long pfB2 = mb[(size_t)(64 + d0 + 2) * wpl + wkc];
  unsigned long long pfB3 = mb[(size_t)(64 + d0 + 3) * wpl + wkc];
  unsigned long long dg = dT[(size_t)w * 64 + lane];
  int next_own = w + 8;

  int kept = 0;
  int c = 0;
  while (c < nchunks && kept < MAX_OUT) {
    SCAN_CHUNK(pfA0, pfA1, pfA2, pfA3)
    if (c >= nchunks || kept >= MAX_OUT) break;
    SCAN_CHUNK(pfB0, pfB1, pfB2, pfB3)
  }

  __syncthreads();
  const int kc = kept < MAX_OUT ? kept : MAX_OUT;
  const int base = img * M_TOT + LV_OFF[lvl];
  const size_t bo = (size_t)il * 1024;
  for (int i = tid; i < kc; i += 512) {
    unsigned r = skept[i];
    unsigned pp = n_pos[base + (int)r];
    kept_pos[bo + i] = pp;
    kept_key[bo + i] =
        ((unsigned long long)__float_as_uint(n_sc[base + (int)r]) << 32) |
        (unsigned)(~pp);
  }
  if (tid == 0) kept_cnt[il] = (unsigned)kc;
}

// ================= K3: per-image merge of kept lists -> output rows ===========
__global__ __launch_bounds__(1024) void k_merge(const float* cand_box,
    const float* cand_s, const unsigned* kept_pos,
    const unsigned long long* kept_key, const unsigned* kept_cnt, float* out) {
  const int img = blockIdx.x;
  const int tid = (int)threadIdx.x;
  __shared__ unsigned cnts[5];
  __shared__ unsigned long long skey[5][1024];
  if (tid < 5) {
    unsigned c = kept_cnt[img * 5 + tid];
    cnts[tid] = c < (unsigned)MAX_OUT ? c : (unsigned)MAX_OUT;
  }
  __syncthreads();
  for (int e = tid; e < 5 * 1024; e += 1024) {
    int l = e >> 10, s = e & 1023;
    skey[l][s] = (s < (int)cnts[l])
        ? kept_key[(size_t)(img * 5 + l) * 1024 + s] : 0ULL;
  }
  __syncthreads();
  unsigned T = cnts[0] + cnts[1] + cnts[2] + cnts[3] + cnts[4];
  unsigned Tc = T < (unsigned)MAX_OUT ? T : (unsigned)MAX_OUT;
  for (int r = (int)Tc + tid; r < MAX_OUT; r += 1024) {
    float* o = out + (size_t)img * (MAX_OUT * 5) + (size_t)r * 5;
    o[0] = 0.f; o[1] = 0.f; o[2] = 0.f; o[3] = 0.f; o[4] = 0.f;
  }
  for (int e = tid; e < 5 * 1024; e += 1024) {
    int l = e >> 10, s = e & 1023;
    if (s >= (int)cnts[l]) continue;
    unsigned long long k0 = skey[l][s];
    unsigned rank = (unsigned)s;
    #pragma unroll
    for (int l2 = 0; l2 < 5; ++l2) {
      if (l2 == l) continue;
      int lo = 0, hi = (int)cnts[l2];
      while (lo < hi) {
        int mid = (lo + hi) >> 1;
        if (skey[l2][mid] > k0) lo = mid + 1; else hi = mid;
      }
      rank += (unsigned)lo;
    }
    if (rank < (unsigned)MAX_OUT) {
      unsigned pos = kept_pos[(size_t)(img * 5 + l) * 1024 + s];
      const float* b = cand_box + (size_t)(img * M_TOT + pos) * 4;
      float* o = out + (size_t)img * (MAX_OUT * 5) + (size_t)rank * 5;
      o[0] = b[0]; o[1] = b[1]; o[2] = b[2]; o[3] = b[3];
      o[4] = cand_s[img * M_TOT + pos];
    }
  }
}

// ================= host launch =================
extern "C" void kernel_launch(void* const* d_in, const int* in_sizes, int n_in,
                              void* d_out, int out_size, void* d_ws, size_t ws_size,
                              hipStream_t stream) {
  Ptrs p;
  bool interleaved = (n_in == 10 && in_sizes[1] == 4 * 12 * 128 * 128);
  for (int l = 0; l < 5; ++l) {
    if (interleaved) {
      p.cls[l] = (const float*)d_in[2 * l];
      p.reg[l] = (const float*)d_in[2 * l + 1];
    } else {
      p.cls[l] = (const float*)d_in[l];
      p.reg[l] = (const float*)d_in[5 + l];
    }
  }
  uint8_t* w = (uint8_t*)d_ws;
  size_t o = 0;
  auto carve = [&](size_t bytes) {
    void* ptr = w + o;
    o += (bytes + 255) & ~(size_t)255;
    return ptr;
  };
  // gcnt + ghist + vflags adjacent -> one zero kernel covers all three
  unsigned* gcnt = (unsigned*)carve((size_t)20 * 4);                 // 256B slot
  unsigned* ghist = (unsigned*)carve((size_t)20 * 4096 * 4);
  unsigned long long* vflags = (unsigned long long*)carve((size_t)20 * 32 * 8);
  size_t zero_bytes = 256 + (size_t)20 * 4096 * 4 + (size_t)20 * 32 * 8;
  unsigned long long* T64_arr = (unsigned long long*)carve((size_t)20 * 8);
  unsigned* u_arr = (unsigned*)carve((size_t)4 * U_PER_IMG * 4);
  float* cand_box = (float*)carve((size_t)4 * M_TOT * 4 * 4);
  float* cand_s = (float*)carve((size_t)4 * M_TOT * 4);
  float* n_x1 = (float*)carve((size_t)4 * M_TOT * 4);
  float* n_y1 = (float*)carve((size_t)4 * M_TOT * 4);
  float* n_x2 = (float*)carve((size_t)4 * M_TOT * 4);
  float* n_y2 = (float*)carve((size_t)4 * M_TOT * 4);
  float* n_ar = (float*)carve((size_t)4 * M_TOT * 4);
  float* n_sc = (float*)carve((size_t)4 * M_TOT * 4);
  unsigned* n_pos = (unsigned*)carve((size_t)4 * M_TOT * 4);
  unsigned* V_arr = (unsigned*)carve((size_t)20 * 4);
  unsigned* kept_pos = (unsigned*)carve((size_t)4 * 5 * 1024 * 4);
  unsigned long long* kept_key = (unsigned long long*)carve((size_t)4 * 5 * 1024 * 8);
  unsigned* kept_cnt = (unsigned*)carve((size_t)20 * 4);
  unsigned long long* diagT = (unsigned long long*)carve((size_t)20 * 40 * 64 * 8);
  unsigned long long* mask = (unsigned long long*)carve((size_t)4 * MWORDS_PER_IMG * 8);
  // gtk (20*4096 u64 = 640KB) aliases mask: dead before k_mask writes it.
  unsigned long long* gtk = mask;
  (void)ws_size; (void)out_size;

  int n4 = (int)(zero_bytes >> 4);
  k_zero<<<(n4 + 255) / 256, 256, 0, stream>>>((uint4*)gcnt, n4);
  k_sig<<<dim3(18, 4), 1024, 0, stream>>>(p, u_arr, ghist);
  k_thresh<<<20, 1024, 0, stream>>>(u_arr, ghist, T64_arr);
  k_collect<<<dim3(18, 4), 1024, 0, stream>>>(u_arr, T64_arr, gtk, gcnt);
  k_rank<<<dim3(16, 20), 256, 0, stream>>>(p, gtk, gcnt, cand_box, cand_s,
                                           vflags);
  k_part<<<20, 256, 0, stream>>>(cand_box, cand_s, vflags,
      n_x1, n_y1, n_x2, n_y2, n_ar, n_sc, n_pos, V_arr);
  k_mask<<<dim3(807, 4), 256, 0, stream>>>(n_x1, n_y1, n_x2, n_y2, n_ar,
                                           mask, diagT);
  k_scan<<<20, 512, 0, stream>>>(mask, diagT, n_pos, n_sc, V_arr,
                                 kept_pos, kept_key, kept_cnt);
  k_merge<<<4, 1024, 0, stream>>>(cand_box, cand_s, kept_pos, kept_key,
                                  kept_cnt, (float*)d_out);
}

// Round 14
// 116.536 us; speedup vs baseline: 2.0790x; 1.1623x over previous
//
#include <hip/hip_runtime.h>
#include <cstdint>
#include <cstddef>

// ---------------- constants ----------------
__constant__ int LV_N[5]    = {49152, 12288, 3072, 768, 192};   // H*W*3
__constant__ int LV_K[5]    = {2000, 2000, 2000, 768, 192};     // min(PRE_NMS, N)
__constant__ int LV_OFF[5]  = {0, 2000, 4000, 6000, 6768};      // concat offsets
__constant__ int LV_UOFF[5] = {0, 49152, 61440, 64512, 65280};  // u-array offsets
__constant__ int LV_W[5]    = {128, 64, 32, 16, 8};
__constant__ int LV_S[5]    = {4, 8, 16, 32, 64};
__constant__ int LV_LOGHW[5]= {14, 12, 10, 8, 6};
// mask geometry (rows padded by 192 so scan prefetch needs no bounds tests)
__constant__ int WPL[5]     = {32, 32, 32, 12, 3};              // words per row
__constant__ int MOFF[5]    = {0, 70144, 140288, 210432, 221952};
__constant__ int MB_BASE[6] = {0, 256, 512, 768, 804, 807};     // mask-block bases
__constant__ int MB_CT[5]   = {8, 8, 8, 3, 1};                  // col tiles per lvl
__constant__ int SGB6[6]    = {0, 12, 15, 16, 17, 18};          // 4096-elem tile bases

#define M_TOT 6960
#define U_PER_IMG 65472
#define MAX_OUT 1000
#define MWORDS_PER_IMG 223104
#define CAP 4096

struct Ptrs { const float* cls[5]; const float* reg[5]; };

// fl(inter/uni) > 0.7f  <=>  inter/uni >= MTH  (tie at MTH rounds to even
// mantissa 0x3F333334 > 0.7f). Evaluated in f64: exact except a ~2^-53 band.
#define MTH 0.7000000178813934326171875

// ---------------- XLA:CPU-compatible expf (Cephes/Eigen pexp, FMA-contracted) ----
__device__ __forceinline__ float xla_expf(float x) {
  const float exp_hi = 88.3762626647950f;
  const float exp_lo = -88.3762626647949f;
  const float log2ef = 1.44269504088896341f;
  const float c1 = 0.693359375f;
  const float c2 = -2.12194440e-4f;
  const float p0 = 1.9875691500e-4f;
  const float p1 = 1.3981999507e-3f;
  const float p2 = 8.3334519073e-3f;
  const float p3 = 4.1665795894e-2f;
  const float p4 = 1.6666665459e-1f;
  const float p5 = 5.0000001201e-1f;
  float xx = fminf(fmaxf(x, exp_lo), exp_hi);
  float fx = floorf(__fmaf_rn(xx, log2ef, 0.5f));
  float r = __fmaf_rn(fx, -c1, xx);
  r = __fmaf_rn(fx, -c2, r);
  float z = __fmul_rn(r, r);
  float y = __fmaf_rn(p0, r, p1);
  y = __fmaf_rn(y, r, p2);
  y = __fmaf_rn(y, r, p3);
  y = __fmaf_rn(y, r, p4);
  y = __fmaf_rn(y, r, p5);
  y = __fmaf_rn(y, z, r);
  y = __fadd_rn(y, 1.0f);
  int n = (int)fx;
  float two_n = __uint_as_float((unsigned)(n + 127) << 23);
  return __fmul_rn(y, two_n);
}

__device__ __forceinline__ float ref_sigmoid(float x) {
  return __fdiv_rn(1.0f, __fadd_rn(1.0f, xla_expf(-x)));
}

// ================= K-1: fast zero of gcnt+ghist+vflags ======================
__global__ __launch_bounds__(256) void k_zero(uint4* ptr, int n4) {
  int i = (int)blockIdx.x * 256 + (int)threadIdx.x;
  if (i < n4) ptr[i] = make_uint4(0u, 0u, 0u, 0u);
}

// ================= K0: wide sigmoid + 4096-bin score-bit histogram ============
// u is stored PLANE-MAJOR (same order as the input read) -> both sides
// coalesced. The channel-last index only enters via key construction later.
__global__ __launch_bounds__(1024) void k_sig(Ptrs p, unsigned* u_arr,
                                              unsigned* ghist) {
  const int img = blockIdx.y;
  const int bx = blockIdx.x;
  int lvl = 0;
  while (bx >= SGB6[lvl + 1]) ++lvl;
  const int N = LV_N[lvl];
  const int e0 = (bx - SGB6[lvl]) * 4096;
  const int e1 = (e0 + 4096 < N) ? e0 + 4096 : N;
  const int tid = (int)threadIdx.x;
  __shared__ unsigned h[4096];
  for (int e = tid; e < 4096; e += 1024) h[e] = 0;
  __syncthreads();
  const float* cls = p.cls[lvl] + (size_t)img * N;
  unsigned* u = u_arr + img * U_PER_IMG + LV_UOFF[lvl];
  for (int e = e0 + tid; e < e1; e += 1024) {
    float logit = cls[e];                  // plane-major: fully coalesced
    unsigned ub = __float_as_uint(ref_sigmoid(logit));
    u[e] = ub;                             // plane-major: coalesced store
    atomicAdd(&h[(ub >> 18) & 4095u], 1u);
  }
  __syncthreads();
  unsigned* gh = ghist + (size_t)(img * 5 + lvl) * 4096;
  for (int e = tid; e < 4096; e += 1024)
    if (h[e]) atomicAdd(&gh[e], h[e]);
}

// ================= K1a: threshold pick (hierarchical wave suffix-scan) =======
__global__ __launch_bounds__(1024) void k_thresh(const unsigned* u_arr,
    const unsigned* ghist, unsigned long long* T64_arr) {
  const int blk = blockIdx.x;
  const int img = blk / 5, lvl = blk % 5;
  const int N = LV_N[lvl], K = LV_K[lvl], LOGHW = LV_LOGHW[lvl];
  const int HW = 1 << LOGHW;
  const int tid = (int)threadIdx.x;
  const int lane = tid & 63, w = tid >> 6;
  if (N <= K) { if (tid == 0) T64_arr[blk] = 0ULL; return; }
  __shared__ unsigned h[4096];
  __shared__ unsigned wsum[16], wsuf[16];
  __shared__ unsigned sh_D, sh_sD, sh_sD1;
  const unsigned* u = u_arr + img * U_PER_IMG + LV_UOFF[lvl];

  unsigned long long prefix = 0;
  unsigned want = (unsigned)K, above = 0;
  const int shifts[6] = {50, 38, 26, 14, 2, 0};
  for (int rd = 0; rd < 6; ++rd) {
    const int shift = shifts[rd];
    if (rd == 5) {                          // final 2-bit round: trivial serial
      for (int e = tid; e < 4; e += 1024) h[e] = 0;
      __syncthreads();
      for (int q = tid; q < N; q += 1024) {
        unsigned a = (unsigned)q >> LOGHW, pix = (unsigned)q & (unsigned)(HW - 1);
        unsigned ecl = pix * 3u + a;
        unsigned long long key =
            ((unsigned long long)u[q] << 32) | (unsigned)(~ecl);
        if ((key >> 2) == prefix) atomicAdd(&h[(unsigned)key & 3u], 1u);
      }
      __syncthreads();
      if (tid == 0) {
        unsigned cum = 0; int D = 0;
        for (int v = 3; v >= 0; --v) {
          if (cum + h[v] >= want) { D = v; break; }
          cum += h[v];
        }
        T64_arr[blk] = (prefix << 2) | (unsigned)D;
      }
      return;
    }
    if (rd == 0) {
      for (int e = tid; e < 4096; e += 1024)
        h[e] = ghist[(size_t)blk * 4096 + e];
    } else {                               // exact rescan (rarely taken)
      for (int e = tid; e < 4096; e += 1024) h[e] = 0;
      __syncthreads();
      for (int q = tid; q < N; q += 1024) {
        unsigned a = (unsigned)q >> LOGHW, pix = (unsigned)q & (unsigned)(HW - 1);
        unsigned ecl = pix * 3u + a;
        unsigned long long key =
            ((unsigned long long)u[q] << 32) | (unsigned)(~ecl);
        if ((key >> (shift + 12)) == prefix)
          atomicAdd(&h[(unsigned)(key >> shift) & 4095u], 1u);
      }
    }
    __syncthreads();
    // hierarchical suffix scan: 4 elems/thread, wave shfl, 16-wave combine
    unsigned h0 = h[4 * tid + 0], h1 = h[4 * tid + 1];
    unsigned h2 = h[4 * tid + 2], h3 = h[4 * tid + 3];
    unsigned s = h0 + h1 + h2 + h3;
    unsigned suf = s;
    #pragma unroll
    for (int off = 1; off < 64; off <<= 1) {
      unsigned t2 = __shfl_down(suf, off);
      if (lane + off < 64) suf += t2;
    }
    if (lane == 0) wsum[w] = suf;
    __syncthreads();
    if (tid < 16) {
      unsigned v = wsum[tid];
      #pragma unroll
      for (int off = 1; off < 16; off <<= 1) {
        unsigned t2 = __shfl_down(v, off);
        if (tid + off < 16) v += t2;
      }
      wsuf[tid] = v;
    }
    __syncthreads();
    unsigned Sth = ((w + 1 < 16) ? wsuf[w + 1] : 0u) + (suf - s);
    unsigned f3 = Sth + h3;
    unsigned f2 = f3 + h2;
    unsigned f1 = f2 + h1;
    unsigned f0 = f1 + h0;
    if (f0 >= want && f1 < want) { sh_D = 4u * tid + 0; sh_sD = f0; sh_sD1 = f1; }
    if (f1 >= want && f2 < want) { sh_D = 4u * tid + 1; sh_sD = f1; sh_sD1 = f2; }
    if (f2 >= want && f3 < want) { sh_D = 4u * tid + 2; sh_sD = f2; sh_sD1 = f3; }
    if (f3 >= want && Sth < want) { sh_D = 4u * tid + 3; sh_sD = f3; sh_sD1 = Sth; }
    __syncthreads();
    unsigned D = sh_D, sD = sh_sD, sD1 = sh_sD1;
    unsigned long long npref = (prefix << 12) | (unsigned long long)D;
    if (above + sD <= (unsigned)CAP) {
      if (tid == 0) T64_arr[blk] = npref << shift;
      return;                              // uniform decision across block
    }
    above += sD1; want -= sD1; prefix = npref;
    __syncthreads();
  }
}

// ================= K1b: wide collect, ONE global atomic per block ============
// Plane-major u reads (coalesced); channel-last index enters only via the key.
__global__ __launch_bounds__(1024) void k_collect(const unsigned* u_arr,
    const unsigned long long* T64_arr, unsigned long long* gtk, unsigned* gcnt) {
  const int img = blockIdx.y;
  const int bx = blockIdx.x;
  int lvl = 0;
  while (bx >= SGB6[lvl + 1]) ++lvl;
  const int N = LV_N[lvl], LOGHW = LV_LOGHW[lvl];
  const int HW = 1 << LOGHW;
  const int e0 = (bx - SGB6[lvl]) * 4096;
  const int tid = (int)threadIdx.x;
  const int lane = tid & 63;
  const int w = tid >> 6;                     // 16 waves
  const unsigned long long T = T64_arr[img * 5 + lvl];
  const unsigned* u = u_arr + img * U_PER_IMG + LV_UOFF[lvl];

  __shared__ unsigned wcnt[64];               // [wave*4 + iter] -> offsets

  unsigned long long key0 = 0, key1 = 0, key2 = 0, key3 = 0;
  unsigned long long bm0, bm1, bm2, bm3;
  #define MKKEY(KV, Q)                                                      \
    {                                                                       \
      unsigned a_ = (unsigned)(Q) >> LOGHW;                                 \
      unsigned pix_ = (unsigned)(Q) & (unsigned)(HW - 1);                   \
      unsigned ecl_ = pix_ * 3u + a_;                                       \
      KV = ((unsigned long long)u[Q] << 32) | (unsigned)(~ecl_);            \
    }
  {
    int q = e0 + 0 * 1024 + tid;
    bool pr = false;
    if (q < N) { MKKEY(key0, q) pr = key0 >= T; }
    bm0 = __ballot(pr);
    if (lane == 0) wcnt[w * 4 + 0] = (unsigned)__popcll(bm0);
  }
  {
    int q = e0 + 1 * 1024 + tid;
    bool pr = false;
    if (q < N) { MKKEY(key1, q) pr = key1 >= T; }
    bm1 = __ballot(pr);
    if (lane == 0) wcnt[w * 4 + 1] = (unsigned)__popcll(bm1);
  }
  {
    int q = e0 + 2 * 1024 + tid;
    bool pr = false;
    if (q < N) { MKKEY(key2, q) pr = key2 >= T; }
    bm2 = __ballot(pr);
    if (lane == 0) wcnt[w * 4 + 2] = (unsigned)__popcll(bm2);
  }
  {
    int q = e0 + 3 * 1024 + tid;
    bool pr = false;
    if (q < N) { MKKEY(key3, q) pr = key3 >= T; }
    bm3 = __ballot(pr);
    if (lane == 0) wcnt[w * 4 + 3] = (unsigned)__popcll(bm3);
  }
  #undef MKKEY
  __syncthreads();
  if (tid < 64) {
    unsigned c = wcnt[tid];
    unsigned pre = c;
    #pragma unroll
    for (int off = 1; off < 64; off <<= 1) {
      unsigned t = __shfl_up(pre, off);
      if (tid >= off) pre += t;
    }
    unsigned total = __shfl(pre, 63);
    unsigned base = 0;
    if (tid == 63 && total) base = atomicAdd(gcnt + (img * 5 + lvl), total);
    base = __shfl(base, 63);
    wcnt[tid] = base + pre - c;               // exclusive (wave,iter) offset
  }
  __syncthreads();
  unsigned long long* dst = gtk + (size_t)(img * 5 + lvl) * CAP;
  const unsigned long long below = (1ULL << lane) - 1ULL;
  if ((bm0 >> lane) & 1ULL) {
    unsigned slot = wcnt[w * 4 + 0] + (unsigned)__popcll(bm0 & below);
    if (slot < (unsigned)CAP) dst[slot] = key0;
  }
  if ((bm1 >> lane) & 1ULL) {
    unsigned slot = wcnt[w * 4 + 1] + (unsigned)__popcll(bm1 & below);
    if (slot < (unsigned)CAP) dst[slot] = key1;
  }
  if ((bm2 >> lane) & 1ULL) {
    unsigned slot = wcnt[w * 4 + 2] + (unsigned)__popcll(bm2 & below);
    if (slot < (unsigned)CAP) dst[slot] = key2;
  }
  if ((bm3 >> lane) & 1ULL) {
    unsigned slot = wcnt[w * 4 + 3] + (unsigned)__popcll(bm3 & below);
    if (slot < (unsigned)CAP) dst[slot] = key3;
  }
}

// ================= K1c: brute-force rank + direct decode (no sort) ===========
__global__ __launch_bounds__(256) void k_rank(Ptrs p,
    const unsigned long long* gtk, const unsigned* gcnt,
    float* cand_box, float* cand_s, unsigned long long* vflags) {
  const int il = (int)blockIdx.y;
  const int img = il / 5, lvl = il % 5;
  const int N = LV_N[lvl], K = LV_K[lvl], W = LV_W[lvl], S = LV_S[lvl];
  const int HW = N / 3;
  const float* reg = p.reg[lvl] + (size_t)img * 12 * HW;
  const int tid = (int)threadIdx.x;
  unsigned cnt = gcnt[il];
  if (cnt > (unsigned)CAP) cnt = CAP;
  if ((unsigned)blockIdx.x * 256u >= cnt) return;   // uniform: skip staging too
  const unsigned cnt32 = (cnt + 31u) & ~31u;
  __shared__ ulonglong2 keys2[CAP / 2];
  unsigned long long* keys = (unsigned long long*)keys2;
  const unsigned long long* src = gtk + (size_t)il * CAP;
  for (int e = tid; e < (int)cnt32; e += 256)
    keys[e] = (e < (int)cnt) ? src[e] : 0ULL;   // real keys >= 2^32 > 0 pad
  __syncthreads();
  const int s = (int)blockIdx.x * 256 + tid;
  if (s >= (int)cnt) return;
  const unsigned long long mykey = keys[s];
  unsigned r0 = 0, r1 = 0, r2 = 0, r3 = 0;
  const unsigned half = cnt32 >> 1;           // # of ulonglong2 entries
  for (unsigned j = 0; j < half; j += 16) {
    #pragma unroll
    for (int q = 0; q < 16; q += 4) {
      ulonglong2 a = keys2[j + q + 0];
      ulonglong2 b = keys2[j + q + 1];
      ulonglong2 cc = keys2[j + q + 2];
      ulonglong2 d = keys2[j + q + 3];
      r0 += (a.x > mykey ? 1u : 0u) + (a.y > mykey ? 1u : 0u);
      r1 += (b.x > mykey ? 1u : 0u) + (b.y > mykey ? 1u : 0u);
      r2 += (cc.x > mykey ? 1u : 0u) + (cc.y > mykey ? 1u : 0u);
      r3 += (d.x > mykey ? 1u : 0u) + (d.y > mykey ? 1u : 0u);
    }
  }
  unsigned rank = r0 + r1 + r2 + r3;
  if (rank >= (unsigned)K) return;

  unsigned ubits = (unsigned)(mykey >> 32);
  unsigned idx = ~((unsigned)mykey);
  int a = (int)(idx % 3u); int pix = (int)(idx / 3u);
  int xq = pix % W, yq = pix / W;
  float dx = reg[(a * 4 + 0) * HW + pix];
  float dy = reg[(a * 4 + 1) * HW + pix];
  float dw = reg[(a * 4 + 2) * HW + pix];
  float dh = reg[(a * 4 + 3) * HW + pix];
  double rr = (a == 0) ? 0.5 : (a == 1 ? 1.0 : 2.0);
  double hr = sqrt(rr), wr = 1.0 / hr;
  double st = (double)S;
  double wsd = st * wr * 8.0, hsd = st * hr * 8.0;
  double sxd = (double)(xq * S), syd = (double)(yq * S);
  float a0 = (float)(sxd - 0.5 * wsd), a1 = (float)(syd - 0.5 * hsd);
  float a2 = (float)(sxd + 0.5 * wsd), a3 = (float)(syd + 0.5 * hsd);
  float px = __fmul_rn(__fadd_rn(a0, a2), 0.5f);
  float py = __fmul_rn(__fadd_rn(a1, a3), 0.5f);
  float pw = __fsub_rn(a2, a0), ph = __fsub_rn(a3, a1);
  const float MRf = 4.135166556742356f;  // |log(16/1000)| rounded to f32
  float dwc = fminf(fmaxf(dw, -MRf), MRf);
  float dhc = fminf(fmaxf(dh, -MRf), MRf);
  float gw = __fmul_rn(pw, xla_expf(dwc));
  float gh = __fmul_rn(ph, xla_expf(dhc));
  float gx = __fmaf_rn(pw, dx, px);
  float gy = __fmaf_rn(ph, dy, py);
  float x1 = fminf(fmaxf(__fmaf_rn(gw, -0.5f, gx), 0.0f), 512.0f);
  float y1 = fminf(fmaxf(__fmaf_rn(gh, -0.5f, gy), 0.0f), 512.0f);
  float x2 = fminf(fmaxf(__fmaf_rn(gw,  0.5f, gx), 0.0f), 512.0f);
  float y2 = fminf(fmaxf(__fmaf_rn(gh,  0.5f, gy), 0.0f), 512.0f);
  bool valid = (__fsub_rn(x2, x1) > 0.0f) && (__fsub_rn(y2, y1) > 0.0f);
  int pos = img * M_TOT + LV_OFF[lvl] + (int)rank;
  cand_box[(size_t)pos * 4 + 0] = x1;
  cand_box[(size_t)pos * 4 + 1] = y1;
  cand_box[(size_t)pos * 4 + 2] = x2;
  cand_box[(size_t)pos * 4 + 3] = y2;
  float score = __uint_as_float(ubits);
  cand_s[pos] = valid ? score : -1.0f;
  if (valid)
    atomicOr(&vflags[(size_t)il * 32 + (rank >> 6)], 1ULL << (rank & 63));
}

// ================= K1d: partition (valids first) + NMS-order arrays ==========
__global__ __launch_bounds__(256) void k_part(const float* cand_box,
    const float* cand_s, const unsigned long long* vflags,
    float* n_x1, float* n_y1, float* n_x2, float* n_y2, float* n_ar,
    float* n_sc, unsigned* n_pos, unsigned* V_arr) {
  const int il = (int)blockIdx.x;
  const int img = il / 5, lvl = il % 5;
  const int K = LV_K[lvl];
  const int tid = (int)threadIdx.x;
  __shared__ unsigned long long sflag[32];
  __shared__ unsigned wpre[33];
  if (tid < 32) sflag[tid] = vflags[(size_t)il * 32 + tid];
  __syncthreads();
  if (tid < 32) {
    unsigned c = (unsigned)__popcll(sflag[tid]);
    #pragma unroll
    for (int off = 1; off < 32; off <<= 1) {
      unsigned t = __shfl_up(c, off);
      if (tid >= off) c += t;
    }
    wpre[tid + 1] = c;
    if (tid == 0) wpre[0] = 0;
  }
  __syncthreads();
  const unsigned V = wpre[32];
  const float offv = __fmul_rn((float)lvl, 513.0f);
  const int base = img * M_TOT + LV_OFF[lvl];
  for (int r = tid; r < K; r += 256) {
    unsigned long long word = sflag[r >> 6];
    unsigned fl = (unsigned)((word >> (r & 63)) & 1ULL);
    unsigned excl = wpre[r >> 6] +
                    (unsigned)__popcll(word & ((1ULL << (r & 63)) - 1ULL));
    unsigned pdst = fl ? excl : V + ((unsigned)r - excl);
    const float* b = cand_box + (size_t)(base + r) * 4;
    float ox1 = __fadd_rn(b[0], offv), oy1 = __fadd_rn(b[1], offv);
    float ox2 = __fadd_rn(b[2], offv), oy2 = __fadd_rn(b[3], offv);
    int dst = base + (int)pdst;
    n_x1[dst] = ox1; n_y1[dst] = oy1; n_x2[dst] = ox2; n_y2[dst] = oy2;
    n_ar[dst] = __fmul_rn(__fsub_rn(ox2, ox1), __fsub_rn(oy2, oy1));
    n_sc[dst] = cand_s[base + r];
    n_pos[dst] = (unsigned)(LV_OFF[lvl] + r);
  }
  if (tid == 0) V_arr[il] = V;
}

// ================= K2a: suppression bit-matrix build + diag transpose ========
#define TSTAGE(S, M)                                                        \
  {                                                                         \
    unsigned long long t_ = __shfl_xor(x, S);                               \
    x = (lane & S) ? ((x & (M)) | ((t_ >> S) & ~(M)))                       \
                   : ((x & ~(M)) | ((t_ << S) & (M)));                      \
  }

__global__ __launch_bounds__(256) void k_mask(
    const float* n_x1, const float* n_y1, const float* n_x2, const float* n_y2,
    const float* n_ar, unsigned long long* mask, unsigned long long* diagT) {
  const int img = blockIdx.y;
  const int bx = blockIdx.x;
  int lvl = 0;
  while (bx >= MB_BASE[lvl + 1]) ++lvl;
  const int t = bx - MB_BASE[lvl];
  const int ct = MB_CT[lvl];
  const int rt = t / ct, c = t % ct;
  const int K = LV_K[lvl];
  const int row0 = rt * 64, col0 = c * 256;
  if (col0 + 255 <= row0) return;  // entire tile has j <= r: bits never consumed

  __shared__ float4 cb4[256];
  __shared__ float cba[256];
  __shared__ float4 rb4[64];
  __shared__ float rba[64];
  const int base = img * M_TOT + LV_OFF[lvl];
  const int tid = (int)threadIdx.x;
  if (tid < 64) {
    int r = row0 + tid;
    if (r < K) {
      rb4[tid] = make_float4(n_x1[base + r], n_y1[base + r],
                             n_x2[base + r], n_y2[base + r]);
      rba[tid] = n_ar[base + r];
    } else {
      rb4[tid] = make_float4(0.f, 0.f, 0.f, 0.f);
      rba[tid] = 0.f;
    }
  }
  {
    int j = col0 + tid;
    if (j < K) {
      cb4[tid] = make_float4(n_x1[base + j], n_y1[base + j],
                             n_x2[base + j], n_y2[base + j]);
      cba[tid] = n_ar[base + j];
    }
  }
  __syncthreads();
  const int wl = tid >> 6, lane = tid & 63;
  const int r = row0 + lane;
  const bool rvalid = (r < K);
  const float4 rb = rb4[lane];
  const float rar = rba[lane];
  unsigned long long word = 0ULL;
  const int jbase = wl * 64;
  const int jmax = K - col0 - jbase;   // bit k valid iff k < jmax
  #pragma unroll 16
  for (int k = 0; k < 64; ++k) {
    float4 cb = cb4[jbase + k];        // broadcast: all lanes same address
    float car = cba[jbase + k];
    float iw = fmaxf(__fsub_rn(fminf(rb.z, cb.z), fmaxf(rb.x, cb.x)), 0.0f);
    float ih = fmaxf(__fsub_rn(fminf(rb.w, cb.w), fmaxf(rb.y, cb.y)), 0.0f);
    float inter = __fmul_rn(iw, ih);
    float uni = __fsub_rn(__fadd_rn(rar, car), inter);
    bool sup = (uni > 0.0f) && ((double)inter >= MTH * (double)uni);
    if (sup && k < jmax) word |= (1ULL << k);
  }
  if (!rvalid) word = 0ULL;
  if (rvalid)
    mask[(size_t)img * MWORDS_PER_IMG + MOFF[lvl] +
         (size_t)r * WPL[lvl] + (size_t)((col0 >> 6) + wl)] = word;
  // diag 64x64 block of this chunk lives in word wl where col0+64*wl == row0:
  // transpose it across lanes (lane i -> column i) and store to diagT.
  if (col0 + (wl << 6) == row0) {
    unsigned long long x = word;
    TSTAGE(32, 0xFFFFFFFF00000000ULL)
    TSTAGE(16, 0xFFFF0000FFFF0000ULL)
    TSTAGE(8,  0xFF00FF00FF00FF00ULL)
    TSTAGE(4,  0xF0F0F0F0F0F0F0F0ULL)
    TSTAGE(2,  0xCCCCCCCCCCCCCCCCULL)
    TSTAGE(1,  0xAAAAAAAAAAAAAAAAULL)
    diagT[(size_t)(img * 5 + lvl) * (40 * 64) + (size_t)rt * 64 + lane] = x;
  }
}

// ================= K2b: 8-wave chunked greedy scan ===========================
#define SCAN_CHUNK(P0, P1, P2, P3)                                          \
  {                                                                         \
    const int r0 = c << 6;                                                  \
    if (w == (c & 7)) {                                                     \
      unsigned long long v = (g == (c >> 3)) ? aw : ~0ULL;                  \
      v &= __shfl_xor(v, 1);                                                \
      v &= __shfl_xor(v, 2);                                                \
      v &= __shfl_xor(v, 4);                                                \
      v &= __shfl_xor(v, 8);                                                \
      v = __shfl(v, (c >> 3) * 16);                                         \
      unsigned long long x = dg;                                            \
      unsigned long long kw = v;                                            \
      while (true) {                                                        \
        bool keep_j = (((v >> lane) & 1ULL) != 0ULL) &&                     \
                      ((kw & below & x) == 0ULL);                           \
        unsigned long long nkw = __ballot(keep_j);                          \
        if (nkw == kw) break;                                               \
        kw = nkw;                                                           \
      }                                                                     \
      if ((kw >> lane) & 1ULL)                                              \
        skept[kept + (int)__popcll(kw & below)] = (unsigned)(r0 + lane);    \
      if (lane == 0) s_kw[c & 1] = kw;                                      \
      int no_ = next_own < 40 ? next_own : 39;                              \
      dg = dT[(size_t)no_ * 64 + lane];                                     \
      next_own += 8;                                                        \
    }                                                                       \
    __syncthreads();                                                        \
    unsigned long long kwv = s_kw[c & 1];                                   \
    kept += (int)__popcll(kwv);                                             \
    aw &= ~(P0 & (unsigned long long)((long long)(kwv << (63 - (d0 + 0))) >> 63)); \
    aw &= ~(P1 & (unsigned long long)((long long)(kwv << (63 - (d0 + 1))) >> 63)); \
    aw &= ~(P2 & (unsigned long long)((long long)(kwv << (63 - (d0 + 2))) >> 63)); \
    aw &= ~(P3 & (unsigned long long)((long long)(kwv << (63 - (d0 + 3))) >> 63)); \
    P0 = mb[(size_t)(r0 + 128 + d0 + 0) * wpl + wkc];                       \
    P1 = mb[(size_t)(r0 + 128 + d0 + 1) * wpl + wkc];                       \
    P2 = mb[(size_t)(r0 + 128 + d0 + 2) * wpl + wkc];                       \
    P3 = mb[(size_t)(r0 + 128 + d0 + 3) * wpl + wkc];                       \
    ++c;                                                                    \
  }

__global__ __launch_bounds__(512) void k_scan(const unsigned long long* mask,
    const unsigned long long* diagT,
    const unsigned* n_pos, const float* n_sc, const unsigned* V_arr,
    unsigned* kept_pos, unsigned long long* kept_key, unsigned* kept_cnt) {
  const int il = (int)blockIdx.x;
  const int img = il / 5, lvl = il % 5;
  const int K = LV_K[lvl], wpl = WPL[lvl];
  const int tid = (int)threadIdx.x;
  const int w = tid >> 6, lane = tid & 63;
  const unsigned long long* mb =
      mask + (size_t)img * MWORDS_PER_IMG + MOFF[lvl];
  const unsigned long long* dT = diagT + (size_t)il * (40 * 64);

  __shared__ unsigned long long s_kw[2];
  __shared__ unsigned skept[MAX_OUT + 64];

  const int g = lane >> 4;
  const int wk = w + 8 * g;
  const int wkc = wk < wpl ? wk : 0;      // clamped (dup loads harmless)
  const int d0 = (lane & 15) * 4;         // my 4 suppression rows per chunk
  const unsigned long long below = (1ULL << lane) - 1ULL;

  const int V = (int)V_arr[il];
  unsigned long long aw;
  {
    int lo = wk * 64, hi = V < lo + 64 ? V : lo + 64;
    aw = (hi > lo) ? ((hi - lo == 64) ? ~0ULL : ((1ULL << (hi - lo)) - 1ULL))
                   : 0ULL;
  }

  const int nchunks = (K + 63) >> 6;
  unsigned long long pfA0 = mb[(size_t)(d0 + 0) * wpl + wkc];
  unsigned long long pfA1 = mb[(size_t)(d0 + 1) * wpl + wkc];
  unsigned long long pfA2 = mb[(size_t)(d0 + 2) * wpl + wkc];
  unsigned long long pfA3 = mb[(size_t)(d0 + 3) * wpl + wkc];
  unsigned long long pfB0 = mb[(size_t)(64 + d0 + 0) * wpl + wkc];
  unsigned long long pfB1 = mb[(size_t)(64 + d0 + 1) * wpl + wkc];
  unsigned long long pfB2 = mb[(size_t)(64 + d0 + 2) * wpl + wkc];
  unsigned long long pfB3 = mb[(size_t)(64 + d0 + 3) * wpl + wkc];
  unsigned long long dg = dT[(size_t)w * 64 + lane];
  int next_own = w + 8;

  int kept = 0;
  int c = 0;
  while (c < nchunks && kept < MAX_OUT) {
    SCAN_CHUNK(pfA0, pfA1, pfA2, pfA3)
    if (c >= nchunks || kept >= MAX_OUT) break;
    SCAN_CHUNK(pfB0, pfB1, pfB2, pfB3)
  }

  __syncthreads();
  const int kc = kept < MAX_OUT ? kept : MAX_OUT;
  const int base = img * M_TOT + LV_OFF[lvl];
  const size_t bo = (size_t)il * 1024;
  for (int i = tid; i < kc; i += 512) {
    unsigned r = skept[i];
    unsigned pp = n_pos[base + (int)r];
    kept_pos[bo + i] = pp;
    kept_key[bo + i] =
        ((unsigned long long)__float_as_uint(n_sc[base + (int)r]) << 32) |
        (unsigned)(~pp);
  }
  if (tid == 0) kept_cnt[il] = (unsigned)kc;
}

// ================= K3: per-(img,lvl) merge -> output rows (20 blocks) =========
__global__ __launch_bounds__(1024) void k_merge(const float* cand_box,
    const float* cand_s, const unsigned* kept_pos,
    const unsigned long long* kept_key, const unsigned* kept_cnt, float* out) {
  const int il = (int)blockIdx.x;      // img*5 + l
  const int img = il / 5, l = il % 5;
  const int tid = (int)threadIdx.x;
  __shared__ unsigned cnts[5];
  __shared__ unsigned long long skey[5][1024];
  if (tid < 5) {
    unsigned c = kept_cnt[img * 5 + tid];
    cnts[tid] = c < (unsigned)MAX_OUT ? c : (unsigned)MAX_OUT;
  }
  __syncthreads();
  for (int e = tid; e < 5 * 1024; e += 1024) {
    int l2 = e >> 10, s = e & 1023;
    skey[l2][s] = (s < (int)cnts[l2])
        ? kept_key[(size_t)(img * 5 + l2) * 1024 + s] : 0ULL;
  }
  __syncthreads();
  if (l == 0) {                        // one block per image zero-fills tail
    unsigned T = cnts[0] + cnts[1] + cnts[2] + cnts[3] + cnts[4];
    unsigned Tc = T < (unsigned)MAX_OUT ? T : (unsigned)MAX_OUT;
    for (int r = (int)Tc + tid; r < MAX_OUT; r += 1024) {
      float* o = out + (size_t)img * (MAX_OUT * 5) + (size_t)r * 5;
      o[0] = 0.f; o[1] = 0.f; o[2] = 0.f; o[3] = 0.f; o[4] = 0.f;
    }
  }
  const int s = tid;
  if (s >= (int)cnts[l]) return;
  unsigned long long k0 = skey[l][s];
  unsigned rank = (unsigned)s;
  #pragma unroll
  for (int l2 = 0; l2 < 5; ++l2) {
    if (l2 == l) continue;
    int lo = 0, hi = (int)cnts[l2];
    while (lo < hi) {
      int mid = (lo + hi) >> 1;
      if (skey[l2][mid] > k0) lo = mid + 1; else hi = mid;
    }
    rank += (unsigned)lo;
  }
  if (rank < (unsigned)MAX_OUT) {
    unsigned pos = kept_pos[(size_t)(img * 5 + l) * 1024 + s];
    const float* b = cand_box + (size_t)(img * M_TOT + pos) * 4;
    float* o = out + (size_t)img * (MAX_OUT * 5) + (size_t)rank * 5;
    o[0] = b[0]; o[1] = b[1]; o[2] = b[2]; o[3] = b[3];
    o[4] = cand_s[img * M_TOT + pos];
  }
}

// ================= host launch =================
extern "C" void kernel_launch(void* const* d_in, const int* in_sizes, int n_in,
                              void* d_out, int out_size, void* d_ws, size_t ws_size,
                              hipStream_t stream) {
  Ptrs p;
  bool interleaved = (n_in == 10 && in_sizes[1] == 4 * 12 * 128 * 128);
  for (int l = 0; l < 5; ++l) {
    if (interleaved) {
      p.cls[l] = (const float*)d_in[2 * l];
      p.reg[l] = (const float*)d_in[2 * l + 1];
    } else {
      p.cls[l] = (const float*)d_in[l];
      p.reg[l] = (const float*)d_in[5 + l];
    }
  }
  uint8_t* w = (uint8_t*)d_ws;
  size_t o = 0;
  auto carve = [&](size_t bytes) {
    void* ptr = w + o;
    o += (bytes + 255) & ~(size_t)255;
    return ptr;
  };
  // gcnt + ghist + vflags adjacent -> one zero kernel covers all three
  unsigned* gcnt = (unsigned*)carve((size_t)20 * 4);                 // 256B slot
  unsigned* ghist = (unsigned*)carve((size_t)20 * 4096 * 4);
  unsigned long long* vflags = (unsigned long long*)carve((size_t)20 * 32 * 8);
  size_t zero_bytes = 256 + (size_t)20 * 4096 * 4 + (size_t)20 * 32 * 8;
  unsigned long long* T64_arr = (unsigned long long*)carve((size_t)20 * 8);
  unsigned* u_arr = (unsigned*)carve((size_t)4 * U_PER_IMG * 4);
  float* cand_box = (float*)carve((size_t)4 * M_TOT * 4 * 4);
  float* cand_s = (float*)carve((size_t)4 * M_TOT * 4);
  float* n_x1 = (float*)carve((size_t)4 * M_TOT * 4);
  float* n_y1 = (float*)carve((size_t)4 * M_TOT * 4);
  float* n_x2 = (float*)carve((size_t)4 * M_TOT * 4);
  float* n_y2 = (float*)carve((size_t)4 * M_TOT * 4);
  float* n_ar = (float*)carve((size_t)4 * M_TOT * 4);
  float* n_sc = (float*)carve((size_t)4 * M_TOT * 4);
  unsigned* n_pos = (unsigned*)carve((size_t)4 * M_TOT * 4);
  unsigned* V_arr = (unsigned*)carve((size_t)20 * 4);
  unsigned* kept_pos = (unsigned*)carve((size_t)4 * 5 * 1024 * 4);
  unsigned long long* kept_key = (unsigned long long*)carve((size_t)4 * 5 * 1024 * 8);
  unsigned* kept_cnt = (unsigned*)carve((size_t)20 * 4);
  unsigned long long* diagT = (unsigned long long*)carve((size_t)20 * 40 * 64 * 8);
  unsigned long long* mask = (unsigned long long*)carve((size_t)4 * MWORDS_PER_IMG * 8);
  // gtk (20*4096 u64 = 640KB) aliases mask: dead before k_mask writes it.
  unsigned long long* gtk = mask;
  (void)ws_size; (void)out_size;

  int n4 = (int)(zero_bytes >> 4);
  k_zero<<<(n4 + 255) / 256, 256, 0, stream>>>((uint4*)gcnt, n4);
  k_sig<<<dim3(18, 4), 1024, 0, stream>>>(p, u_arr, ghist);
  k_thresh<<<20, 1024, 0, stream>>>(u_arr, ghist, T64_arr);
  k_collect<<<dim3(18, 4), 1024, 0, stream>>>(u_arr, T64_arr, gtk, gcnt);
  k_rank<<<dim3(16, 20), 256, 0, stream>>>(p, gtk, gcnt, cand_box, cand_s,
                                           vflags);
  k_part<<<20, 256, 0, stream>>>(cand_box, cand_s, vflags,
      n_x1, n_y1, n_x2, n_y2, n_ar, n_sc, n_pos, V_arr);
  k_mask<<<dim3(807, 4), 256, 0, stream>>>(n_x1, n_y1, n_x2, n_y2, n_ar,
                                           mask, diagT);
  k_scan<<<20, 512, 0, stream>>>(mask, diagT, n_pos, n_sc, V_arr,
                                 kept_pos, kept_key, kept_cnt);
  k_merge<<<20, 1024, 0, stream>>>(cand_box, cand_s, kept_pos, kept_key,
                                   kept_cnt, (float*)d_out);
}

// Round 15
// 114.291 us; speedup vs baseline: 2.1198x; 1.0196x over previous
//
#include <hip/hip_runtime.h>
#include <cstdint>
#include <cstddef>

// ---------------- constants ----------------
__constant__ int LV_N[5]    = {49152, 12288, 3072, 768, 192};   // H*W*3
__constant__ int LV_K[5]    = {2000, 2000, 2000, 768, 192};     // min(PRE_NMS, N)
__constant__ int LV_OFF[5]  = {0, 2000, 4000, 6000, 6768};      // concat offsets
__constant__ int LV_UOFF[5] = {0, 49152, 61440, 64512, 65280};  // u-array offsets
__constant__ int LV_W[5]    = {128, 64, 32, 16, 8};
__constant__ int LV_S[5]    = {4, 8, 16, 32, 64};
__constant__ int LV_LOGHW[5]= {14, 12, 10, 8, 6};
// mask geometry (rows padded by 192 so scan prefetch needs no bounds tests)
__constant__ int WPL[5]     = {32, 32, 32, 12, 3};              // words per row
__constant__ int MOFF[5]    = {0, 70144, 140288, 210432, 221952};
__constant__ int MB_BASE[6] = {0, 256, 512, 768, 804, 807};     // mask-block bases
__constant__ int MB_CT[5]   = {8, 8, 8, 3, 1};                  // col tiles per lvl
__constant__ int SGB6[6]    = {0, 12, 15, 16, 17, 18};          // 4096-elem tile bases

#define M_TOT 6960
#define U_PER_IMG 65472
#define MAX_OUT 1000
#define MWORDS_PER_IMG 223104
#define CAP 4096

struct Ptrs { const float* cls[5]; const float* reg[5]; };

// fl(inter/uni) > 0.7f  <=>  inter/uni >= MTH  (tie at MTH rounds to even
// mantissa 0x3F333334 > 0.7f). Evaluated in f64: exact except a ~2^-53 band.
#define MTH 0.7000000178813934326171875

// ---------------- XLA:CPU-compatible expf (Cephes/Eigen pexp, FMA-contracted) ----
__device__ __forceinline__ float xla_expf(float x) {
  const float exp_hi = 88.3762626647950f;
  const float exp_lo = -88.3762626647949f;
  const float log2ef = 1.44269504088896341f;
  const float c1 = 0.693359375f;
  const float c2 = -2.12194440e-4f;
  const float p0 = 1.9875691500e-4f;
  const float p1 = 1.3981999507e-3f;
  const float p2 = 8.3334519073e-3f;
  const float p3 = 4.1665795894e-2f;
  const float p4 = 1.6666665459e-1f;
  const float p5 = 5.0000001201e-1f;
  float xx = fminf(fmaxf(x, exp_lo), exp_hi);
  float fx = floorf(__fmaf_rn(xx, log2ef, 0.5f));
  float r = __fmaf_rn(fx, -c1, xx);
  r = __fmaf_rn(fx, -c2, r);
  float z = __fmul_rn(r, r);
  float y = __fmaf_rn(p0, r, p1);
  y = __fmaf_rn(y, r, p2);
  y = __fmaf_rn(y, r, p3);
  y = __fmaf_rn(y, r, p4);
  y = __fmaf_rn(y, r, p5);
  y = __fmaf_rn(y, z, r);
  y = __fadd_rn(y, 1.0f);
  int n = (int)fx;
  float two_n = __uint_as_float((unsigned)(n + 127) << 23);
  return __fmul_rn(y, two_n);
}

__device__ __forceinline__ float ref_sigmoid(float x) {
  return __fdiv_rn(1.0f, __fadd_rn(1.0f, xla_expf(-x)));
}

// ================= K0: wide sigmoid + per-block histogram slice ==============
// u stored PLANE-MAJOR (coalesced both sides). ghist is PER-BLOCK (plain
// stores, no pre-zero, no atomics); bx==0 blocks also zero vflags+gcnt.
__global__ __launch_bounds__(1024) void k_sig(Ptrs p, unsigned* u_arr,
    unsigned* ghist, unsigned long long* vflags, unsigned* gcnt) {
  const int img = blockIdx.y;
  const int bx = blockIdx.x;
  int lvl = 0;
  while (bx >= SGB6[lvl + 1]) ++lvl;
  const int N = LV_N[lvl];
  const int e0 = (bx - SGB6[lvl]) * 4096;
  const int e1 = (e0 + 4096 < N) ? e0 + 4096 : N;
  const int tid = (int)threadIdx.x;
  if (bx == 0) {
    if (tid < 160) vflags[(size_t)img * 160 + tid] = 0ULL;
    if (tid < 5) gcnt[img * 5 + tid] = 0u;
  }
  __shared__ unsigned h[4096];
  for (int e = tid; e < 4096; e += 1024) h[e] = 0;
  __syncthreads();
  const float* cls = p.cls[lvl] + (size_t)img * N;
  unsigned* u = u_arr + img * U_PER_IMG + LV_UOFF[lvl];
  for (int e = e0 + tid; e < e1; e += 1024) {
    float logit = cls[e];                  // plane-major: fully coalesced
    unsigned ub = __float_as_uint(ref_sigmoid(logit));
    u[e] = ub;                             // plane-major: coalesced store
    atomicAdd(&h[(ub >> 18) & 4095u], 1u);
  }
  __syncthreads();
  unsigned* gh = ghist + ((size_t)(img * 18 + bx) << 12);
  for (int e = tid; e < 4096; e += 1024) gh[e] = h[e];
}

// ================= K1a: threshold pick (hierarchical wave suffix-scan) =======
__global__ __launch_bounds__(1024) void k_thresh(const unsigned* u_arr,
    const unsigned* ghist, unsigned long long* T64_arr) {
  const int blk = blockIdx.x;
  const int img = blk / 5, lvl = blk % 5;
  const int N = LV_N[lvl], K = LV_K[lvl], LOGHW = LV_LOGHW[lvl];
  const int HW = 1 << LOGHW;
  const int tid = (int)threadIdx.x;
  const int lane = tid & 63, w = tid >> 6;
  if (N <= K) { if (tid == 0) T64_arr[blk] = 0ULL; return; }
  __shared__ unsigned h[4096];
  __shared__ unsigned wsum[16], wsuf[16];
  __shared__ unsigned sh_D, sh_sD, sh_sD1;
  const unsigned* u = u_arr + img * U_PER_IMG + LV_UOFF[lvl];

  unsigned long long prefix = 0;
  unsigned want = (unsigned)K, above = 0;
  const int shifts[6] = {50, 38, 26, 14, 2, 0};
  for (int rd = 0; rd < 6; ++rd) {
    const int shift = shifts[rd];
    if (rd == 5) {                          // final 2-bit round: trivial serial
      for (int e = tid; e < 4; e += 1024) h[e] = 0;
      __syncthreads();
      for (int q = tid; q < N; q += 1024) {
        unsigned a = (unsigned)q >> LOGHW, pix = (unsigned)q & (unsigned)(HW - 1);
        unsigned ecl = pix * 3u + a;
        unsigned long long key =
            ((unsigned long long)u[q] << 32) | (unsigned)(~ecl);
        if ((key >> 2) == prefix) atomicAdd(&h[(unsigned)key & 3u], 1u);
      }
      __syncthreads();
      if (tid == 0) {
        unsigned cum = 0; int D = 0;
        for (int v = 3; v >= 0; --v) {
          if (cum + h[v] >= want) { D = v; break; }
          cum += h[v];
        }
        T64_arr[blk] = (prefix << 2) | (unsigned)D;
      }
      return;
    }
    unsigned h0, h1, h2, h3;
    if (rd == 0) {                         // sum per-block slices (uint4 loads)
      h0 = h1 = h2 = h3 = 0;
      for (int t = SGB6[lvl]; t < SGB6[lvl + 1]; ++t) {
        const uint4* g4 = (const uint4*)(ghist + ((size_t)(img * 18 + t) << 12));
        uint4 v = g4[tid];
        h0 += v.x; h1 += v.y; h2 += v.z; h3 += v.w;
      }
    } else {                               // exact rescan (rarely taken)
      for (int e = tid; e < 4096; e += 1024) h[e] = 0;
      __syncthreads();
      for (int q = tid; q < N; q += 1024) {
        unsigned a = (unsigned)q >> LOGHW, pix = (unsigned)q & (unsigned)(HW - 1);
        unsigned ecl = pix * 3u + a;
        unsigned long long key =
            ((unsigned long long)u[q] << 32) | (unsigned)(~ecl);
        if ((key >> (shift + 12)) == prefix)
          atomicAdd(&h[(unsigned)(key >> shift) & 4095u], 1u);
      }
      __syncthreads();
      h0 = h[4 * tid + 0]; h1 = h[4 * tid + 1];
      h2 = h[4 * tid + 2]; h3 = h[4 * tid + 3];
    }
    // hierarchical suffix scan: 4 elems/thread, wave shfl, 16-wave combine
    unsigned s = h0 + h1 + h2 + h3;
    unsigned suf = s;
    #pragma unroll
    for (int off = 1; off < 64; off <<= 1) {
      unsigned t2 = __shfl_down(suf, off);
      if (lane + off < 64) suf += t2;
    }
    if (lane == 0) wsum[w] = suf;
    __syncthreads();
    if (tid < 16) {
      unsigned v = wsum[tid];
      #pragma unroll
      for (int off = 1; off < 16; off <<= 1) {
        unsigned t2 = __shfl_down(v, off);
        if (tid + off < 16) v += t2;
      }
      wsuf[tid] = v;
    }
    __syncthreads();
    unsigned Sth = ((w + 1 < 16) ? wsuf[w + 1] : 0u) + (suf - s);
    unsigned f3 = Sth + h3;
    unsigned f2 = f3 + h2;
    unsigned f1 = f2 + h1;
    unsigned f0 = f1 + h0;
    if (f0 >= want && f1 < want) { sh_D = 4u * tid + 0; sh_sD = f0; sh_sD1 = f1; }
    if (f1 >= want && f2 < want) { sh_D = 4u * tid + 1; sh_sD = f1; sh_sD1 = f2; }
    if (f2 >= want && f3 < want) { sh_D = 4u * tid + 2; sh_sD = f2; sh_sD1 = f3; }
    if (f3 >= want && Sth < want) { sh_D = 4u * tid + 3; sh_sD = f3; sh_sD1 = Sth; }
    __syncthreads();
    unsigned D = sh_D, sD = sh_sD, sD1 = sh_sD1;
    unsigned long long npref = (prefix << 12) | (unsigned long long)D;
    if (above + sD <= (unsigned)CAP) {
      if (tid == 0) T64_arr[blk] = npref << shift;
      return;                              // uniform decision across block
    }
    above += sD1; want -= sD1; prefix = npref;
    __syncthreads();
  }
}

// ================= K1b: wide collect, ONE global atomic per block ============
__global__ __launch_bounds__(1024) void k_collect(const unsigned* u_arr,
    const unsigned long long* T64_arr, unsigned long long* gtk, unsigned* gcnt) {
  const int img = blockIdx.y;
  const int bx = blockIdx.x;
  int lvl = 0;
  while (bx >= SGB6[lvl + 1]) ++lvl;
  const int N = LV_N[lvl], LOGHW = LV_LOGHW[lvl];
  const int HW = 1 << LOGHW;
  const int e0 = (bx - SGB6[lvl]) * 4096;
  const int tid = (int)threadIdx.x;
  const int lane = tid & 63;
  const int w = tid >> 6;                     // 16 waves
  const unsigned long long T = T64_arr[img * 5 + lvl];
  const unsigned* u = u_arr + img * U_PER_IMG + LV_UOFF[lvl];

  __shared__ unsigned wcnt[64];               // [wave*4 + iter] -> offsets

  unsigned long long key0 = 0, key1 = 0, key2 = 0, key3 = 0;
  unsigned long long bm0, bm1, bm2, bm3;
  #define MKKEY(KV, Q)                                                      \
    {                                                                       \
      unsigned a_ = (unsigned)(Q) >> LOGHW;                                 \
      unsigned pix_ = (unsigned)(Q) & (unsigned)(HW - 1);                   \
      unsigned ecl_ = pix_ * 3u + a_;                                       \
      KV = ((unsigned long long)u[Q] << 32) | (unsigned)(~ecl_);            \
    }
  {
    int q = e0 + 0 * 1024 + tid;
    bool pr = false;
    if (q < N) { MKKEY(key0, q) pr = key0 >= T; }
    bm0 = __ballot(pr);
    if (lane == 0) wcnt[w * 4 + 0] = (unsigned)__popcll(bm0);
  }
  {
    int q = e0 + 1 * 1024 + tid;
    bool pr = false;
    if (q < N) { MKKEY(key1, q) pr = key1 >= T; }
    bm1 = __ballot(pr);
    if (lane == 0) wcnt[w * 4 + 1] = (unsigned)__popcll(bm1);
  }
  {
    int q = e0 + 2 * 1024 + tid;
    bool pr = false;
    if (q < N) { MKKEY(key2, q) pr = key2 >= T; }
    bm2 = __ballot(pr);
    if (lane == 0) wcnt[w * 4 + 2] = (unsigned)__popcll(bm2);
  }
  {
    int q = e0 + 3 * 1024 + tid;
    bool pr = false;
    if (q < N) { MKKEY(key3, q) pr = key3 >= T; }
    bm3 = __ballot(pr);
    if (lane == 0) wcnt[w * 4 + 3] = (unsigned)__popcll(bm3);
  }
  #undef MKKEY
  __syncthreads();
  if (tid < 64) {
    unsigned c = wcnt[tid];
    unsigned pre = c;
    #pragma unroll
    for (int off = 1; off < 64; off <<= 1) {
      unsigned t = __shfl_up(pre, off);
      if (tid >= off) pre += t;
    }
    unsigned total = __shfl(pre, 63);
    unsigned base = 0;
    if (tid == 63 && total) base = atomicAdd(gcnt + (img * 5 + lvl), total);
    base = __shfl(base, 63);
    wcnt[tid] = base + pre - c;               // exclusive (wave,iter) offset
  }
  __syncthreads();
  unsigned long long* dst = gtk + (size_t)(img * 5 + lvl) * CAP;
  const unsigned long long below = (1ULL << lane) - 1ULL;
  if ((bm0 >> lane) & 1ULL) {
    unsigned slot = wcnt[w * 4 + 0] + (unsigned)__popcll(bm0 & below);
    if (slot < (unsigned)CAP) dst[slot] = key0;
  }
  if ((bm1 >> lane) & 1ULL) {
    unsigned slot = wcnt[w * 4 + 1] + (unsigned)__popcll(bm1 & below);
    if (slot < (unsigned)CAP) dst[slot] = key1;
  }
  if ((bm2 >> lane) & 1ULL) {
    unsigned slot = wcnt[w * 4 + 2] + (unsigned)__popcll(bm2 & below);
    if (slot < (unsigned)CAP) dst[slot] = key2;
  }
  if ((bm3 >> lane) & 1ULL) {
    unsigned slot = wcnt[w * 4 + 3] + (unsigned)__popcll(bm3 & below);
    if (slot < (unsigned)CAP) dst[slot] = key3;
  }
}

// ================= K1c: brute-force rank + direct decode (no sort) ===========
__global__ __launch_bounds__(256) void k_rank(Ptrs p,
    const unsigned long long* gtk, const unsigned* gcnt,
    float* cand_box, float* cand_s, unsigned long long* vflags) {
  const int il = (int)blockIdx.y;
  const int img = il / 5, lvl = il % 5;
  const int N = LV_N[lvl], K = LV_K[lvl], W = LV_W[lvl], S = LV_S[lvl];
  const int HW = N / 3;
  const float* reg = p.reg[lvl] + (size_t)img * 12 * HW;
  const int tid = (int)threadIdx.x;
  unsigned cnt = gcnt[il];
  if (cnt > (unsigned)CAP) cnt = CAP;
  if ((unsigned)blockIdx.x * 256u >= cnt) return;   // uniform: skip staging too
  const unsigned cnt32 = (cnt + 31u) & ~31u;
  __shared__ ulonglong2 keys2[CAP / 2];
  unsigned long long* keys = (unsigned long long*)keys2;
  const unsigned long long* src = gtk + (size_t)il * CAP;
  for (int e = tid; e < (int)cnt32; e += 256)
    keys[e] = (e < (int)cnt) ? src[e] : 0ULL;   // real keys >= 2^32 > 0 pad
  __syncthreads();
  const int s = (int)blockIdx.x * 256 + tid;
  if (s >= (int)cnt) return;
  const unsigned long long mykey = keys[s];
  unsigned r0 = 0, r1 = 0, r2 = 0, r3 = 0;
  const unsigned half = cnt32 >> 1;           // # of ulonglong2 entries
  for (unsigned j = 0; j < half; j += 16) {
    #pragma unroll
    for (int q = 0; q < 16; q += 4) {
      ulonglong2 a = keys2[j + q + 0];
      ulonglong2 b = keys2[j + q + 1];
      ulonglong2 cc = keys2[j + q + 2];
      ulonglong2 d = keys2[j + q + 3];
      r0 += (a.x > mykey ? 1u : 0u) + (a.y > mykey ? 1u : 0u);
      r1 += (b.x > mykey ? 1u : 0u) + (b.y > mykey ? 1u : 0u);
      r2 += (cc.x > mykey ? 1u : 0u) + (cc.y > mykey ? 1u : 0u);
      r3 += (d.x > mykey ? 1u : 0u) + (d.y > mykey ? 1u : 0u);
    }
  }
  unsigned rank = r0 + r1 + r2 + r3;
  if (rank >= (unsigned)K) return;

  unsigned ubits = (unsigned)(mykey >> 32);
  unsigned idx = ~((unsigned)mykey);
  int a = (int)(idx % 3u); int pix = (int)(idx / 3u);
  int xq = pix % W, yq = pix / W;
  float dx = reg[(a * 4 + 0) * HW + pix];
  float dy = reg[(a * 4 + 1) * HW + pix];
  float dw = reg[(a * 4 + 2) * HW + pix];
  float dh = reg[(a * 4 + 3) * HW + pix];
  double rr = (a == 0) ? 0.5 : (a == 1 ? 1.0 : 2.0);
  double hr = sqrt(rr), wr = 1.0 / hr;
  double st = (double)S;
  double wsd = st * wr * 8.0, hsd = st * hr * 8.0;
  double sxd = (double)(xq * S), syd = (double)(yq * S);
  float a0 = (float)(sxd - 0.5 * wsd), a1 = (float)(syd - 0.5 * hsd);
  float a2 = (float)(sxd + 0.5 * wsd), a3 = (float)(syd + 0.5 * hsd);
  float px = __fmul_rn(__fadd_rn(a0, a2), 0.5f);
  float py = __fmul_rn(__fadd_rn(a1, a3), 0.5f);
  float pw = __fsub_rn(a2, a0), ph = __fsub_rn(a3, a1);
  const float MRf = 4.135166556742356f;  // |log(16/1000)| rounded to f32
  float dwc = fminf(fmaxf(dw, -MRf), MRf);
  float dhc = fminf(fmaxf(dh, -MRf), MRf);
  float gw = __fmul_rn(pw, xla_expf(dwc));
  float gh = __fmul_rn(ph, xla_expf(dhc));
  float gx = __fmaf_rn(pw, dx, px);
  float gy = __fmaf_rn(ph, dy, py);
  float x1 = fminf(fmaxf(__fmaf_rn(gw, -0.5f, gx), 0.0f), 512.0f);
  float y1 = fminf(fmaxf(__fmaf_rn(gh, -0.5f, gy), 0.0f), 512.0f);
  float x2 = fminf(fmaxf(__fmaf_rn(gw,  0.5f, gx), 0.0f), 512.0f);
  float y2 = fminf(fmaxf(__fmaf_rn(gh,  0.5f, gy), 0.0f), 512.0f);
  bool valid = (__fsub_rn(x2, x1) > 0.0f) && (__fsub_rn(y2, y1) > 0.0f);
  int pos = img * M_TOT + LV_OFF[lvl] + (int)rank;
  cand_box[(size_t)pos * 4 + 0] = x1;
  cand_box[(size_t)pos * 4 + 1] = y1;
  cand_box[(size_t)pos * 4 + 2] = x2;
  cand_box[(size_t)pos * 4 + 3] = y2;
  float score = __uint_as_float(ubits);
  cand_s[pos] = valid ? score : -1.0f;
  if (valid)
    atomicOr(&vflags[(size_t)il * 32 + (rank >> 6)], 1ULL << (rank & 63));
}

// ================= K1d: partition (valids first) + NMS-order arrays ==========
__global__ __launch_bounds__(256) void k_part(const float* cand_box,
    const float* cand_s, const unsigned long long* vflags,
    float* n_x1, float* n_y1, float* n_x2, float* n_y2, float* n_ar,
    float* n_sc, unsigned* n_pos, unsigned* V_arr) {
  const int il = (int)blockIdx.x;
  const int img = il / 5, lvl = il % 5;
  const int K = LV_K[lvl];
  const int tid = (int)threadIdx.x;
  __shared__ unsigned long long sflag[32];
  __shared__ unsigned wpre[33];
  if (tid < 32) sflag[tid] = vflags[(size_t)il * 32 + tid];
  __syncthreads();
  if (tid < 32) {
    unsigned c = (unsigned)__popcll(sflag[tid]);
    #pragma unroll
    for (int off = 1; off < 32; off <<= 1) {
      unsigned t = __shfl_up(c, off);
      if (tid >= off) c += t;
    }
    wpre[tid + 1] = c;
    if (tid == 0) wpre[0] = 0;
  }
  __syncthreads();
  const unsigned V = wpre[32];
  const float offv = __fmul_rn((float)lvl, 513.0f);
  const int base = img * M_TOT + LV_OFF[lvl];
  for (int r = tid; r < K; r += 256) {
    unsigned long long word = sflag[r >> 6];
    unsigned fl = (unsigned)((word >> (r & 63)) & 1ULL);
    unsigned excl = wpre[r >> 6] +
                    (unsigned)__popcll(word & ((1ULL << (r & 63)) - 1ULL));
    unsigned pdst = fl ? excl : V + ((unsigned)r - excl);
    const float* b = cand_box + (size_t)(base + r) * 4;
    float ox1 = __fadd_rn(b[0], offv), oy1 = __fadd_rn(b[1], offv);
    float ox2 = __fadd_rn(b[2], offv), oy2 = __fadd_rn(b[3], offv);
    int dst = base + (int)pdst;
    n_x1[dst] = ox1; n_y1[dst] = oy1; n_x2[dst] = ox2; n_y2[dst] = oy2;
    n_ar[dst] = __fmul_rn(__fsub_rn(ox2, ox1), __fsub_rn(oy2, oy1));
    n_sc[dst] = cand_s[base + r];
    n_pos[dst] = (unsigned)(LV_OFF[lvl] + r);
  }
  if (tid == 0) V_arr[il] = V;
}

// ================= K2a: suppression bit-matrix build + diag transpose ========
#define TSTAGE(S, M)                                                        \
  {                                                                         \
    unsigned long long t_ = __shfl_xor(x, S);                               \
    x = (lane & S) ? ((x & (M)) | ((t_ >> S) & ~(M)))                       \
                   : ((x & ~(M)) | ((t_ << S) & (M)));                      \
  }

__global__ __launch_bounds__(256) void k_mask(
    const float* n_x1, const float* n_y1, const float* n_x2, const float* n_y2,
    const float* n_ar, unsigned long long* mask, unsigned long long* diagT) {
  const int img = blockIdx.y;
  const int bx = blockIdx.x;
  int lvl = 0;
  while (bx >= MB_BASE[lvl + 1]) ++lvl;
  const int t = bx - MB_BASE[lvl];
  const int ct = MB_CT[lvl];
  const int rt = t / ct, c = t % ct;
  const int K = LV_K[lvl];
  const int row0 = rt * 64, col0 = c * 256;
  if (col0 + 255 <= row0) return;  // entire tile has j <= r: bits never consumed

  __shared__ float4 cb4[256];
  __shared__ float cba[256];
  __shared__ float4 rb4[64];
  __shared__ float rba[64];
  const int base = img * M_TOT + LV_OFF[lvl];
  const int tid = (int)threadIdx.x;
  if (tid < 64) {
    int r = row0 + tid;
    if (r < K) {
      rb4[tid] = make_float4(n_x1[base + r], n_y1[base + r],
                             n_x2[base + r], n_y2[base + r]);
      rba[tid] = n_ar[base + r];
    } else {
      rb4[tid] = make_float4(0.f, 0.f, 0.f, 0.f);
      rba[tid] = 0.f;
    }
  }
  {
    int j = col0 + tid;
    if (j < K) {
      cb4[tid] = make_float4(n_x1[base + j], n_y1[base + j],
                             n_x2[base + j], n_y2[base + j]);
      cba[tid] = n_ar[base + j];
    }
  }
  __syncthreads();
  const int wl = tid >> 6, lane = tid & 63;
  // word entirely below the diagonal: its bits only ever target chunks that
  // are already materialized in k_scan (ln < r>>6 provably) -> never consumed.
  // (diag word col0+64*wl==row0 never satisfies this.)
  if (col0 + (wl << 6) + 63 <= row0) return;
  const int r = row0 + lane;
  const bool rvalid = (r < K);
  const float4 rb = rb4[lane];
  const float rar = rba[lane];
  unsigned long long word = 0ULL;
  const int jbase = wl * 64;
  const int jmax = K - col0 - jbase;   // bit k valid iff k < jmax
  #pragma unroll 16
  for (int k = 0; k < 64; ++k) {
    float4 cb = cb4[jbase + k];        // broadcast: all lanes same address
    float car = cba[jbase + k];
    float iw = fmaxf(__fsub_rn(fminf(rb.z, cb.z), fmaxf(rb.x, cb.x)), 0.0f);
    float ih = fmaxf(__fsub_rn(fminf(rb.w, cb.w), fmaxf(rb.y, cb.y)), 0.0f);
    float inter = __fmul_rn(iw, ih);
    float uni = __fsub_rn(__fadd_rn(rar, car), inter);
    bool sup = (uni > 0.0f) && ((double)inter >= MTH * (double)uni);
    if (sup && k < jmax) word |= (1ULL << k);
  }
  if (!rvalid) word = 0ULL;
  if (rvalid)
    mask[(size_t)img * MWORDS_PER_IMG + MOFF[lvl] +
         (size_t)r * WPL[lvl] + (size_t)((col0 >> 6) + wl)] = word;
  // diag 64x64 block of this chunk lives in word wl where col0+64*wl == row0:
  // transpose it across lanes (lane i -> column i) and store to diagT.
  if (col0 + (wl << 6) == row0) {
    unsigned long long x = word;
    TSTAGE(32, 0xFFFFFFFF00000000ULL)
    TSTAGE(16, 0xFFFF0000FFFF0000ULL)
    TSTAGE(8,  0xFF00FF00FF00FF00ULL)
    TSTAGE(4,  0xF0F0F0F0F0F0F0F0ULL)
    TSTAGE(2,  0xCCCCCCCCCCCCCCCCULL)
    TSTAGE(1,  0xAAAAAAAAAAAAAAAAULL)
    diagT[(size_t)(img * 5 + lvl) * (40 * 64) + (size_t)rt * 64 + lane] = x;
  }
}

// ================= K2b: 8-wave chunked greedy scan ===========================
#define SCAN_CHUNK(P0, P1, P2, P3)                                          \
  {                                                                         \
    const int r0 = c << 6;                                                  \
    if (w == (c & 7)) {                                                     \
      unsigned long long v = (g == (c >> 3)) ? aw : ~0ULL;                  \
      v &= __shfl_xor(v, 1);                                                \
      v &= __shfl_xor(v, 2);                                                \
      v &= __shfl_xor(v, 4);                                                \
      v &= __shfl_xor(v, 8);                                                \
      v = __shfl(v, (c >> 3) * 16);                                         \
      unsigned long long x = dg;                                            \
      unsigned long long kw = v;                                            \
      while (true) {                                                        \
        bool keep_j = (((v >> lane) & 1ULL) != 0ULL) &&                     \
                      ((kw & below & x) == 0ULL);                           \
        unsigned long long nkw = __ballot(keep_j);                          \
        if (nkw == kw) break;                                               \
        kw = nkw;                                                           \
      }                                                                     \
      if ((kw >> lane) & 1ULL)                                              \
        skept[kept + (int)__popcll(kw & below)] = (unsigned)(r0 + lane);    \
      if (lane == 0) s_kw[c & 1] = kw;                                      \
      int no_ = next_own < 40 ? next_own : 39;                              \
      dg = dT[(size_t)no_ * 64 + lane];                                     \
      next_own += 8;                                                        \
    }                                                                       \
    __syncthreads();                                                        \
    unsigned long long kwv = s_kw[c & 1];                                   \
    kept += (int)__popcll(kwv);                                             \
    aw &= ~(P0 & (unsigned long long)((long long)(kwv << (63 - (d0 + 0))) >> 63)); \
    aw &= ~(P1 & (unsigned long long)((long long)(kwv << (63 - (d0 + 1))) >> 63)); \
    aw &= ~(P2 & (unsigned long long)((long long)(kwv << (63 - (d0 + 2))) >> 63)); \
    aw &= ~(P3 & (unsigned long long)((long long)(kwv << (63 - (d0 + 3))) >> 63)); \
    P0 = mb[(size_t)(r0 + 128 + d0 + 0) * wpl + wkc];                       \
    P1 = mb[(size_t)(r0 + 128 + d0 + 1) * wpl + wkc];                       \
    P2 = mb[(size_t)(r0 + 128 + d0 + 2) * wpl + wkc];                       \
    P3 = mb[(size_t)(r0 + 128 + d0 + 3) * wpl + wkc];                       \
    ++c;                                                                    \
  }

__global__ __launch_bounds__(512) void k_scan(const unsigned long long* mask,
    const unsigned long long* diagT,
    const unsigned* n_pos, const float* n_sc, const unsigned* V_arr,
    unsigned* kept_pos, unsigned long long* kept_key, unsigned* kept_cnt) {
  const int il = (int)blockIdx.x;
  const int img = il / 5, lvl = il % 5;
  const int K = LV_K[lvl], wpl = WPL[lvl];
  const int tid = (int)threadIdx.x;
  const int w = tid >> 6, lane = tid & 63;
  const unsigned long long* mb =
      mask + (size_t)img * MWORDS_PER_IMG + MOFF[lvl];
  const unsigned long long* dT = diagT + (size_t)il * (40 * 64);

  __shared__ unsigned long long s_kw[2];
  __shared__ unsigned skept[MAX_OUT + 64];

  const int g = lane >> 4;
  const int wk = w + 8 * g;
  const int wkc = wk < wpl ? wk : 0;      // clamped (dup loads harmless)
  const int d0 = (lane & 15) * 4;         // my 4 suppression rows per chunk
  const unsigned long long below = (1ULL << lane) - 1ULL;

  const int V = (int)V_arr[il];
  unsigned long long aw;
  {
    int lo = wk * 64, hi = V < lo + 64 ? V : lo + 64;
    aw = (hi > lo) ? ((hi - lo == 64) ? ~0ULL : ((1ULL << (hi - lo)) - 1ULL))
                   : 0ULL;
  }

  const int nchunks = (K + 63) >> 6;
  unsigned long long pfA0 = mb[(size_t)(d0 + 0) * wpl + wkc];
  unsigned long long pfA1 = mb[(size_t)(d0 + 1) * wpl + wkc];
  unsigned long long pfA2 = mb[(size_t)(d0 + 2) * wpl + wkc];
  unsigned long long pfA3 = mb[(size_t)(d0 + 3) * wpl + wkc];
  unsigned long long pfB0 = mb[(size_t)(64 + d0 + 0) * wpl + wkc];
  unsigned long long pfB1 = mb[(size_t)(64 + d0 + 1) * wpl + wkc];
  unsigned long long pfB2 = mb[(size_t)(64 + d0 + 2) * wpl + wkc];
  unsigned long long pfB3 = mb[(size_t)(64 + d0 + 3) * wpl + wkc];
  unsigned long long dg = dT[(size_t)w * 64 + lane];
  int next_own = w + 8;

  int kept = 0;
  int c = 0;
  while (c < nchunks && kept < MAX_OUT) {
    SCAN_CHUNK(pfA0, pfA1, pfA2, pfA3)
    if (c >= nchunks || kept >= MAX_OUT) break;
    SCAN_CHUNK(pfB0, pfB1, pfB2, pfB3)
  }

  __syncthreads();
  const int kc = kept < MAX_OUT ? kept : MAX_OUT;
  const int base = img * M_TOT + LV_OFF[lvl];
  const size_t bo = (size_t)il * 1024;
  for (int i = tid; i < kc; i += 512) {
    unsigned r = skept[i];
    unsigned pp = n_pos[base + (int)r];
    kept_pos[bo + i] = pp;
    kept_key[bo + i] =
        ((unsigned long long)__float_as_uint(n_sc[base + (int)r]) << 32) |
        (unsigned)(~pp);
  }
  if (tid == 0) kept_cnt[il] = (unsigned)kc;
}

// ================= K3: per-(img,lvl) merge -> output rows (20 blocks) =========
__global__ __launch_bounds__(1024) void k_merge(const float* cand_box,
    const float* cand_s, const unsigned* kept_pos,
    const unsigned long long* kept_key, const unsigned* kept_cnt, float* out) {
  const int il = (int)blockIdx.x;      // img*5 + l
  const int img = il / 5, l = il % 5;
  const int tid = (int)threadIdx.x;
  __shared__ unsigned cnts[5];
  __shared__ unsigned long long skey[5][1024];
  if (tid < 5) {
    unsigned c = kept_cnt[img * 5 + tid];
    cnts[tid] = c < (unsigned)MAX_OUT ? c : (unsigned)MAX_OUT;
  }
  __syncthreads();
  for (int e = tid; e < 5 * 1024; e += 1024) {
    int l2 = e >> 10, s = e & 1023;
    skey[l2][s] = (s < (int)cnts[l2])
        ? kept_key[(size_t)(img * 5 + l2) * 1024 + s] : 0ULL;
  }
  __syncthreads();
  if (l == 0) {                        // one block per image zero-fills tail
    unsigned T = cnts[0] + cnts[1] + cnts[2] + cnts[3] + cnts[4];
    unsigned Tc = T < (unsigned)MAX_OUT ? T : (unsigned)MAX_OUT;
    for (int r = (int)Tc + tid; r < MAX_OUT; r += 1024) {
      float* o = out + (size_t)img * (MAX_OUT * 5) + (size_t)r * 5;
      o[0] = 0.f; o[1] = 0.f; o[2] = 0.f; o[3] = 0.f; o[4] = 0.f;
    }
  }
  const int s = tid;
  if (s >= (int)cnts[l]) return;
  unsigned long long k0 = skey[l][s];
  unsigned rank = (unsigned)s;
  #pragma unroll
  for (int l2 = 0; l2 < 5; ++l2) {
    if (l2 == l) continue;
    int lo = 0, hi = (int)cnts[l2];
    while (lo < hi) {
      int mid = (lo + hi) >> 1;
      if (skey[l2][mid] > k0) lo = mid + 1; else hi = mid;
    }
    rank += (unsigned)lo;
  }
  if (rank < (unsigned)MAX_OUT) {
    unsigned pos = kept_pos[(size_t)(img * 5 + l) * 1024 + s];
    const float* b = cand_box + (size_t)(img * M_TOT + pos) * 4;
    float* o = out + (size_t)img * (MAX_OUT * 5) + (size_t)rank * 5;
    o[0] = b[0]; o[1] = b[1]; o[2] = b[2]; o[3] = b[3];
    o[4] = cand_s[img * M_TOT + pos];
  }
}

// ================= host launch =================
extern "C" void kernel_launch(void* const* d_in, const int* in_sizes, int n_in,
                              void* d_out, int out_size, void* d_ws, size_t ws_size,
                              hipStream_t stream) {
  Ptrs p;
  bool interleaved = (n_in == 10 && in_sizes[1] == 4 * 12 * 128 * 128);
  for (int l = 0; l < 5; ++l) {
    if (interleaved) {
      p.cls[l] = (const float*)d_in[2 * l];
      p.reg[l] = (const float*)d_in[2 * l + 1];
    } else {
      p.cls[l] = (const float*)d_in[l];
      p.reg[l] = (const float*)d_in[5 + l];
    }
  }
  uint8_t* w = (uint8_t*)d_ws;
  size_t o = 0;
  auto carve = [&](size_t bytes) {
    void* ptr = w + o;
    o += (bytes + 255) & ~(size_t)255;
    return ptr;
  };
  unsigned* gcnt = (unsigned*)carve((size_t)20 * 4);
  unsigned* ghist = (unsigned*)carve((size_t)72 * 4096 * 4);   // per-block slices
  unsigned long long* vflags = (unsigned long long*)carve((size_t)20 * 32 * 8);
  unsigned long long* T64_arr = (unsigned long long*)carve((size_t)20 * 8);
  unsigned* u_arr = (unsigned*)carve((size_t)4 * U_PER_IMG * 4);
  float* cand_box = (float*)carve((size_t)4 * M_TOT * 4 * 4);
  float* cand_s = (float*)carve((size_t)4 * M_TOT * 4);
  float* n_x1 = (float*)carve((size_t)4 * M_TOT * 4);
  float* n_y1 = (float*)carve((size_t)4 * M_TOT * 4);
  float* n_x2 = (float*)carve((size_t)4 * M_TOT * 4);
  float* n_y2 = (float*)carve((size_t)4 * M_TOT * 4);
  float* n_ar = (float*)carve((size_t)4 * M_TOT * 4);
  float* n_sc = (float*)carve((size_t)4 * M_TOT * 4);
  unsigned* n_pos = (unsigned*)carve((size_t)4 * M_TOT * 4);
  unsigned* V_arr = (unsigned*)carve((size_t)20 * 4);
  unsigned* kept_pos = (unsigned*)carve((size_t)4 * 5 * 1024 * 4);
  unsigned long long* kept_key = (unsigned long long*)carve((size_t)4 * 5 * 1024 * 8);
  unsigned* kept_cnt = (unsigned*)carve((size_t)20 * 4);
  unsigned long long* diagT = (unsigned long long*)carve((size_t)20 * 40 * 64 * 8);
  unsigned long long* mask = (unsigned long long*)carve((size_t)4 * MWORDS_PER_IMG * 8);
  // gtk (20*4096 u64 = 640KB) aliases mask: dead before k_mask writes it.
  unsigned long long* gtk = mask;
  (void)ws_size; (void)out_size;

  k_sig<<<dim3(18, 4), 1024, 0, stream>>>(p, u_arr, ghist, vflags, gcnt);
  k_thresh<<<20, 1024, 0, stream>>>(u_arr, ghist, T64_arr);
  k_collect<<<dim3(18, 4), 1024, 0, stream>>>(u_arr, T64_arr, gtk, gcnt);
  k_rank<<<dim3(16, 20), 256, 0, stream>>>(p, gtk, gcnt, cand_box, cand_s,
                                           vflags);
  k_part<<<20, 256, 0, stream>>>(cand_box, cand_s, vflags,
      n_x1, n_y1, n_x2, n_y2, n_ar, n_sc, n_pos, V_arr);
  k_mask<<<dim3(807, 4), 256, 0, stream>>>(n_x1, n_y1, n_x2, n_y2, n_ar,
                                           mask, diagT);
  k_scan<<<20, 512, 0, stream>>>(mask, diagT, n_pos, n_sc, V_arr,
                                 kept_pos, kept_key, kept_cnt);
  k_merge<<<20, 1024, 0, stream>>>(cand_box, cand_s, kept_pos, kept_key,
                                   kept_cnt, (float*)d_out);
}

// Round 16
// 110.774 us; speedup vs baseline: 2.1871x; 1.0318x over previous
//
#include <hip/hip_runtime.h>
#include <cstdint>
#include <cstddef>

// ---------------- constants ----------------
__constant__ int LV_N[5]    = {49152, 12288, 3072, 768, 192};   // H*W*3
__constant__ int LV_K[5]    = {2000, 2000, 2000, 768, 192};     // min(PRE_NMS, N)
__constant__ int LV_OFF[5]  = {0, 2000, 4000, 6000, 6768};      // concat offsets
__constant__ int LV_UOFF[5] = {0, 49152, 61440, 64512, 65280};  // u-array offsets
__constant__ int LV_W[5]    = {128, 64, 32, 16, 8};
__constant__ int LV_S[5]    = {4, 8, 16, 32, 64};
__constant__ int LV_LOGHW[5]= {14, 12, 10, 8, 6};
// mask geometry (rows padded by 192 so scan prefetch needs no bounds tests)
__constant__ int WPL[5]     = {32, 32, 32, 12, 3};              // words per row
__constant__ int MOFF[5]    = {0, 70144, 140288, 210432, 221952};
__constant__ int MB_BASE[6] = {0, 256, 512, 768, 804, 807};     // mask-block bases
__constant__ int MB_CT[5]   = {8, 8, 8, 3, 1};                  // col tiles per lvl
__constant__ int SGB6[6]    = {0, 12, 15, 16, 17, 18};          // 4096-elem tile bases

#define M_TOT 6960
#define U_PER_IMG 65472
#define MAX_OUT 1000
#define MWORDS_PER_IMG 223104
#define CAP 4096

struct Ptrs { const float* cls[5]; const float* reg[5]; };

// fl(inter/uni) > 0.7f  <=>  inter/uni >= MTH  (tie at MTH rounds to even
// mantissa 0x3F333334 > 0.7f). Evaluated in f64: exact except a ~2^-53 band.
#define MTH 0.7000000178813934326171875

// ---------------- XLA:CPU-compatible expf (Cephes/Eigen pexp, FMA-contracted) ----
__device__ __forceinline__ float xla_expf(float x) {
  const float exp_hi = 88.3762626647950f;
  const float exp_lo = -88.3762626647949f;
  const float log2ef = 1.44269504088896341f;
  const float c1 = 0.693359375f;
  const float c2 = -2.12194440e-4f;
  const float p0 = 1.9875691500e-4f;
  const float p1 = 1.3981999507e-3f;
  const float p2 = 8.3334519073e-3f;
  const float p3 = 4.1665795894e-2f;
  const float p4 = 1.6666665459e-1f;
  const float p5 = 5.0000001201e-1f;
  float xx = fminf(fmaxf(x, exp_lo), exp_hi);
  float fx = floorf(__fmaf_rn(xx, log2ef, 0.5f));
  float r = __fmaf_rn(fx, -c1, xx);
  r = __fmaf_rn(fx, -c2, r);
  float z = __fmul_rn(r, r);
  float y = __fmaf_rn(p0, r, p1);
  y = __fmaf_rn(y, r, p2);
  y = __fmaf_rn(y, r, p3);
  y = __fmaf_rn(y, r, p4);
  y = __fmaf_rn(y, r, p5);
  y = __fmaf_rn(y, z, r);
  y = __fadd_rn(y, 1.0f);
  int n = (int)fx;
  float two_n = __uint_as_float((unsigned)(n + 127) << 23);
  return __fmul_rn(y, two_n);
}

__device__ __forceinline__ float ref_sigmoid(float x) {
  return __fdiv_rn(1.0f, __fadd_rn(1.0f, xla_expf(-x)));
}

// ================= K0: wide sigmoid + per-block histogram slice ==============
// float4/uint4 vectorized (all level sizes are multiples of 4; 16B-aligned).
__global__ __launch_bounds__(1024) void k_sig(Ptrs p, unsigned* u_arr,
    unsigned* ghist, unsigned long long* vflags, unsigned* gcnt) {
  const int img = blockIdx.y;
  const int bx = blockIdx.x;
  int lvl = 0;
  while (bx >= SGB6[lvl + 1]) ++lvl;
  const int N = LV_N[lvl];
  const int e0 = (bx - SGB6[lvl]) * 4096;
  const int e1 = (e0 + 4096 < N) ? e0 + 4096 : N;
  const int tid = (int)threadIdx.x;
  if (bx == 0) {
    if (tid < 160) vflags[(size_t)img * 160 + tid] = 0ULL;
    if (tid < 5) gcnt[img * 5 + tid] = 0u;
  }
  __shared__ unsigned h[4096];
  for (int e = tid; e < 4096; e += 1024) h[e] = 0;
  __syncthreads();
  const float* cls = p.cls[lvl] + (size_t)img * N;
  unsigned* u = u_arr + img * U_PER_IMG + LV_UOFF[lvl];
  for (int e = e0 + tid * 4; e < e1; e += 4096) {
    float4 v = *(const float4*)&cls[e];
    unsigned b0 = __float_as_uint(ref_sigmoid(v.x));
    unsigned b1 = __float_as_uint(ref_sigmoid(v.y));
    unsigned b2 = __float_as_uint(ref_sigmoid(v.z));
    unsigned b3 = __float_as_uint(ref_sigmoid(v.w));
    *(uint4*)&u[e] = make_uint4(b0, b1, b2, b3);
    atomicAdd(&h[(b0 >> 18) & 4095u], 1u);
    atomicAdd(&h[(b1 >> 18) & 4095u], 1u);
    atomicAdd(&h[(b2 >> 18) & 4095u], 1u);
    atomicAdd(&h[(b3 >> 18) & 4095u], 1u);
  }
  __syncthreads();
  unsigned* gh = ghist + ((size_t)(img * 18 + bx) << 12);
  for (int e = tid; e < 4096; e += 1024) gh[e] = h[e];
}

// ================= K1a: threshold pick (hierarchical wave suffix-scan) =======
__global__ __launch_bounds__(1024) void k_thresh(const unsigned* u_arr,
    const unsigned* ghist, unsigned long long* T64_arr) {
  const int blk = blockIdx.x;
  const int img = blk / 5, lvl = blk % 5;
  const int N = LV_N[lvl], K = LV_K[lvl], LOGHW = LV_LOGHW[lvl];
  const int HW = 1 << LOGHW;
  const int tid = (int)threadIdx.x;
  const int lane = tid & 63, w = tid >> 6;
  if (N <= K) { if (tid == 0) T64_arr[blk] = 0ULL; return; }
  __shared__ unsigned h[4096];
  __shared__ unsigned wsum[16], wsuf[16];
  __shared__ unsigned sh_D, sh_sD, sh_sD1;
  const unsigned* u = u_arr + img * U_PER_IMG + LV_UOFF[lvl];

  unsigned long long prefix = 0;
  unsigned want = (unsigned)K, above = 0;
  const int shifts[6] = {50, 38, 26, 14, 2, 0};
  for (int rd = 0; rd < 6; ++rd) {
    const int shift = shifts[rd];
    if (rd == 5) {                          // final 2-bit round: trivial serial
      for (int e = tid; e < 4; e += 1024) h[e] = 0;
      __syncthreads();
      for (int q = tid; q < N; q += 1024) {
        unsigned a = (unsigned)q >> LOGHW, pix = (unsigned)q & (unsigned)(HW - 1);
        unsigned ecl = pix * 3u + a;
        unsigned long long key =
            ((unsigned long long)u[q] << 32) | (unsigned)(~ecl);
        if ((key >> 2) == prefix) atomicAdd(&h[(unsigned)key & 3u], 1u);
      }
      __syncthreads();
      if (tid == 0) {
        unsigned cum = 0; int D = 0;
        for (int v = 3; v >= 0; --v) {
          if (cum + h[v] >= want) { D = v; break; }
          cum += h[v];
        }
        T64_arr[blk] = (prefix << 2) | (unsigned)D;
      }
      return;
    }
    unsigned h0, h1, h2, h3;
    if (rd == 0) {                         // sum per-block slices (uint4 loads)
      h0 = h1 = h2 = h3 = 0;
      for (int t = SGB6[lvl]; t < SGB6[lvl + 1]; ++t) {
        const uint4* g4 = (const uint4*)(ghist + ((size_t)(img * 18 + t) << 12));
        uint4 v = g4[tid];
        h0 += v.x; h1 += v.y; h2 += v.z; h3 += v.w;
      }
    } else {                               // exact rescan (rarely taken)
      for (int e = tid; e < 4096; e += 1024) h[e] = 0;
      __syncthreads();
      for (int q = tid; q < N; q += 1024) {
        unsigned a = (unsigned)q >> LOGHW, pix = (unsigned)q & (unsigned)(HW - 1);
        unsigned ecl = pix * 3u + a;
        unsigned long long key =
            ((unsigned long long)u[q] << 32) | (unsigned)(~ecl);
        if ((key >> (shift + 12)) == prefix)
          atomicAdd(&h[(unsigned)(key >> shift) & 4095u], 1u);
      }
      __syncthreads();
      h0 = h[4 * tid + 0]; h1 = h[4 * tid + 1];
      h2 = h[4 * tid + 2]; h3 = h[4 * tid + 3];
    }
    // hierarchical suffix scan: 4 elems/thread, wave shfl, 16-wave combine
    unsigned s = h0 + h1 + h2 + h3;
    unsigned suf = s;
    #pragma unroll
    for (int off = 1; off < 64; off <<= 1) {
      unsigned t2 = __shfl_down(suf, off);
      if (lane + off < 64) suf += t2;
    }
    if (lane == 0) wsum[w] = suf;
    __syncthreads();
    if (tid < 16) {
      unsigned v = wsum[tid];
      #pragma unroll
      for (int off = 1; off < 16; off <<= 1) {
        unsigned t2 = __shfl_down(v, off);
        if (tid + off < 16) v += t2;
      }
      wsuf[tid] = v;
    }
    __syncthreads();
    unsigned Sth = ((w + 1 < 16) ? wsuf[w + 1] : 0u) + (suf - s);
    unsigned f3 = Sth + h3;
    unsigned f2 = f3 + h2;
    unsigned f1 = f2 + h1;
    unsigned f0 = f1 + h0;
    if (f0 >= want && f1 < want) { sh_D = 4u * tid + 0; sh_sD = f0; sh_sD1 = f1; }
    if (f1 >= want && f2 < want) { sh_D = 4u * tid + 1; sh_sD = f1; sh_sD1 = f2; }
    if (f2 >= want && f3 < want) { sh_D = 4u * tid + 2; sh_sD = f2; sh_sD1 = f3; }
    if (f3 >= want && Sth < want) { sh_D = 4u * tid + 3; sh_sD = f3; sh_sD1 = Sth; }
    __syncthreads();
    unsigned D = sh_D, sD = sh_sD, sD1 = sh_sD1;
    unsigned long long npref = (prefix << 12) | (unsigned long long)D;
    if (above + sD <= (unsigned)CAP) {
      if (tid == 0) T64_arr[blk] = npref << shift;
      return;                              // uniform decision across block
    }
    above += sD1; want -= sD1; prefix = npref;
    __syncthreads();
  }
}

// ================= K1b: wide collect, ONE global atomic per block ============
__global__ __launch_bounds__(1024) void k_collect(const unsigned* u_arr,
    const unsigned long long* T64_arr, unsigned long long* gtk, unsigned* gcnt) {
  const int img = blockIdx.y;
  const int bx = blockIdx.x;
  int lvl = 0;
  while (bx >= SGB6[lvl + 1]) ++lvl;
  const int N = LV_N[lvl], LOGHW = LV_LOGHW[lvl];
  const int HW = 1 << LOGHW;
  const int e0 = (bx - SGB6[lvl]) * 4096;
  const int tid = (int)threadIdx.x;
  const int lane = tid & 63;
  const int w = tid >> 6;                     // 16 waves
  const unsigned long long T = T64_arr[img * 5 + lvl];
  const unsigned* u = u_arr + img * U_PER_IMG + LV_UOFF[lvl];

  __shared__ unsigned wcnt[64];               // [wave*4 + iter] -> offsets

  unsigned long long key0 = 0, key1 = 0, key2 = 0, key3 = 0;
  unsigned long long bm0, bm1, bm2, bm3;
  #define MKKEY(KV, Q)                                                      \
    {                                                                       \
      unsigned a_ = (unsigned)(Q) >> LOGHW;                                 \
      unsigned pix_ = (unsigned)(Q) & (unsigned)(HW - 1);                   \
      unsigned ecl_ = pix_ * 3u + a_;                                       \
      KV = ((unsigned long long)u[Q] << 32) | (unsigned)(~ecl_);            \
    }
  {
    int q = e0 + 0 * 1024 + tid;
    bool pr = false;
    if (q < N) { MKKEY(key0, q) pr = key0 >= T; }
    bm0 = __ballot(pr);
    if (lane == 0) wcnt[w * 4 + 0] = (unsigned)__popcll(bm0);
  }
  {
    int q = e0 + 1 * 1024 + tid;
    bool pr = false;
    if (q < N) { MKKEY(key1, q) pr = key1 >= T; }
    bm1 = __ballot(pr);
    if (lane == 0) wcnt[w * 4 + 1] = (unsigned)__popcll(bm1);
  }
  {
    int q = e0 + 2 * 1024 + tid;
    bool pr = false;
    if (q < N) { MKKEY(key2, q) pr = key2 >= T; }
    bm2 = __ballot(pr);
    if (lane == 0) wcnt[w * 4 + 2] = (unsigned)__popcll(bm2);
  }
  {
    int q = e0 + 3 * 1024 + tid;
    bool pr = false;
    if (q < N) { MKKEY(key3, q) pr = key3 >= T; }
    bm3 = __ballot(pr);
    if (lane == 0) wcnt[w * 4 + 3] = (unsigned)__popcll(bm3);
  }
  #undef MKKEY
  __syncthreads();
  if (tid < 64) {
    unsigned c = wcnt[tid];
    unsigned pre = c;
    #pragma unroll
    for (int off = 1; off < 64; off <<= 1) {
      unsigned t = __shfl_up(pre, off);
      if (tid >= off) pre += t;
    }
    unsigned total = __shfl(pre, 63);
    unsigned base = 0;
    if (tid == 63 && total) base = atomicAdd(gcnt + (img * 5 + lvl), total);
    base = __shfl(base, 63);
    wcnt[tid] = base + pre - c;               // exclusive (wave,iter) offset
  }
  __syncthreads();
  unsigned long long* dst = gtk + (size_t)(img * 5 + lvl) * CAP;
  const unsigned long long below = (1ULL << lane) - 1ULL;
  if ((bm0 >> lane) & 1ULL) {
    unsigned slot = wcnt[w * 4 + 0] + (unsigned)__popcll(bm0 & below);
    if (slot < (unsigned)CAP) dst[slot] = key0;
  }
  if ((bm1 >> lane) & 1ULL) {
    unsigned slot = wcnt[w * 4 + 1] + (unsigned)__popcll(bm1 & below);
    if (slot < (unsigned)CAP) dst[slot] = key1;
  }
  if ((bm2 >> lane) & 1ULL) {
    unsigned slot = wcnt[w * 4 + 2] + (unsigned)__popcll(bm2 & below);
    if (slot < (unsigned)CAP) dst[slot] = key2;
  }
  if ((bm3 >> lane) & 1ULL) {
    unsigned slot = wcnt[w * 4 + 3] + (unsigned)__popcll(bm3 & below);
    if (slot < (unsigned)CAP) dst[slot] = key3;
  }
}

// ================= K1c: brute-force rank + direct decode (no sort) ===========
__global__ __launch_bounds__(256) void k_rank(Ptrs p,
    const unsigned long long* gtk, const unsigned* gcnt,
    float* cand_box, float* cand_s, unsigned long long* vflags) {
  const int il = (int)blockIdx.y;
  const int img = il / 5, lvl = il % 5;
  const int N = LV_N[lvl], K = LV_K[lvl], W = LV_W[lvl], S = LV_S[lvl];
  const int HW = N / 3;
  const float* reg = p.reg[lvl] + (size_t)img * 12 * HW;
  const int tid = (int)threadIdx.x;
  unsigned cnt = gcnt[il];
  if (cnt > (unsigned)CAP) cnt = CAP;
  if ((unsigned)blockIdx.x * 256u >= cnt) return;   // uniform: skip staging too
  const unsigned cnt32 = (cnt + 31u) & ~31u;
  __shared__ ulonglong2 keys2[CAP / 2];
  unsigned long long* keys = (unsigned long long*)keys2;
  const ulonglong2* src2 = (const ulonglong2*)(gtk + (size_t)il * CAP);
  for (int e = tid; e < (int)(cnt32 >> 1); e += 256) {
    ulonglong2 v = src2[e];                     // beyond-cnt garbage zeroed:
    if (2 * e >= (int)cnt) v.x = 0ULL;          // real keys >= 2^32 > 0 pad
    if (2 * e + 1 >= (int)cnt) v.y = 0ULL;
    keys2[e] = v;
  }
  __syncthreads();
  const int s = (int)blockIdx.x * 256 + tid;
  if (s >= (int)cnt) return;
  const unsigned long long mykey = keys[s];
  unsigned r0 = 0, r1 = 0, r2 = 0, r3 = 0;
  const unsigned half = cnt32 >> 1;           // # of ulonglong2 entries
  for (unsigned j = 0; j < half; j += 16) {
    #pragma unroll
    for (int q = 0; q < 16; q += 4) {
      ulonglong2 a = keys2[j + q + 0];
      ulonglong2 b = keys2[j + q + 1];
      ulonglong2 cc = keys2[j + q + 2];
      ulonglong2 d = keys2[j + q + 3];
      r0 += (a.x > mykey ? 1u : 0u) + (a.y > mykey ? 1u : 0u);
      r1 += (b.x > mykey ? 1u : 0u) + (b.y > mykey ? 1u : 0u);
      r2 += (cc.x > mykey ? 1u : 0u) + (cc.y > mykey ? 1u : 0u);
      r3 += (d.x > mykey ? 1u : 0u) + (d.y > mykey ? 1u : 0u);
    }
  }
  unsigned rank = r0 + r1 + r2 + r3;
  if (rank >= (unsigned)K) return;

  unsigned ubits = (unsigned)(mykey >> 32);
  unsigned idx = ~((unsigned)mykey);
  int a = (int)(idx % 3u); int pix = (int)(idx / 3u);
  int xq = pix % W, yq = pix / W;
  float dx = reg[(a * 4 + 0) * HW + pix];
  float dy = reg[(a * 4 + 1) * HW + pix];
  float dw = reg[(a * 4 + 2) * HW + pix];
  float dh = reg[(a * 4 + 3) * HW + pix];
  double rr = (a == 0) ? 0.5 : (a == 1 ? 1.0 : 2.0);
  double hr = sqrt(rr), wr = 1.0 / hr;
  double st = (double)S;
  double wsd = st * wr * 8.0, hsd = st * hr * 8.0;
  double sxd = (double)(xq * S), syd = (double)(yq * S);
  float a0 = (float)(sxd - 0.5 * wsd), a1 = (float)(syd - 0.5 * hsd);
  float a2 = (float)(sxd + 0.5 * wsd), a3 = (float)(syd + 0.5 * hsd);
  float px = __fmul_rn(__fadd_rn(a0, a2), 0.5f);
  float py = __fmul_rn(__fadd_rn(a1, a3), 0.5f);
  float pw = __fsub_rn(a2, a0), ph = __fsub_rn(a3, a1);
  const float MRf = 4.135166556742356f;  // |log(16/1000)| rounded to f32
  float dwc = fminf(fmaxf(dw, -MRf), MRf);
  float dhc = fminf(fmaxf(dh, -MRf), MRf);
  float gw = __fmul_rn(pw, xla_expf(dwc));
  float gh = __fmul_rn(ph, xla_expf(dhc));
  float gx = __fmaf_rn(pw, dx, px);
  float gy = __fmaf_rn(ph, dy, py);
  float x1 = fminf(fmaxf(__fmaf_rn(gw, -0.5f, gx), 0.0f), 512.0f);
  float y1 = fminf(fmaxf(__fmaf_rn(gh, -0.5f, gy), 0.0f), 512.0f);
  float x2 = fminf(fmaxf(__fmaf_rn(gw,  0.5f, gx), 0.0f), 512.0f);
  float y2 = fminf(fmaxf(__fmaf_rn(gh,  0.5f, gy), 0.0f), 512.0f);
  bool valid = (__fsub_rn(x2, x1) > 0.0f) && (__fsub_rn(y2, y1) > 0.0f);
  int pos = img * M_TOT + LV_OFF[lvl] + (int)rank;
  cand_box[(size_t)pos * 4 + 0] = x1;
  cand_box[(size_t)pos * 4 + 1] = y1;
  cand_box[(size_t)pos * 4 + 2] = x2;
  cand_box[(size_t)pos * 4 + 3] = y2;
  float score = __uint_as_float(ubits);
  cand_s[pos] = valid ? score : -1.0f;
  if (valid)
    atomicOr(&vflags[(size_t)il * 32 + (rank >> 6)], 1ULL << (rank & 63));
}

// ================= K1d: partition (valids first) + NMS-order arrays ==========
__global__ __launch_bounds__(256) void k_part(const float* cand_box,
    const float* cand_s, const unsigned long long* vflags,
    float* n_x1, float* n_y1, float* n_x2, float* n_y2, float* n_ar,
    float* n_sc, unsigned* n_pos, unsigned* V_arr) {
  const int il = (int)blockIdx.x;
  const int img = il / 5, lvl = il % 5;
  const int K = LV_K[lvl];
  const int tid = (int)threadIdx.x;
  __shared__ unsigned long long sflag[32];
  __shared__ unsigned wpre[33];
  if (tid < 32) sflag[tid] = vflags[(size_t)il * 32 + tid];
  __syncthreads();
  if (tid < 32) {
    unsigned c = (unsigned)__popcll(sflag[tid]);
    #pragma unroll
    for (int off = 1; off < 32; off <<= 1) {
      unsigned t = __shfl_up(c, off);
      if (tid >= off) c += t;
    }
    wpre[tid + 1] = c;
    if (tid == 0) wpre[0] = 0;
  }
  __syncthreads();
  const unsigned V = wpre[32];
  const float offv = __fmul_rn((float)lvl, 513.0f);
  const int base = img * M_TOT + LV_OFF[lvl];
  for (int r = tid; r < K; r += 256) {
    unsigned long long word = sflag[r >> 6];
    unsigned fl = (unsigned)((word >> (r & 63)) & 1ULL);
    unsigned excl = wpre[r >> 6] +
                    (unsigned)__popcll(word & ((1ULL << (r & 63)) - 1ULL));
    unsigned pdst = fl ? excl : V + ((unsigned)r - excl);
    const float* b = cand_box + (size_t)(base + r) * 4;
    float ox1 = __fadd_rn(b[0], offv), oy1 = __fadd_rn(b[1], offv);
    float ox2 = __fadd_rn(b[2], offv), oy2 = __fadd_rn(b[3], offv);
    int dst = base + (int)pdst;
    n_x1[dst] = ox1; n_y1[dst] = oy1; n_x2[dst] = ox2; n_y2[dst] = oy2;
    n_ar[dst] = __fmul_rn(__fsub_rn(ox2, ox1), __fsub_rn(oy2, oy1));
    n_sc[dst] = cand_s[base + r];
    n_pos[dst] = (unsigned)(LV_OFF[lvl] + r);
  }
  if (tid == 0) V_arr[il] = V;
}

// ================= K2a: suppression bit-matrix build + diag transpose ========
#define TSTAGE(S, M)                                                        \
  {                                                                         \
    unsigned long long t_ = __shfl_xor(x, S);                               \
    x = (lane & S) ? ((x & (M)) | ((t_ >> S) & ~(M)))                       \
                   : ((x & ~(M)) | ((t_ << S) & (M)));                      \
  }

__global__ __launch_bounds__(256) void k_mask(
    const float* n_x1, const float* n_y1, const float* n_x2, const float* n_y2,
    const float* n_ar, unsigned long long* mask, unsigned long long* diagT) {
  const int img = blockIdx.y;
  const int bx = blockIdx.x;
  int lvl = 0;
  while (bx >= MB_BASE[lvl + 1]) ++lvl;
  const int t = bx - MB_BASE[lvl];
  const int ct = MB_CT[lvl];
  const int rt = t / ct, c = t % ct;
  const int K = LV_K[lvl];
  const int row0 = rt * 64, col0 = c * 256;
  if (col0 + 255 <= row0) return;  // entire tile has j <= r: bits never consumed

  __shared__ float4 cb4[256];
  __shared__ float cba[256];
  __shared__ float4 rb4[64];
  __shared__ float rba[64];
  const int base = img * M_TOT + LV_OFF[lvl];
  const int tid = (int)threadIdx.x;
  if (tid < 64) {
    int r = row0 + tid;
    if (r < K) {
      rb4[tid] = make_float4(n_x1[base + r], n_y1[base + r],
                             n_x2[base + r], n_y2[base + r]);
      rba[tid] = n_ar[base + r];
    } else {
      rb4[tid] = make_float4(0.f, 0.f, 0.f, 0.f);
      rba[tid] = 0.f;
    }
  }
  {
    int j = col0 + tid;
    if (j < K) {
      cb4[tid] = make_float4(n_x1[base + j], n_y1[base + j],
                             n_x2[base + j], n_y2[base + j]);
      cba[tid] = n_ar[base + j];
    }
  }
  __syncthreads();
  const int wl = tid >> 6, lane = tid & 63;
  // word entirely below the diagonal: never consumed by k_scan -> skip.
  if (col0 + (wl << 6) + 63 <= row0) return;
  // word entirely beyond K: MUST not store (r*WPL+(col>>6) would alias the
  // NEXT row's word 0 -> write race). Only possible at lvl4 wl=3.
  if (col0 + (wl << 6) >= K) return;
  const int r = row0 + lane;
  const bool rvalid = (r < K);
  const float4 rb = rb4[lane];
  const float rar = rba[lane];
  unsigned long long word = 0ULL;
  const int jbase = wl * 64;
  const int jmax = K - col0 - jbase;   // >0 here; bits >= jmax masked after loop
  #pragma unroll 16
  for (int k = 0; k < 64; ++k) {
    float4 cb = cb4[jbase + k];        // broadcast: all lanes same address
    float car = cba[jbase + k];
    float iw = fmaxf(__fsub_rn(fminf(rb.z, cb.z), fmaxf(rb.x, cb.x)), 0.0f);
    float ih = fmaxf(__fsub_rn(fminf(rb.w, cb.w), fmaxf(rb.y, cb.y)), 0.0f);
    float inter = __fmul_rn(iw, ih);
    float uni = __fsub_rn(__fadd_rn(rar, car), inter);
    bool sup = (uni > 0.0f) && ((double)inter >= MTH * (double)uni);
    word |= sup ? (1ULL << k) : 0ULL;
  }
  if (jmax < 64) word &= (1ULL << jmax) - 1ULL;   // hoisted column-bound mask
  if (!rvalid) word = 0ULL;
  if (rvalid)
    mask[(size_t)img * MWORDS_PER_IMG + MOFF[lvl] +
         (size_t)r * WPL[lvl] + (size_t)((col0 >> 6) + wl)] = word;
  // diag 64x64 block of this chunk lives in word wl where col0+64*wl == row0:
  // transpose it across lanes (lane i -> column i) and store to diagT.
  if (col0 + (wl << 6) == row0) {
    unsigned long long x = word;
    TSTAGE(32, 0xFFFFFFFF00000000ULL)
    TSTAGE(16, 0xFFFF0000FFFF0000ULL)
    TSTAGE(8,  0xFF00FF00FF00FF00ULL)
    TSTAGE(4,  0xF0F0F0F0F0F0F0F0ULL)
    TSTAGE(2,  0xCCCCCCCCCCCCCCCCULL)
    TSTAGE(1,  0xAAAAAAAAAAAAAAAAULL)
    diagT[(size_t)(img * 5 + lvl) * (40 * 64) + (size_t)rt * 64 + lane] = x;
  }
}

// ================= K2b: 8-wave chunked greedy scan ===========================
#define SCAN_CHUNK(P0, P1, P2, P3)                                          \
  {                                                                         \
    const int r0 = c << 6;                                                  \
    if (w == (c & 7)) {                                                     \
      unsigned long long v = (g == (c >> 3)) ? aw : ~0ULL;                  \
      v &= __shfl_xor(v, 1);                                                \
      v &= __shfl_xor(v, 2);                                                \
      v &= __shfl_xor(v, 4);                                                \
      v &= __shfl_xor(v, 8);                                                \
      v = __shfl(v, (c >> 3) * 16);                                         \
      unsigned long long x = dg;                                            \
      unsigned long long kw = v;                                            \
      while (true) {                                                        \
        bool keep_j = (((v >> lane) & 1ULL) != 0ULL) &&                     \
                      ((kw & below & x) == 0ULL);                           \
        unsigned long long nkw = __ballot(keep_j);                          \
        if (nkw == kw) break;                                               \
        kw = nkw;                                                           \
      }                                                                     \
      if ((kw >> lane) & 1ULL)                                              \
        skept[kept + (int)__popcll(kw & below)] = (unsigned)(r0 + lane);    \
      if (lane == 0) s_kw[c & 1] = kw;                                      \
      int no_ = next_own < 40 ? next_own : 39;                              \
      dg = dT[(size_t)no_ * 64 + lane];                                     \
      next_own += 8;                                                        \
    }                                                                       \
    __syncthreads();                                                        \
    unsigned long long kwv = s_kw[c & 1];                                   \
    kept += (int)__popcll(kwv);                                             \
    aw &= ~(P0 & (unsigned long long)((long long)(kwv << (63 - (d0 + 0))) >> 63)); \
    aw &= ~(P1 & (unsigned long long)((long long)(kwv << (63 - (d0 + 1))) >> 63)); \
    aw &= ~(P2 & (unsigned long long)((long long)(kwv << (63 - (d0 + 2))) >> 63)); \
    aw &= ~(P3 & (unsigned long long)((long long)(kwv << (63 - (d0 + 3))) >> 63)); \
    P0 = mb[(size_t)(r0 + 128 + d0 + 0) * wpl + wkc];                       \
    P1 = mb[(size_t)(r0 + 128 + d0 + 1) * wpl + wkc];                       \
    P2 = mb[(size_t)(r0 + 128 + d0 + 2) * wpl + wkc];                       \
    P3 = mb[(size_t)(r0 + 128 + d0 + 3) * wpl + wkc];                       \
    ++c;                                                                    \
  }

__global__ __launch_bounds__(512) void k_scan(const unsigned long long* mask,
    const unsigned long long* diagT,
    const unsigned* n_pos, const float* n_sc, const unsigned* V_arr,
    unsigned* kept_pos, unsigned long long* kept_key, unsigned* kept_cnt) {
  const int il = (int)blockIdx.x;
  const int img = il / 5, lvl = il % 5;
  const int K = LV_K[lvl], wpl = WPL[lvl];
  const int tid = (int)threadIdx.x;
  const int w = tid >> 6, lane = tid & 63;
  const unsigned long long* mb =
      mask + (size_t)img * MWORDS_PER_IMG + MOFF[lvl];
  const unsigned long long* dT = diagT + (size_t)il * (40 * 64);

  __shared__ unsigned long long s_kw[2];
  __shared__ unsigned skept[MAX_OUT + 64];

  const int g = lane >> 4;
  const int wk = w + 8 * g;
  const int wkc = wk < wpl ? wk : 0;      // clamped (dup loads harmless)
  const int d0 = (lane & 15) * 4;         // my 4 suppression rows per chunk
  const unsigned long long below = (1ULL << lane) - 1ULL;

  const int V = (int)V_arr[il];
  unsigned long long aw;
  {
    int lo = wk * 64, hi = V < lo + 64 ? V : lo + 64;
    aw = (hi > lo) ? ((hi - lo == 64) ? ~0ULL : ((1ULL << (hi - lo)) - 1ULL))
                   : 0ULL;
  }

  const int nchunks = (K + 63) >> 6;
  unsigned long long pfA0 = mb[(size_t)(d0 + 0) * wpl + wkc];
  unsigned long long pfA1 = mb[(size_t)(d0 + 1) * wpl + wkc];
  unsigned long long pfA2 = mb[(size_t)(d0 + 2) * wpl + wkc];
  unsigned long long pfA3 = mb[(size_t)(d0 + 3) * wpl + wkc];
  unsigned long long pfB0 = mb[(size_t)(64 + d0 + 0) * wpl + wkc];
  unsigned long long pfB1 = mb[(size_t)(64 + d0 + 1) * wpl + wkc];
  unsigned long long pfB2 = mb[(size_t)(64 + d0 + 2) * wpl + wkc];
  unsigned long long pfB3 = mb[(size_t)(64 + d0 + 3) * wpl + wkc];
  unsigned long long dg = dT[(size_t)w * 64 + lane];
  int next_own = w + 8;

  int kept = 0;
  int c = 0;
  while (c < nchunks && kept < MAX_OUT) {
    SCAN_CHUNK(pfA0, pfA1, pfA2, pfA3)
    if (c >= nchunks || kept >= MAX_OUT) break;
    SCAN_CHUNK(pfB0, pfB1, pfB2, pfB3)
  }

  __syncthreads();
  const int kc = kept < MAX_OUT ? kept : MAX_OUT;
  const int base = img * M_TOT + LV_OFF[lvl];
  const size_t bo = (size_t)il * 1024;
  for (int i = tid; i < kc; i += 512) {
    unsigned r = skept[i];
    unsigned pp = n_pos[base + (int)r];
    kept_pos[bo + i] = pp;
    kept_key[bo + i] =
        ((unsigned long long)__float_as_uint(n_sc[base + (int)r]) << 32) |
        (unsigned)(~pp);
  }
  if (tid == 0) kept_cnt[il] = (unsigned)kc;
}

// ================= K3: per-(img,lvl) merge -> output rows (20 blocks) =========
__global__ __launch_bounds__(1024) void k_merge(const float* cand_box,
    const float* cand_s, const unsigned* kept_pos,
    const unsigned long long* kept_key, const unsigned* kept_cnt, float* out) {
  const int il = (int)blockIdx.x;      // img*5 + l
  const int img = il / 5, l = il % 5;
  const int tid = (int)threadIdx.x;
  __shared__ unsigned cnts[5];
  __shared__ unsigned long long skey[5][1024];
  if (tid < 5) {
    unsigned c = kept_cnt[img * 5 + tid];
    cnts[tid] = c < (unsigned)MAX_OUT ? c : (unsigned)MAX_OUT;
  }
  __syncthreads();
  for (int e = tid; e < 5 * 1024; e += 1024) {
    int l2 = e >> 10, s = e & 1023;
    skey[l2][s] = (s < (int)cnts[l2])
        ? kept_key[(size_t)(img * 5 + l2) * 1024 + s] : 0ULL;
  }
  __syncthreads();
  if (l == 0) {                        // one block per image zero-fills tail
    unsigned T = cnts[0] + cnts[1] + cnts[2] + cnts[3] + cnts[4];
    unsigned Tc = T < (unsigned)MAX_OUT ? T : (unsigned)MAX_OUT;
    for (int r = (int)Tc + tid; r < MAX_OUT; r += 1024) {
      float* o = out + (size_t)img * (MAX_OUT * 5) + (size_t)r * 5;
      o[0] = 0.f; o[1] = 0.f; o[2] = 0.f; o[3] = 0.f; o[4] = 0.f;
    }
  }
  const int s = tid;
  if (s >= (int)cnts[l]) return;
  unsigned long long k0 = skey[l][s];
  unsigned rank = (unsigned)s;
  #pragma unroll
  for (int l2 = 0; l2 < 5; ++l2) {
    if (l2 == l) continue;
    int lo = 0, hi = (int)cnts[l2];
    while (lo < hi) {
      int mid = (lo + hi) >> 1;
      if (skey[l2][mid] > k0) lo = mid + 1; else hi = mid;
    }
    rank += (unsigned)lo;
  }
  if (rank < (unsigned)MAX_OUT) {
    unsigned pos = kept_pos[(size_t)(img * 5 + l) * 1024 + s];
    const float* b = cand_box + (size_t)(img * M_TOT + pos) * 4;
    float* o = out + (size_t)img * (MAX_OUT * 5) + (size_t)rank * 5;
    o[0] = b[0]; o[1] = b[1]; o[2] = b[2]; o[3] = b[3];
    o[4] = cand_s[img * M_TOT + pos];
  }
}

// ================= host launch =================
extern "C" void kernel_launch(void* const* d_in, const int* in_sizes, int n_in,
                              void* d_out, int out_size, void* d_ws, size_t ws_size,
                              hipStream_t stream) {
  Ptrs p;
  bool interleaved = (n_in == 10 && in_sizes[1] == 4 * 12 * 128 * 128);
  for (int l = 0; l < 5; ++l) {
    if (interleaved) {
      p.cls[l] = (const float*)d_in[2 * l];
      p.reg[l] = (const float*)d_in[2 * l + 1];
    } else {
      p.cls[l] = (const float*)d_in[l];
      p.reg[l] = (const float*)d_in[5 + l];
    }
  }
  uint8_t* w = (uint8_t*)d_ws;
  size_t o = 0;
  auto carve = [&](size_t bytes) {
    void* ptr = w + o;
    o += (bytes + 255) & ~(size_t)255;
    return ptr;
  };
  unsigned* gcnt = (unsigned*)carve((size_t)20 * 4);
  unsigned* ghist = (unsigned*)carve((size_t)72 * 4096 * 4);   // per-block slices
  unsigned long long* vflags = (unsigned long long*)carve((size_t)20 * 32 * 8);
  unsigned long long* T64_arr = (unsigned long long*)carve((size_t)20 * 8);
  unsigned* u_arr = (unsigned*)carve((size_t)4 * U_PER_IMG * 4);
  float* cand_box = (float*)carve((size_t)4 * M_TOT * 4 * 4);
  float* cand_s = (float*)carve((size_t)4 * M_TOT * 4);
  float* n_x1 = (float*)carve((size_t)4 * M_TOT * 4);
  float* n_y1 = (float*)carve((size_t)4 * M_TOT * 4);
  float* n_x2 = (float*)carve((size_t)4 * M_TOT * 4);
  float* n_y2 = (float*)carve((size_t)4 * M_TOT * 4);
  float* n_ar = (float*)carve((size_t)4 * M_TOT * 4);
  float* n_sc = (float*)carve((size_t)4 * M_TOT * 4);
  unsigned* n_pos = (unsigned*)carve((size_t)4 * M_TOT * 4);
  unsigned* V_arr = (unsigned*)carve((size_t)20 * 4);
  unsigned* kept_pos = (unsigned*)carve((size_t)4 * 5 * 1024 * 4);
  unsigned long long* kept_key = (unsigned long long*)carve((size_t)4 * 5 * 1024 * 8);
  unsigned* kept_cnt = (unsigned*)carve((size_t)20 * 4);
  unsigned long long* diagT = (unsigned long long*)carve((size_t)20 * 40 * 64 * 8);
  unsigned long long* mask = (unsigned long long*)carve((size_t)4 * MWORDS_PER_IMG * 8);
  // gtk (20*4096 u64 = 640KB) aliases mask: dead before k_mask writes it.
  unsigned long long* gtk = mask;
  (void)ws_size; (void)out_size;

  k_sig<<<dim3(18, 4), 1024, 0, stream>>>(p, u_arr, ghist, vflags, gcnt);
  k_thresh<<<20, 1024, 0, stream>>>(u_arr, ghist, T64_arr);
  k_collect<<<dim3(18, 4), 1024, 0, stream>>>(u_arr, T64_arr, gtk, gcnt);
  k_rank<<<dim3(16, 20), 256, 0, stream>>>(p, gtk, gcnt, cand_box, cand_s,
                                           vflags);
  k_part<<<20, 256, 0, stream>>>(cand_box, cand_s, vflags,
      n_x1, n_y1, n_x2, n_y2, n_ar, n_sc, n_pos, V_arr);
  k_mask<<<dim3(807, 4), 256, 0, stream>>>(n_x1, n_y1, n_x2, n_y2, n_ar,
                                           mask, diagT);
  k_scan<<<20, 512, 0, stream>>>(mask, diagT, n_pos, n_sc, V_arr,
                                 kept_pos, kept_key, kept_cnt);
  k_merge<<<20, 1024, 0, stream>>>(cand_box, cand_s, kept_pos, kept_key,
                                   kept_cnt, (float*)d_out);
}